// Round 1
// baseline (4979.214 us; speedup 1.0000x reference)
//
#include <hip/hip_runtime.h>
#include <hip/hip_bf16.h>

#define DEV __device__ __forceinline__

// ---------------- problem constants ----------------
// B=8, H=W=96, C=180, NH=6, WS=8, hd=30, DA=96, HID=720
// windows: 8 * 12 * 12 = 1152, tokens/window = 64, rows = 73728
static constexpr int NWIN = 1152;
static constexpr int NROW = 73728;

// ---------------- workspace byte offsets (peak ~186.5 MB) ----------------
static constexpr size_t OFF_QKV   = 0;            // bf16 [NROW][540]   (dead after attn)
static constexpr size_t OFF_AWIN  = 79626240;     // f32  [NROW][180]   (dead after proj)
static constexpr size_t OFF_X1    = 132710400;    // f32  [8*9216][180] (live until pe)
static constexpr size_t OFF_TBL   = 185794560;    // f32  [225][6]
static constexpr size_t OFF_BIASA = 185800192;    // f32  [6][64][64]
static constexpr size_t OFF_CWT   = 185899008;    // f32  [9][90][180]
// overlays inside [0, 132.7MB) after attention/proj are done:
static constexpr size_t OFF_V1    = 0;            // f32 [8*96][9216]
static constexpr size_t OFF_AB1   = 28311552;     // f32 [8*96][9216]
static constexpr size_t OFF_AB2   = 56623104;     // f32 [8*96][9216]
static constexpr size_t OFF_V2    = 56623104;     // f32 [8*180][9216] (overlays ab2, dead)
static constexpr size_t OFF_VN    = 0;            // f32 [8*180][9216] (overlays v1+ab1, dead)
static constexpr size_t OFF_CB    = 56623104;     // f32 [8*180][9216] (overlays v2, dead)
static constexpr size_t OFF_H     = 0;            // bf16 [NROW][720]  (overlays conv temps, dead)

DEV float geluf(float x){ return 0.5f*x*(1.f + erff(x*0.70710678118654752f)); }

DEV void fma16(float (&acc)[4][4], const float4 a, const float4 w){
  acc[0][0] += a.x*w.x; acc[0][1] += a.x*w.y; acc[0][2] += a.x*w.z; acc[0][3] += a.x*w.w;
  acc[1][0] += a.y*w.x; acc[1][1] += a.y*w.y; acc[1][2] += a.y*w.z; acc[1][3] += a.y*w.w;
  acc[2][0] += a.z*w.x; acc[2][1] += a.z*w.y; acc[2][2] += a.z*w.z; acc[2][3] += a.z*w.w;
  acc[3][0] += a.w*w.x; acc[3][1] += a.w*w.y; acc[3][2] += a.w*w.z; acc[3][3] += a.w*w.w;
}

// ---------------- CPB MLP table: tbl[225][6] ----------------
__global__ __launch_bounds__(512) void k_cpb_tbl(const float* __restrict__ w1,
    const float* __restrict__ b1, const float* __restrict__ w2, float* __restrict__ tbl){
  int m = blockIdx.x, tid = threadIdx.x;
  int i = m/15, j = m - (m/15)*15;
  float d0 = (float)(i-7), d1 = (float)(j-7);
  float t0 = d0*(8.f/7.f), t1 = d1*(8.f/7.f);
  float f0 = log2f(fabsf(t0)+1.f)*(1.f/3.f); if (t0 < 0.f) f0 = -f0;
  float f1 = log2f(fabsf(t1)+1.f)*(1.f/3.f); if (t1 < 0.f) f1 = -f1;
  float hv = fmaxf(f0*w1[2*tid] + f1*w1[2*tid+1] + b1[tid], 0.f);
  __shared__ float red[6][8];
  int lane = tid & 63, wv = tid >> 6;
  for (int h = 0; h < 6; ++h) {
    float p = hv * w2[h*512 + tid];
    for (int off = 32; off; off >>= 1) p += __shfl_down(p, off);
    if (lane == 0) red[h][wv] = p;
  }
  __syncthreads();
  if (tid < 6) {
    float s = 0.f;
    for (int w = 0; w < 8; ++w) s += red[tid][w];
    tbl[m*6 + tid] = s;
  }
}

// ---------------- biasA[h][n][m] = 16*sigmoid(tbl[rpi(n,m)][h]) ----------------
__global__ __launch_bounds__(256) void k_cpb_bias(const float* __restrict__ tbl,
    float* __restrict__ biasA){
  int idx = blockIdx.x*256 + threadIdx.x;
  if (idx >= 6*64*64) return;
  int h = idx >> 12, n = (idx >> 6) & 63, m = idx & 63;
  int dh = (n>>3) - (m>>3) + 7, dw = (n&7) - (m&7) + 7;
  float v = tbl[(dh*15 + dw)*6 + h];
  biasA[idx] = 16.f / (1.f + expf(-v));
}

// ---------------- qkv GEMM (window-gathered): x -> qkv bf16 [NROW][540] ----------------
__global__ __launch_bounds__(256) void k_qkv(const float* __restrict__ x,
    const float* __restrict__ qkv_w, const float* __restrict__ qb,
    const float* __restrict__ vb, __hip_bfloat16* __restrict__ qkv){
  __shared__ float A[6120], Wl[6120];      // [90][68]
  __shared__ float outl[4352];             // [64][68]
  __shared__ int rowOff[64];
  int win = blockIdx.x, tid = threadIdx.x;
  if (tid < 64) {
    int b = win/144, rem = win - b*144, wh = rem/12, ww = rem - (rem/12)*12;
    int l = (wh*8 + (tid>>3))*96 + ww*8 + (tid&7);
    rowOff[tid] = (b*9216 + l)*180;
  }
  __syncthreads();
  int pg = tid & 15, cg = tid >> 4;
  for (int cc = 0; cc < 9; ++cc) {
    int c0 = cc*64;
    float acc[4][4] = {};
    for (int kt = 0; kt < 2; ++kt) {
      int k0 = kt*90;
      for (int idx = tid; idx < 5760; idx += 256) {
        int i = idx/90, k = idx - i*90;
        A[k*68 + i] = x[rowOff[i] + k0 + k];
      }
      for (int idx = tid; idx < 5760; idx += 256) {
        int ci = idx/90, k = idx - ci*90;
        int c = c0 + ci;
        Wl[k*68 + ci] = (c < 540) ? qkv_w[c*180 + k0 + k] : 0.f;
      }
      __syncthreads();
      #pragma unroll 6
      for (int kk = 0; kk < 90; ++kk)
        fma16(acc, *(const float4*)(A + kk*68 + 4*pg), *(const float4*)(Wl + kk*68 + 4*cg));
      __syncthreads();
    }
    #pragma unroll
    for (int i = 0; i < 4; ++i)
      #pragma unroll
      for (int j = 0; j < 4; ++j)
        outl[(4*pg+i)*68 + 4*cg + j] = acc[i][j];
    __syncthreads();
    for (int idx = tid; idx < 4096; idx += 256) {
      int r = idx >> 6, ci = idx & 63;
      int c = c0 + ci;
      if (c < 540) {
        float bias = (c < 180) ? qb[c] : (c < 360 ? 0.f : vb[c-360]);
        qkv[(size_t)(win*64 + r)*540 + c] = __float2bfloat16(outl[r*68 + ci] + bias);
      }
    }
    __syncthreads();
  }
}

// ---------------- attention per (window, head) -> awin [NROW][180] ----------------
__global__ __launch_bounds__(256) void k_attn(const __hip_bfloat16* __restrict__ qkv,
    const float* __restrict__ biasA, const float* __restrict__ lsc,
    float* __restrict__ awin){
  __shared__ float qs[2048], ks[2048], vs[2048];   // [64][32]
  __shared__ float ps[4416];                       // [64][69]
  int blk = blockIdx.x;
  int win = blk/6, h = blk - win*6;
  int tid = threadIdx.x;
  for (int idx = tid; idx < 2048; idx += 256) {
    int n = idx >> 5, d = idx & 31;
    float qv = 0.f, kv = 0.f, vv = 0.f;
    if (d < 30) {
      size_t row = (size_t)(win*64 + n)*540;
      qv = __bfloat162float(qkv[row + h*30 + d]);
      kv = __bfloat162float(qkv[row + 180 + h*30 + d]);
      vv = __bfloat162float(qkv[row + 360 + h*30 + d]);
    }
    qs[idx] = qv; ks[idx] = kv; vs[idx] = vv;
  }
  __syncthreads();
  if (tid < 128) {
    int n = tid & 63;
    float* base = (tid < 64) ? (qs + n*32) : (ks + n*32);
    float s = 0.f;
    for (int d = 0; d < 30; ++d) { float v = base[d]; s += v*v; }
    float inv = 1.f / fmaxf(sqrtf(s), 1e-12f);
    for (int d = 0; d < 30; ++d) base[d] *= inv;
  }
  __syncthreads();
  float scale = expf(fminf(lsc[h], 4.6051701859880914f));
  {
    int n = tid >> 2, q4 = tid & 3;
    float qreg[32];
    #pragma unroll
    for (int d = 0; d < 32; ++d) qreg[d] = qs[n*32 + d];
    float sc[16];
    #pragma unroll
    for (int mm = 0; mm < 16; ++mm) {
      int m = q4*16 + mm;
      float s = 0.f;
      #pragma unroll
      for (int d4 = 0; d4 < 8; ++d4) {
        float4 kv4 = *(const float4*)(ks + m*32 + d4*4);
        s += qreg[d4*4+0]*kv4.x + qreg[d4*4+1]*kv4.y + qreg[d4*4+2]*kv4.z + qreg[d4*4+3]*kv4.w;
      }
      sc[mm] = s*scale + biasA[((h*64 + n) << 6) + m];
    }
    float mx = -1e30f;
    #pragma unroll
    for (int mm = 0; mm < 16; ++mm) mx = fmaxf(mx, sc[mm]);
    mx = fmaxf(mx, __shfl_xor(mx, 1));
    mx = fmaxf(mx, __shfl_xor(mx, 2));
    float sum = 0.f;
    #pragma unroll
    for (int mm = 0; mm < 16; ++mm) { sc[mm] = expf(sc[mm] - mx); sum += sc[mm]; }
    sum += __shfl_xor(sum, 1);
    sum += __shfl_xor(sum, 2);
    float rinv = 1.f / sum;
    #pragma unroll
    for (int mm = 0; mm < 16; ++mm) ps[n*69 + q4*16 + mm] = sc[mm]*rinv;
  }
  __syncthreads();
  {
    int n = tid & 63, g = tid >> 6;
    float acc[8] = {};
    for (int m = 0; m < 64; ++m) {
      float p = ps[n*69 + m];
      float4 v0 = *(const float4*)(vs + m*32 + g*8);
      float4 v1 = *(const float4*)(vs + m*32 + g*8 + 4);
      acc[0] += p*v0.x; acc[1] += p*v0.y; acc[2] += p*v0.z; acc[3] += p*v0.w;
      acc[4] += p*v1.x; acc[5] += p*v1.y; acc[6] += p*v1.z; acc[7] += p*v1.w;
    }
    __syncthreads();   // qs no longer needed; reuse as output staging
    #pragma unroll
    for (int k = 0; k < 8; ++k) qs[n*32 + g*8 + k] = acc[k];
  }
  __syncthreads();
  for (int idx = tid; idx < 1920; idx += 256) {
    int n = idx/30, d = idx - n*30;
    awin[(size_t)(win*64 + n)*180 + h*30 + d] = qs[n*32 + d];
  }
}

// ---------------- proj + norm1 LN + residual + window-reverse -> x1 ----------------
__global__ __launch_bounds__(256) void k_proj(const float* __restrict__ awin,
    const float* __restrict__ pw, const float* __restrict__ pb,
    const float* __restrict__ g1, const float* __restrict__ b1,
    const float* __restrict__ x, float* __restrict__ x1){
  __shared__ float A[6120], Wl[6120];
  __shared__ float outl[11840];    // [64][185]
  __shared__ float mArr[64], rsArr[64];
  int win = blockIdx.x, tid = threadIdx.x;
  int pg = tid & 15, cg = tid >> 4;
  size_t base = (size_t)win*64;
  for (int cc = 0; cc < 3; ++cc) {
    int c0 = cc*64;
    float acc[4][4] = {};
    for (int kt = 0; kt < 2; ++kt) {
      int k0 = kt*90;
      for (int idx = tid; idx < 5760; idx += 256) {
        int i = idx/90, k = idx - i*90;
        A[k*68 + i] = awin[(base + i)*180 + k0 + k];
      }
      for (int idx = tid; idx < 5760; idx += 256) {
        int ci = idx/90, k = idx - ci*90;
        int c = c0 + ci;
        Wl[k*68 + ci] = (c < 180) ? pw[c*180 + k0 + k] : 0.f;
      }
      __syncthreads();
      #pragma unroll 6
      for (int kk = 0; kk < 90; ++kk)
        fma16(acc, *(const float4*)(A + kk*68 + 4*pg), *(const float4*)(Wl + kk*68 + 4*cg));
      __syncthreads();
    }
    #pragma unroll
    for (int i = 0; i < 4; ++i)
      #pragma unroll
      for (int j = 0; j < 4; ++j) {
        int c = c0 + 4*cg + j;
        if (c < 180) outl[(4*pg+i)*185 + c] = acc[i][j] + pb[c];
      }
  }
  __syncthreads();
  if (tid < 64) {
    float s = 0.f;
    for (int c = 0; c < 180; ++c) s += outl[tid*185 + c];
    float m = s*(1.f/180.f);
    float v = 0.f;
    for (int c = 0; c < 180; ++c) { float d = outl[tid*185 + c] - m; v += d*d; }
    mArr[tid] = m; rsArr[tid] = rsqrtf(v*(1.f/180.f) + 1e-5f);
  }
  __syncthreads();
  int b = win/144, rem = win - b*144, wh = rem/12, ww = rem - (rem/12)*12;
  for (int idx = tid; idx < 11520; idx += 256) {
    int r = idx/180, c = idx - r*180;
    int l = (wh*8 + (r>>3))*96 + ww*8 + (r&7);
    size_t o = (size_t)(b*9216 + l)*180 + c;
    x1[o] = x[o] + (outl[r*185 + c] - mArr[r])*rsArr[r]*g1[c] + b1[c];
  }
}

// ---------------- VAB p1: 1x1 conv C->DA + gelu, NHWC in -> NCHW out ----------------
__global__ __launch_bounds__(256) void k_p1(const float* __restrict__ x1,
    const float* __restrict__ w, const float* __restrict__ bias, float* __restrict__ v1){
  __shared__ float A[6120], Wl[6120];
  int blk = blockIdx.x, tid = threadIdx.x;
  int b = blk/144, p0 = (blk - b*144)*64;
  int pg = tid & 15, cg = tid >> 4;
  int rowb = b*9216 + p0;
  for (int cc = 0; cc < 2; ++cc) {
    int c0 = cc*64;
    float acc[4][4] = {};
    for (int kt = 0; kt < 2; ++kt) {
      int k0 = kt*90;
      for (int idx = tid; idx < 5760; idx += 256) {
        int i = idx/90, k = idx - i*90;
        A[k*68 + i] = x1[(size_t)(rowb + i)*180 + k0 + k];
      }
      for (int idx = tid; idx < 5760; idx += 256) {
        int ci = idx/90, k = idx - ci*90;
        int c = c0 + ci;
        Wl[k*68 + ci] = (c < 96) ? w[c*180 + k0 + k] : 0.f;
      }
      __syncthreads();
      #pragma unroll 6
      for (int kk = 0; kk < 90; ++kk)
        fma16(acc, *(const float4*)(A + kk*68 + 4*pg), *(const float4*)(Wl + kk*68 + 4*cg));
      __syncthreads();
    }
    #pragma unroll
    for (int j = 0; j < 4; ++j) {
      int c = c0 + 4*cg + j;
      if (c < 96) {
        float bb = bias[c];
        float4 val;
        val.x = geluf(acc[0][j] + bb);
        val.y = geluf(acc[1][j] + bb);
        val.z = geluf(acc[2][j] + bb);
        val.w = geluf(acc[3][j] + bb);
        *(float4*)(v1 + (size_t)(b*96 + c)*9216 + p0 + 4*pg) = val;
      }
    }
  }
}

// ---------------- VAB pw: 1x1 conv DA->DA, NCHW -> NCHW ----------------
__global__ __launch_bounds__(256) void k_pw(const float* __restrict__ v1,
    const float* __restrict__ w, const float* __restrict__ bias, float* __restrict__ outp){
  __shared__ float A[6528], Wl[6528];   // [96][68]
  int blk = blockIdx.x, tid = threadIdx.x;
  int b = blk/144, p0 = (blk - b*144)*64;
  int pg = tid & 15, cg = tid >> 4;
  for (int idx = tid; idx < 6144; idx += 256) {
    int k = idx >> 6, i = idx & 63;
    A[k*68 + i] = v1[(size_t)(b*96 + k)*9216 + p0 + i];
  }
  for (int cc = 0; cc < 2; ++cc) {
    int c0 = cc*64;
    float acc[4][4] = {};
    for (int idx = tid; idx < 6144; idx += 256) {
      int ci = idx/96, k = idx - ci*96;
      int c = c0 + ci;
      Wl[k*68 + ci] = (c < 96) ? w[c*96 + k] : 0.f;
    }
    __syncthreads();
    #pragma unroll 6
    for (int kk = 0; kk < 96; ++kk)
      fma16(acc, *(const float4*)(A + kk*68 + 4*pg), *(const float4*)(Wl + kk*68 + 4*cg));
    __syncthreads();
    #pragma unroll
    for (int j = 0; j < 4; ++j) {
      int c = c0 + 4*cg + j;
      if (c < 96) {
        float bb = bias[c];
        float4 val = {acc[0][j]+bb, acc[1][j]+bb, acc[2][j]+bb, acc[3][j]+bb};
        *(float4*)(outp + (size_t)(b*96 + c)*9216 + p0 + 4*pg) = val;
      }
    }
  }
}

// ---------------- depthwise 5x5 (dil=1 pad2 / dil=3 pad6) ----------------
__global__ __launch_bounds__(256) void k_dwc(const float* __restrict__ in,
    const float* __restrict__ w, const float* __restrict__ bias,
    float* __restrict__ out, int dil){
  int blk = blockIdx.x, tid = threadIdx.x;
  int bc = blk/36, pc = blk - bc*36;
  int c = bc - (bc/96)*96;
  int p = pc*256 + tid;
  int hh = p/96, ww = p - hh*96;
  float acc = bias[c];
  const float* wc = w + c*25;
  const float* inb = in + (size_t)bc*9216;
  #pragma unroll
  for (int i = 0; i < 5; ++i) {
    int y = hh + dil*(i-2);
    if (y < 0 || y >= 96) continue;
    #pragma unroll
    for (int j = 0; j < 5; ++j) {
      int xq = ww + dil*(j-2);
      if (xq >= 0 && xq < 96) acc += inb[y*96 + xq]*wc[i*5 + j];
    }
  }
  out[(size_t)bc*9216 + p] = acc;
}

// ---------------- VAB p2: 1x1 conv (v1*a) DA->C, + xim residual -> v2 NCHW ----------------
__global__ __launch_bounds__(256) void k_p2(const float* __restrict__ v1,
    const float* __restrict__ a3, const float* __restrict__ x1,
    const float* __restrict__ w, const float* __restrict__ bias, float* __restrict__ v2){
  __shared__ float A[6528], Wl[6528];
  int blk = blockIdx.x, tid = threadIdx.x;
  int b = blk/144, p0 = (blk - b*144)*64;
  int pg = tid & 15, cg = tid >> 4;
  for (int idx = tid; idx < 6144; idx += 256) {
    int k = idx >> 6, i = idx & 63;
    size_t o = (size_t)(b*96 + k)*9216 + p0 + i;
    A[k*68 + i] = v1[o]*a3[o];
  }
  for (int cc = 0; cc < 3; ++cc) {
    int c0 = cc*64;
    float acc[4][4] = {};
    for (int idx = tid; idx < 6144; idx += 256) {
      int ci = idx/96, k = idx - ci*96;
      int c = c0 + ci;
      Wl[k*68 + ci] = (c < 180) ? w[c*96 + k] : 0.f;
    }
    __syncthreads();
    #pragma unroll 6
    for (int kk = 0; kk < 96; ++kk)
      fma16(acc, *(const float4*)(A + kk*68 + 4*pg), *(const float4*)(Wl + kk*68 + 4*cg));
    __syncthreads();
    #pragma unroll
    for (int j = 0; j < 4; ++j) {
      int c = c0 + 4*cg + j;
      if (c < 180) {
        float bb = bias[c];
        float4 val;
        val.x = acc[0][j] + bb + x1[(size_t)(b*9216 + p0 + 4*pg + 0)*180 + c];
        val.y = acc[1][j] + bb + x1[(size_t)(b*9216 + p0 + 4*pg + 1)*180 + c];
        val.z = acc[2][j] + bb + x1[(size_t)(b*9216 + p0 + 4*pg + 2)*180 + c];
        val.w = acc[3][j] + bb + x1[(size_t)(b*9216 + p0 + 4*pg + 3)*180 + c];
        *(float4*)(v2 + (size_t)(b*180 + c)*9216 + p0 + 4*pg) = val;
      }
    }
  }
}

// ---------------- channel LN over NCHW (per-pixel over 180 ch) ----------------
__global__ __launch_bounds__(256) void k_ln_vab(const float* __restrict__ v2,
    const float* __restrict__ g, const float* __restrict__ bb, float* __restrict__ vn){
  int pix = blockIdx.x*256 + threadIdx.x;
  int b = pix/9216, p = pix - b*9216;
  const float* src = v2 + (size_t)b*180*9216 + p;
  float s = 0.f, s2 = 0.f;
  for (int c = 0; c < 180; ++c) { float v = src[(size_t)c*9216]; s += v; s2 += v*v; }
  float m = s*(1.f/180.f);
  float var = fmaxf(s2*(1.f/180.f) - m*m, 0.f);
  float rs = rsqrtf(var + 1e-5f);
  float* dst = vn + (size_t)b*180*9216 + p;
  for (int c = 0; c < 180; ++c) {
    float v = src[(size_t)c*9216];
    dst[(size_t)c*9216] = (v - m)*rs*g[c] + bb[c];
  }
}

// ---------------- transpose convbody weights -> cwt[tap][ci][o] ----------------
__global__ __launch_bounds__(256) void k_prep_cw(const float* __restrict__ cw,
    float* __restrict__ cwt){
  int idx = blockIdx.x*256 + threadIdx.x;
  if (idx >= 9*90*180) return;
  int tap = idx/16200, rem = idx - tap*16200;
  int ci = rem/180, o = rem - ci*180;
  cwt[idx] = cw[o*810 + ci*9 + tap];
}

// ---------------- convbody: 3x3 grouped (groups=2) conv as 9 shifted GEMMs ----------------
__global__ __launch_bounds__(256) void k_convbody(const float* __restrict__ vn,
    const float* __restrict__ cwt, const float* __restrict__ bias, float* __restrict__ cb){
  __shared__ float A[6120];     // [90][68]
  __shared__ float Wl[8640];    // [90][96]
  int blk = blockIdx.x, tid = threadIdx.x;
  int b = blk/144, p0 = (blk - b*144)*64;
  int pg = tid & 15, cg = tid >> 4;
  for (int gch = 0; gch < 2; ++gch) {
    float acc[4][6] = {};
    for (int tap = 0; tap < 9; ++tap) {
      int dh = tap/3 - 1, dwp = tap - (tap/3)*3 - 1;
      for (int idx = tid; idx < 5760; idx += 256) {
        int k = idx >> 6, i = idx & 63;
        int p = p0 + i;
        int hh = p/96 + dh, ww = (p - (p/96)*96) + dwp;
        float v = 0.f;
        if (hh >= 0 && hh < 96 && ww >= 0 && ww < 96)
          v = vn[(size_t)(b*180 + gch*90 + k)*9216 + hh*96 + ww];
        A[k*68 + i] = v;
      }
      for (int idx = tid; idx < 8640; idx += 256) {
        int ci = idx/96, o = idx - ci*96;
        Wl[ci*96 + o] = (o < 90) ? cwt[(tap*90 + ci)*180 + gch*90 + o] : 0.f;
      }
      __syncthreads();
      #pragma unroll 3
      for (int kk = 0; kk < 90; ++kk) {
        float4 a = *(const float4*)(A + kk*68 + 4*pg);
        float w0 = Wl[kk*96 + cg*6 + 0];
        float w1 = Wl[kk*96 + cg*6 + 1];
        float w2 = Wl[kk*96 + cg*6 + 2];
        float w3 = Wl[kk*96 + cg*6 + 3];
        float w4 = Wl[kk*96 + cg*6 + 4];
        float w5 = Wl[kk*96 + cg*6 + 5];
        acc[0][0] += a.x*w0; acc[1][0] += a.y*w0; acc[2][0] += a.z*w0; acc[3][0] += a.w*w0;
        acc[0][1] += a.x*w1; acc[1][1] += a.y*w1; acc[2][1] += a.z*w1; acc[3][1] += a.w*w1;
        acc[0][2] += a.x*w2; acc[1][2] += a.y*w2; acc[2][2] += a.z*w2; acc[3][2] += a.w*w2;
        acc[0][3] += a.x*w3; acc[1][3] += a.y*w3; acc[2][3] += a.z*w3; acc[3][3] += a.w*w3;
        acc[0][4] += a.x*w4; acc[1][4] += a.y*w4; acc[2][4] += a.z*w4; acc[3][4] += a.w*w4;
        acc[0][5] += a.x*w5; acc[1][5] += a.y*w5; acc[2][5] += a.z*w5; acc[3][5] += a.w*w5;
      }
      __syncthreads();
    }
    #pragma unroll
    for (int j = 0; j < 6; ++j) {
      int ol = cg*6 + j;
      if (ol < 90) {
        int o = gch*90 + ol;
        float bb = bias[o];
        float4 val = {acc[0][j]+bb, acc[1][j]+bb, acc[2][j]+bb, acc[3][j]+bb};
        *(float4*)(cb + (size_t)(b*180 + o)*9216 + p0 + 4*pg) = val;
      }
    }
  }
}

// ---------------- patch-embed 1x1 conv + x1 residual -> d_out (x2, NHWC) ----------------
__global__ __launch_bounds__(256) void k_pe(const float* __restrict__ cbv,
    const float* __restrict__ w, const float* __restrict__ bias,
    const float* __restrict__ x1, float* __restrict__ outp){
  __shared__ float A[6120], Wl[6120];
  __shared__ float outl[11840];   // [64][185]
  int blk = blockIdx.x, tid = threadIdx.x;
  int b = blk/144, p0 = (blk - b*144)*64;
  int pg = tid & 15, cg = tid >> 4;
  for (int cc = 0; cc < 3; ++cc) {
    int c0 = cc*64;
    float acc[4][4] = {};
    for (int kt = 0; kt < 2; ++kt) {
      int k0 = kt*90;
      for (int idx = tid; idx < 5760; idx += 256) {
        int k = idx >> 6, i = idx & 63;
        A[k*68 + i] = cbv[(size_t)(b*180 + k0 + k)*9216 + p0 + i];
      }
      for (int idx = tid; idx < 5760; idx += 256) {
        int ci = idx/90, k = idx - ci*90;
        int c = c0 + ci;
        Wl[k*68 + ci] = (c < 180) ? w[c*180 + k0 + k] : 0.f;
      }
      __syncthreads();
      #pragma unroll 6
      for (int kk = 0; kk < 90; ++kk)
        fma16(acc, *(const float4*)(A + kk*68 + 4*pg), *(const float4*)(Wl + kk*68 + 4*cg));
      __syncthreads();
    }
    #pragma unroll
    for (int i = 0; i < 4; ++i)
      #pragma unroll
      for (int j = 0; j < 4; ++j) {
        int c = c0 + 4*cg + j;
        if (c < 180) outl[(4*pg+i)*185 + c] = acc[i][j];
      }
  }
  __syncthreads();
  for (int idx = tid; idx < 11520; idx += 256) {
    int r = idx/180, c = idx - r*180;
    size_t o = (size_t)(b*9216 + p0 + r)*180 + c;
    outp[o] = x1[o] + outl[r*185 + c] + bias[c];
  }
}

// ---------------- fc1 + gelu -> h bf16 [NROW][720] ----------------
__global__ __launch_bounds__(256) void k_fc1(const float* __restrict__ xo,
    const float* __restrict__ w, const float* __restrict__ bias,
    __hip_bfloat16* __restrict__ hbuf){
  __shared__ float A[6120], Wl[6120];
  __shared__ float outl[4352];
  int blk = blockIdx.x, tid = threadIdx.x;
  int r0 = blk*64;
  int pg = tid & 15, cg = tid >> 4;
  for (int cc = 0; cc < 12; ++cc) {
    int c0 = cc*64;
    float acc[4][4] = {};
    for (int kt = 0; kt < 2; ++kt) {
      int k0 = kt*90;
      for (int idx = tid; idx < 5760; idx += 256) {
        int i = idx/90, k = idx - i*90;
        A[k*68 + i] = xo[(size_t)(r0 + i)*180 + k0 + k];
      }
      for (int idx = tid; idx < 5760; idx += 256) {
        int ci = idx/90, k = idx - ci*90;
        int c = c0 + ci;
        Wl[k*68 + ci] = (c < 720) ? w[c*180 + k0 + k] : 0.f;
      }
      __syncthreads();
      #pragma unroll 6
      for (int kk = 0; kk < 90; ++kk)
        fma16(acc, *(const float4*)(A + kk*68 + 4*pg), *(const float4*)(Wl + kk*68 + 4*cg));
      __syncthreads();
    }
    #pragma unroll
    for (int i = 0; i < 4; ++i)
      #pragma unroll
      for (int j = 0; j < 4; ++j)
        outl[(4*pg+i)*68 + 4*cg + j] = acc[i][j];
    __syncthreads();
    for (int idx = tid; idx < 4096; idx += 256) {
      int r = idx >> 6, ci = idx & 63;
      int c = c0 + ci;
      if (c < 720)
        hbuf[(size_t)(r0 + r)*720 + c] = __float2bfloat16(geluf(outl[r*68 + ci] + bias[c]));
    }
    __syncthreads();
  }
}

// ---------------- fc2 + norm2 LN + residual -> d_out ----------------
__global__ __launch_bounds__(256) void k_fc2(const __hip_bfloat16* __restrict__ hbuf,
    const float* __restrict__ w, const float* __restrict__ bias,
    const float* __restrict__ g2, const float* __restrict__ b2,
    float* __restrict__ outp){
  __shared__ float A[6120], Wl[6120];
  __shared__ float outl[11840];
  __shared__ float mArr[64], rsArr[64];
  int blk = blockIdx.x, tid = threadIdx.x;
  int r0 = blk*64;
  int pg = tid & 15, cg = tid >> 4;
  for (int cc = 0; cc < 3; ++cc) {
    int c0 = cc*64;
    float acc[4][4] = {};
    for (int kt = 0; kt < 8; ++kt) {
      int k0 = kt*90;
      for (int idx = tid; idx < 5760; idx += 256) {
        int i = idx/90, k = idx - i*90;
        A[k*68 + i] = __bfloat162float(hbuf[(size_t)(r0 + i)*720 + k0 + k]);
      }
      for (int idx = tid; idx < 5760; idx += 256) {
        int ci = idx/90, k = idx - ci*90;
        int c = c0 + ci;
        Wl[k*68 + ci] = (c < 180) ? w[c*720 + k0 + k] : 0.f;
      }
      __syncthreads();
      #pragma unroll 6
      for (int kk = 0; kk < 90; ++kk)
        fma16(acc, *(const float4*)(A + kk*68 + 4*pg), *(const float4*)(Wl + kk*68 + 4*cg));
      __syncthreads();
    }
    #pragma unroll
    for (int i = 0; i < 4; ++i)
      #pragma unroll
      for (int j = 0; j < 4; ++j) {
        int c = c0 + 4*cg + j;
        if (c < 180) outl[(4*pg+i)*185 + c] = acc[i][j] + bias[c];
      }
  }
  __syncthreads();
  if (tid < 64) {
    float s = 0.f;
    for (int c = 0; c < 180; ++c) s += outl[tid*185 + c];
    float m = s*(1.f/180.f);
    float v = 0.f;
    for (int c = 0; c < 180; ++c) { float d = outl[tid*185 + c] - m; v += d*d; }
    mArr[tid] = m; rsArr[tid] = rsqrtf(v*(1.f/180.f) + 1e-5f);
  }
  __syncthreads();
  for (int idx = tid; idx < 11520; idx += 256) {
    int r = idx/180, c = idx - r*180;
    size_t o = (size_t)(r0 + r)*180 + c;
    outp[o] = outp[o] + (outl[r*185 + c] - mArr[r])*rsArr[r]*g2[c] + b2[c];
  }
}

// ---------------- launch ----------------
extern "C" void kernel_launch(void* const* d_in, const int* in_sizes, int n_in,
                              void* d_out, int out_size, void* d_ws, size_t ws_size,
                              hipStream_t stream) {
  const float* x      = (const float*)d_in[0];
  const float* qkv_w  = (const float*)d_in[1];
  const float* q_bias = (const float*)d_in[2];
  const float* v_bias = (const float*)d_in[3];
  const float* lsc    = (const float*)d_in[4];
  const float* cpb_w1 = (const float*)d_in[5];
  const float* cpb_b1 = (const float*)d_in[6];
  const float* cpb_w2 = (const float*)d_in[7];
  const float* proj_w = (const float*)d_in[8];
  const float* proj_b = (const float*)d_in[9];
  const float* n1g    = (const float*)d_in[10];
  const float* n1b    = (const float*)d_in[11];
  const float* n2g    = (const float*)d_in[12];
  const float* n2b    = (const float*)d_in[13];
  const float* fc1w   = (const float*)d_in[14];
  const float* fc1b   = (const float*)d_in[15];
  const float* fc2w   = (const float*)d_in[16];
  const float* fc2b   = (const float*)d_in[17];
  const float* p1w    = (const float*)d_in[18];
  const float* p1b    = (const float*)d_in[19];
  const float* pww    = (const float*)d_in[20];
  const float* pwb    = (const float*)d_in[21];
  const float* dww    = (const float*)d_in[22];
  const float* dwb    = (const float*)d_in[23];
  const float* ddw    = (const float*)d_in[24];
  const float* ddb    = (const float*)d_in[25];
  const float* p2w    = (const float*)d_in[26];
  const float* p2b    = (const float*)d_in[27];
  const float* vlng   = (const float*)d_in[28];
  const float* vlnb   = (const float*)d_in[29];
  const float* cbw    = (const float*)d_in[30];
  const float* cbb    = (const float*)d_in[31];
  const float* pew    = (const float*)d_in[32];
  const float* peb    = (const float*)d_in[33];
  float* out = (float*)d_out;
  char* ws = (char*)d_ws;

  __hip_bfloat16* qkv  = (__hip_bfloat16*)(ws + OFF_QKV);
  float* awin  = (float*)(ws + OFF_AWIN);
  float* x1    = (float*)(ws + OFF_X1);
  float* tbl   = (float*)(ws + OFF_TBL);
  float* biasA = (float*)(ws + OFF_BIASA);
  float* cwt   = (float*)(ws + OFF_CWT);
  float* v1    = (float*)(ws + OFF_V1);
  float* ab1   = (float*)(ws + OFF_AB1);
  float* ab2   = (float*)(ws + OFF_AB2);
  float* v2    = (float*)(ws + OFF_V2);
  float* vn    = (float*)(ws + OFF_VN);
  float* cbv   = (float*)(ws + OFF_CB);
  __hip_bfloat16* hbuf = (__hip_bfloat16*)(ws + OFF_H);

  k_cpb_tbl<<<225, 512, 0, stream>>>(cpb_w1, cpb_b1, cpb_w2, tbl);
  k_cpb_bias<<<96, 256, 0, stream>>>(tbl, biasA);
  k_qkv<<<NWIN, 256, 0, stream>>>(x, qkv_w, q_bias, v_bias, qkv);
  k_attn<<<NWIN*6, 256, 0, stream>>>(qkv, biasA, lsc, awin);
  k_proj<<<NWIN, 256, 0, stream>>>(awin, proj_w, proj_b, n1g, n1b, x, x1);
  k_p1<<<NWIN, 256, 0, stream>>>(x1, p1w, p1b, v1);
  k_pw<<<NWIN, 256, 0, stream>>>(v1, pww, pwb, ab1);
  k_dwc<<<27648, 256, 0, stream>>>(ab1, dww, dwb, ab2, 1);
  k_dwc<<<27648, 256, 0, stream>>>(ab2, ddw, ddb, ab1, 3);
  k_p2<<<NWIN, 256, 0, stream>>>(v1, ab1, x1, p2w, p2b, v2);
  k_ln_vab<<<288, 256, 0, stream>>>(v2, vlng, vlnb, vn);
  k_prep_cw<<<570, 256, 0, stream>>>(cbw, cwt);
  k_convbody<<<NWIN, 256, 0, stream>>>(vn, cwt, cbb, cbv);
  k_pe<<<NWIN, 256, 0, stream>>>(cbv, pew, peb, x1, out);
  k_fc1<<<NWIN, 256, 0, stream>>>(out, fc1w, fc1b, hbuf);
  k_fc2<<<NWIN, 256, 0, stream>>>(hbuf, fc2w, fc2b, n2g, n2b, out);
}

// Round 2
// 1439.507 us; speedup vs baseline: 3.4590x; 3.4590x over previous
//
#include <hip/hip_runtime.h>
#include <hip/hip_bf16.h>

#define DEV __device__ __forceinline__

typedef __attribute__((ext_vector_type(8))) short s8v;   // 8 bf16 (4 VGPR)
typedef __attribute__((ext_vector_type(4))) float f4v;   // MFMA acc

static constexpr int NWIN = 1152;
static constexpr int NROW = 73728;

// ---------------- workspace layout (peak < 185.8 MB, same cap as round 0) ----
static constexpr size_t OFF_QKV  = 0;            // bf16 [NROW][540]  (dead after attn)
static constexpr size_t OFF_AWIN = 79626240;     // bf16 [NROW][180]  (dead after proj)
static constexpr size_t OFF_X1   = 132710400;    // f32  [NROW][180]  (live until pe/p2)
static constexpr size_t OFF_V1   = 0;            // f32  NCHW [8*96][9216]
static constexpr size_t OFF_AB1  = 28311552;     // f32  NCHW
static constexpr size_t OFF_AB2  = 56623104;     // f32  NCHW
static constexpr size_t OFF_VNB  = 56623104;     // bf16 NHWC [NROW][192] (over ab2, dead)
static constexpr size_t OFF_CBN  = 0;            // bf16 NHWC [NROW][192] (over v1, dead)
static constexpr size_t OFF_H    = 0;            // bf16 [NROW][736]  (over conv temps, dead)
// weights in never-otherwise-used gap [130.6MB, 132.7MB)
static constexpr size_t WB       = 130613248;
static constexpr size_t O_TBL    = WB;                    // f32 [225][6]
static constexpr size_t O_BIASA  = WB + 8192;             // f32 [6][64][64]
static constexpr size_t O_WQ     = WB + 106496;           // bf16 [544][192]
static constexpr size_t O_WPJ    = O_WQ  + 208896;        // bf16 [192][192]
static constexpr size_t O_WPE    = O_WPJ + 73728;         // bf16 [192][192]
static constexpr size_t O_WP1    = O_WPE + 73728;         // bf16 [96][192]
static constexpr size_t O_WPW    = O_WP1 + 36864;         // bf16 [96][96]
static constexpr size_t O_WP2    = O_WPW + 18432;         // bf16 [192][96]
static constexpr size_t O_WF1    = O_WP2 + 36864;         // bf16 [736][192]
static constexpr size_t O_WF2    = O_WF1 + 282624;        // bf16 [192][736]
static constexpr size_t O_WCB    = O_WF2 + 282624;        // bf16 [18][96][96]

DEV float geluf(float x){ return 0.5f*x*(1.f + erff(x*0.70710678118654752f)); }

DEV unsigned short f2b(float v){
  union { __hip_bfloat16 h; unsigned short u; } x;
  x.h = __float2bfloat16(v);
  return x.u;
}

DEV f4v mfma16(s8v a, s8v b, f4v c){
  return __builtin_amdgcn_mfma_f32_16x16x32_bf16(a, b, c, 0, 0, 0);
}

DEV float rsum16(float v){
  v += __shfl_xor(v, 1); v += __shfl_xor(v, 2);
  v += __shfl_xor(v, 4); v += __shfl_xor(v, 8);
  return v;
}

DEV float qkvbias(int c, const float* qb, const float* vb){
  return (c < 180) ? qb[c] : (c < 360 ? 0.f : vb[c-360]);
}

// ---------------- CPB MLP table ----------------
__global__ __launch_bounds__(512) void k_cpb_tbl(const float* __restrict__ w1,
    const float* __restrict__ b1, const float* __restrict__ w2, float* __restrict__ tbl){
  int m = blockIdx.x, tid = threadIdx.x;
  int i = m/15, j = m - (m/15)*15;
  float t0 = (float)(i-7)*(8.f/7.f), t1 = (float)(j-7)*(8.f/7.f);
  float f0 = log2f(fabsf(t0)+1.f)*(1.f/3.f); if (t0 < 0.f) f0 = -f0;
  float f1 = log2f(fabsf(t1)+1.f)*(1.f/3.f); if (t1 < 0.f) f1 = -f1;
  float hv = fmaxf(f0*w1[2*tid] + f1*w1[2*tid+1] + b1[tid], 0.f);
  __shared__ float red[6][8];
  int lane = tid & 63, wv = tid >> 6;
  for (int h = 0; h < 6; ++h) {
    float p = hv * w2[h*512 + tid];
    for (int off = 32; off; off >>= 1) p += __shfl_down(p, off);
    if (lane == 0) red[h][wv] = p;
  }
  __syncthreads();
  if (tid < 6) {
    float s = 0.f;
    for (int w = 0; w < 8; ++w) s += red[tid][w];
    tbl[m*6 + tid] = s;
  }
}

__global__ __launch_bounds__(256) void k_cpb_bias(const float* __restrict__ tbl,
    float* __restrict__ biasA){
  int idx = blockIdx.x*256 + threadIdx.x;
  if (idx >= 6*64*64) return;
  int h = idx >> 12, n = (idx >> 6) & 63, m = idx & 63;
  int dh = (n>>3) - (m>>3) + 7, dw = (n&7) - (m&7) + 7;
  float v = tbl[(dh*15 + dw)*6 + h];
  biasA[idx] = 16.f / (1.f + expf(-v));
}

// ---------------- weight convert + pad ----------------
__global__ __launch_bounds__(256) void k_cvtpad(const float* __restrict__ src,
    unsigned short* __restrict__ dst, int R, int K, int Kp, int total){
  int idx = blockIdx.x*256 + threadIdx.x;
  if (idx >= total) return;
  int r = idx / Kp, k = idx - r*Kp;
  float v = (r < R && k < K) ? src[r*K + k] : 0.f;
  dst[idx] = f2b(v);
}

__global__ __launch_bounds__(256) void k_cvt_wcb(const float* __restrict__ cbw,
    unsigned short* __restrict__ dst){
  int idx = blockIdx.x*256 + threadIdx.x;
  if (idx >= 18*96*96) return;
  int row = idx/96, ci = idx - row*96;
  int g9 = row/96, o = row - g9*96;     // row = (gch*9+tap)*96 + o
  int gch = g9/9, tap = g9 - gch*9;
  float v = (o < 90 && ci < 90) ? cbw[((gch*90 + o)*90 + ci)*9 + tap] : 0.f;
  dst[idx] = f2b(v);
}

// ---------------- qkv: x(win-gathered) @ Wq^T -> qkv bf16 [NROW][540] --------
__global__ __launch_bounds__(256) void k_qkv_mfma(const float* __restrict__ x,
    const unsigned short* __restrict__ wq, const float* __restrict__ qb,
    const float* __restrict__ vb, unsigned short* __restrict__ qkv){
  __shared__ unsigned short A[64*200];
  __shared__ int rowOff[64];
  int win = blockIdx.x, tid = threadIdx.x;
  if (tid < 64) {
    int b = win/144, rem = win - b*144, wh = rem/12, ww = rem - (rem/12)*12;
    int l = (wh*8 + (tid>>3))*96 + ww*8 + (tid&7);
    rowOff[tid] = (b*9216 + l)*180;
  }
  __syncthreads();
  for (int idx = tid; idx < 64*192; idx += 256) {
    int i = idx/192, k = idx - i*192;
    A[i*200 + k] = (k < 180) ? f2b(x[rowOff[i] + k]) : (unsigned short)0;
  }
  __syncthreads();
  int wid = tid>>6, lane = tid&63, lr = lane&15, lg = lane>>4;
  const unsigned short* arow = A + (16*wid + lr)*200 + lg*8;
  for (int pp = 0; pp < 17; ++pp) {
    int c0 = pp*32;
    f4v acc0 = {0.f,0.f,0.f,0.f}, acc1 = {0.f,0.f,0.f,0.f};
    const unsigned short* b0p = wq + (size_t)(c0 + lr)*192 + lg*8;
    const unsigned short* b1p = b0p + 16*192;
    #pragma unroll
    for (int k0 = 0; k0 < 6; ++k0) {
      s8v a  = *(const s8v*)(arow + k0*32);
      s8v b0 = *(const s8v*)(b0p + k0*32);
      s8v b1 = *(const s8v*)(b1p + k0*32);
      acc0 = mfma16(a, b0, acc0);
      acc1 = mfma16(a, b1, acc1);
    }
    size_t rbase = (size_t)win*64 + 16*wid + lg*4;
    #pragma unroll
    for (int i = 0; i < 4; ++i) {
      size_t r = rbase + i;
      int c = c0 + lr;
      if (c < 540) qkv[r*540 + c] = f2b(acc0[i] + qkvbias(c, qb, vb));
      int c2 = c0 + 16 + lr;
      if (c2 < 540) qkv[r*540 + c2] = f2b(acc1[i] + qkvbias(c2, qb, vb));
    }
  }
}

// ---------------- attention per (window, head) -> awin bf16 [NROW][180] ------
__global__ __launch_bounds__(256) void k_attn(const __hip_bfloat16* __restrict__ qkv,
    const float* __restrict__ biasA, const float* __restrict__ lsc,
    __hip_bfloat16* __restrict__ awin){
  __shared__ float qs[2048], ks[2048], vs[2048];   // [64][32]
  __shared__ float ps[4416];                       // [64][69]
  int blk = blockIdx.x;
  int win = blk/6, h = blk - win*6;
  int tid = threadIdx.x;
  for (int idx = tid; idx < 2048; idx += 256) {
    int n = idx >> 5, d = idx & 31;
    float qv = 0.f, kv = 0.f, vv = 0.f;
    if (d < 30) {
      size_t row = (size_t)(win*64 + n)*540;
      qv = __bfloat162float(qkv[row + h*30 + d]);
      kv = __bfloat162float(qkv[row + 180 + h*30 + d]);
      vv = __bfloat162float(qkv[row + 360 + h*30 + d]);
    }
    qs[idx] = qv; ks[idx] = kv; vs[idx] = vv;
  }
  __syncthreads();
  if (tid < 128) {
    int n = tid & 63;
    float* base = (tid < 64) ? (qs + n*32) : (ks + n*32);
    float s = 0.f;
    for (int d = 0; d < 30; ++d) { float v = base[d]; s += v*v; }
    float inv = 1.f / fmaxf(sqrtf(s), 1e-12f);
    for (int d = 0; d < 30; ++d) base[d] *= inv;
  }
  __syncthreads();
  float scale = expf(fminf(lsc[h], 4.6051701859880914f));
  {
    int n = tid >> 2, q4 = tid & 3;
    float qreg[32];
    #pragma unroll
    for (int d = 0; d < 32; ++d) qreg[d] = qs[n*32 + d];
    float sc[16];
    #pragma unroll
    for (int mm = 0; mm < 16; ++mm) {
      int m = q4*16 + mm;
      float s = 0.f;
      #pragma unroll
      for (int d4 = 0; d4 < 8; ++d4) {
        float4 kv4 = *(const float4*)(ks + m*32 + d4*4);
        s += qreg[d4*4+0]*kv4.x + qreg[d4*4+1]*kv4.y + qreg[d4*4+2]*kv4.z + qreg[d4*4+3]*kv4.w;
      }
      sc[mm] = s*scale + biasA[((h*64 + n) << 6) + m];
    }
    float mx = -1e30f;
    #pragma unroll
    for (int mm = 0; mm < 16; ++mm) mx = fmaxf(mx, sc[mm]);
    mx = fmaxf(mx, __shfl_xor(mx, 1));
    mx = fmaxf(mx, __shfl_xor(mx, 2));
    float sum = 0.f;
    #pragma unroll
    for (int mm = 0; mm < 16; ++mm) { sc[mm] = expf(sc[mm] - mx); sum += sc[mm]; }
    sum += __shfl_xor(sum, 1);
    sum += __shfl_xor(sum, 2);
    float rinv = 1.f / sum;
    #pragma unroll
    for (int mm = 0; mm < 16; ++mm) ps[n*69 + q4*16 + mm] = sc[mm]*rinv;
  }
  __syncthreads();
  {
    int n = tid & 63, g = tid >> 6;
    float acc[8] = {};
    for (int m = 0; m < 64; ++m) {
      float p = ps[n*69 + m];
      float4 v0 = *(const float4*)(vs + m*32 + g*8);
      float4 v1 = *(const float4*)(vs + m*32 + g*8 + 4);
      acc[0] += p*v0.x; acc[1] += p*v0.y; acc[2] += p*v0.z; acc[3] += p*v0.w;
      acc[4] += p*v1.x; acc[5] += p*v1.y; acc[6] += p*v1.z; acc[7] += p*v1.w;
    }
    __syncthreads();
    #pragma unroll
    for (int k = 0; k < 8; ++k) qs[n*32 + g*8 + k] = acc[k];
  }
  __syncthreads();
  for (int idx = tid; idx < 1920; idx += 256) {
    int n = idx/30, d = idx - n*30;
    awin[(size_t)(win*64 + n)*180 + h*30 + d] = __float2bfloat16(qs[n*32 + d]);
  }
}

// ---------------- proj + norm1 LN (in-register) + residual + win-reverse -----
__global__ __launch_bounds__(256) void k_proj_mfma(const unsigned short* __restrict__ awin,
    const unsigned short* __restrict__ wpj, const float* __restrict__ pb,
    const float* __restrict__ g1, const float* __restrict__ b1,
    const float* __restrict__ x, float* __restrict__ x1){
  __shared__ unsigned short A[64*200];
  int win = blockIdx.x, tid = threadIdx.x;
  size_t rb = (size_t)win*64;
  for (int idx = tid; idx < 64*192; idx += 256) {
    int i = idx/192, k = idx - i*192;
    A[i*200 + k] = (k < 180) ? awin[(rb + i)*180 + k] : (unsigned short)0;
  }
  __syncthreads();
  int wid = tid>>6, lane = tid&63, lr = lane&15, lg = lane>>4;
  const unsigned short* arow = A + (16*wid + lr)*200 + lg*8;
  f4v z = {0.f,0.f,0.f,0.f};
  f4v acc[12];
  #pragma unroll
  for (int cc = 0; cc < 12; ++cc) acc[cc] = z;
  #pragma unroll
  for (int k0 = 0; k0 < 6; ++k0) {
    s8v a = *(const s8v*)(arow + k0*32);
    #pragma unroll
    for (int cc = 0; cc < 12; ++cc) {
      s8v b = *(const s8v*)(wpj + (size_t)(cc*16 + lr)*192 + k0*32 + lg*8);
      acc[cc] = mfma16(a, b, acc[cc]);
    }
  }
  float psum[4] = {0,0,0,0}, psq[4] = {0,0,0,0};
  #pragma unroll
  for (int cc = 0; cc < 12; ++cc) {
    int c = cc*16 + lr;
    float bias = (c < 180) ? pb[c] : 0.f;
    #pragma unroll
    for (int i = 0; i < 4; ++i) {
      float v = (c < 180) ? acc[cc][i] + bias : 0.f;
      acc[cc][i] = v;
      psum[i] += v; psq[i] += v*v;
    }
  }
  float m[4], rs[4];
  #pragma unroll
  for (int i = 0; i < 4; ++i) {
    float s = rsum16(psum[i]), s2 = rsum16(psq[i]);
    m[i] = s*(1.f/180.f);
    float var = fmaxf(s2*(1.f/180.f) - m[i]*m[i], 0.f);
    rs[i] = rsqrtf(var + 1e-5f);
  }
  int b = win/144, rem = win - b*144, wh = rem/12, ww = rem - (rem/12)*12;
  #pragma unroll
  for (int cc = 0; cc < 12; ++cc) {
    int c = cc*16 + lr;
    if (c < 180) {
      #pragma unroll
      for (int i = 0; i < 4; ++i) {
        int r = 16*wid + lg*4 + i;
        int l = (wh*8 + (r>>3))*96 + ww*8 + (r&7);
        size_t o = (size_t)(b*9216 + l)*180 + c;
        x1[o] = x[o] + (acc[cc][i] - m[i])*rs[i]*g1[c] + b1[c];
      }
    }
  }
}

// ---------------- VAB p1: x1 @ Wp1^T + gelu -> v1 NCHW f32 -------------------
__global__ __launch_bounds__(256) void k_p1_mfma(const float* __restrict__ x1,
    const unsigned short* __restrict__ wp1, const float* __restrict__ bias,
    float* __restrict__ v1){
  __shared__ unsigned short A[64*200];
  int blk = blockIdx.x, tid = threadIdx.x;
  int b = blk/144, p0 = (blk - b*144)*64;
  int rowb = b*9216 + p0;
  for (int idx = tid; idx < 64*192; idx += 256) {
    int i = idx/192, k = idx - i*192;
    A[i*200 + k] = (k < 180) ? f2b(x1[(size_t)(rowb + i)*180 + k]) : (unsigned short)0;
  }
  __syncthreads();
  int wid = tid>>6, lane = tid&63, lr = lane&15, lg = lane>>4;
  const unsigned short* arow = A + (16*wid + lr)*200 + lg*8;
  #pragma unroll
  for (int pp = 0; pp < 3; ++pp) {
    int c0 = pp*32;
    f4v acc0 = {0.f,0.f,0.f,0.f}, acc1 = {0.f,0.f,0.f,0.f};
    #pragma unroll
    for (int k0 = 0; k0 < 6; ++k0) {
      s8v a  = *(const s8v*)(arow + k0*32);
      s8v b0 = *(const s8v*)(wp1 + (size_t)(c0 + lr)*192 + k0*32 + lg*8);
      s8v b1 = *(const s8v*)(wp1 + (size_t)(c0 + 16 + lr)*192 + k0*32 + lg*8);
      acc0 = mfma16(a, b0, acc0);
      acc1 = mfma16(a, b1, acc1);
    }
    int c  = c0 + lr, c2 = c0 + 16 + lr;
    float bv = bias[c], bv2 = bias[c2];
    #pragma unroll
    for (int i = 0; i < 4; ++i) {
      int px = 16*wid + lg*4 + i;
      v1[(size_t)(b*96 + c )*9216 + p0 + px] = geluf(acc0[i] + bv );
      v1[(size_t)(b*96 + c2)*9216 + p0 + px] = geluf(acc1[i] + bv2);
    }
  }
}

// ---------------- VAB pw: v1 @ Wpw^T -> ab1 NCHW f32 -------------------------
__global__ __launch_bounds__(256) void k_pw_mfma(const float* __restrict__ v1,
    const unsigned short* __restrict__ wpw, const float* __restrict__ bias,
    float* __restrict__ outp){
  __shared__ unsigned short A[64*104];
  int blk = blockIdx.x, tid = threadIdx.x;
  int b = blk/144, p0 = (blk - b*144)*64;
  for (int idx = tid; idx < 96*64; idx += 256) {
    int k = idx >> 6, i = idx & 63;
    A[i*104 + k] = f2b(v1[(size_t)(b*96 + k)*9216 + p0 + i]);
  }
  __syncthreads();
  int wid = tid>>6, lane = tid&63, lr = lane&15, lg = lane>>4;
  const unsigned short* arow = A + (16*wid + lr)*104 + lg*8;
  #pragma unroll
  for (int pp = 0; pp < 3; ++pp) {
    int c0 = pp*32;
    f4v acc0 = {0.f,0.f,0.f,0.f}, acc1 = {0.f,0.f,0.f,0.f};
    #pragma unroll
    for (int k0 = 0; k0 < 3; ++k0) {
      s8v a  = *(const s8v*)(arow + k0*32);
      s8v b0 = *(const s8v*)(wpw + (size_t)(c0 + lr)*96 + k0*32 + lg*8);
      s8v b1 = *(const s8v*)(wpw + (size_t)(c0 + 16 + lr)*96 + k0*32 + lg*8);
      acc0 = mfma16(a, b0, acc0);
      acc1 = mfma16(a, b1, acc1);
    }
    int c  = c0 + lr, c2 = c0 + 16 + lr;
    float bv = bias[c], bv2 = bias[c2];
    #pragma unroll
    for (int i = 0; i < 4; ++i) {
      int px = 16*wid + lg*4 + i;
      outp[(size_t)(b*96 + c )*9216 + p0 + px] = acc0[i] + bv;
      outp[(size_t)(b*96 + c2)*9216 + p0 + px] = acc1[i] + bv2;
    }
  }
}

// ---------------- depthwise 5x5 (dil=1 pad2 / dil=3 pad6) --------------------
__global__ __launch_bounds__(256) void k_dwc(const float* __restrict__ in,
    const float* __restrict__ w, const float* __restrict__ bias,
    float* __restrict__ out, int dil){
  int blk = blockIdx.x, tid = threadIdx.x;
  int bc = blk/36, pc = blk - bc*36;
  int c = bc - (bc/96)*96;
  int p = pc*256 + tid;
  int hh = p/96, ww = p - hh*96;
  float acc = bias[c];
  const float* wc = w + c*25;
  const float* inb = in + (size_t)bc*9216;
  #pragma unroll
  for (int i = 0; i < 5; ++i) {
    int y = hh + dil*(i-2);
    if (y < 0 || y >= 96) continue;
    #pragma unroll
    for (int j = 0; j < 5; ++j) {
      int xq = ww + dil*(j-2);
      if (xq >= 0 && xq < 96) acc += inb[y*96 + xq]*wc[i*5 + j];
    }
  }
  out[(size_t)bc*9216 + p] = acc;
}

// ---------------- p2 + residual + VAB-LN (fused) -> vnb NHWC bf16 [NROW][192] -
__global__ __launch_bounds__(256) void k_p2ln_mfma(const float* __restrict__ v1,
    const float* __restrict__ a3, const float* __restrict__ x1,
    const unsigned short* __restrict__ wp2, const float* __restrict__ bias,
    const float* __restrict__ lng, const float* __restrict__ lnb,
    unsigned short* __restrict__ vnb){
  __shared__ unsigned short A[64*104];
  int blk = blockIdx.x, tid = threadIdx.x;
  int b = blk/144, p0 = (blk - b*144)*64;
  for (int idx = tid; idx < 96*64; idx += 256) {
    int k = idx >> 6, i = idx & 63;
    size_t o = (size_t)(b*96 + k)*9216 + p0 + i;
    A[i*104 + k] = f2b(v1[o]*a3[o]);
  }
  __syncthreads();
  int wid = tid>>6, lane = tid&63, lr = lane&15, lg = lane>>4;
  const unsigned short* arow = A + (16*wid + lr)*104 + lg*8;
  f4v z = {0.f,0.f,0.f,0.f};
  f4v acc[12];
  #pragma unroll
  for (int cc = 0; cc < 12; ++cc) acc[cc] = z;
  #pragma unroll
  for (int k0 = 0; k0 < 3; ++k0) {
    s8v a = *(const s8v*)(arow + k0*32);
    #pragma unroll
    for (int cc = 0; cc < 12; ++cc) {
      s8v bb = *(const s8v*)(wp2 + (size_t)(cc*16 + lr)*96 + k0*32 + lg*8);
      acc[cc] = mfma16(a, bb, acc[cc]);
    }
  }
  float psum[4] = {0,0,0,0}, psq[4] = {0,0,0,0};
  #pragma unroll
  for (int cc = 0; cc < 12; ++cc) {
    int c = cc*16 + lr;
    float bv = (c < 180) ? bias[c] : 0.f;
    #pragma unroll
    for (int i = 0; i < 4; ++i) {
      int px = 16*wid + lg*4 + i;
      float v = 0.f;
      if (c < 180) v = acc[cc][i] + bv + x1[(size_t)(b*9216 + p0 + px)*180 + c];
      acc[cc][i] = v;
      psum[i] += v; psq[i] += v*v;
    }
  }
  float m[4], rs[4];
  #pragma unroll
  for (int i = 0; i < 4; ++i) {
    float s = rsum16(psum[i]), s2 = rsum16(psq[i]);
    m[i] = s*(1.f/180.f);
    float var = fmaxf(s2*(1.f/180.f) - m[i]*m[i], 0.f);
    rs[i] = rsqrtf(var + 1e-5f);
  }
  #pragma unroll
  for (int cc = 0; cc < 12; ++cc) {
    int c = cc*16 + lr;
    if (c < 180) {
      #pragma unroll
      for (int i = 0; i < 4; ++i) {
        int px = 16*wid + lg*4 + i;
        vnb[(size_t)(b*9216 + p0 + px)*192 + c] =
            f2b((acc[cc][i] - m[i])*rs[i]*lng[c] + lnb[c]);
      }
    }
  }
  for (int idx = tid; idx < 64*12; idx += 256) {
    int px = idx/12, j = idx - (idx/12)*12;
    vnb[(size_t)(b*9216 + p0 + px)*192 + 180 + j] = 0;
  }
}

// ---------------- convbody: grouped 3x3 as 9 shifted MFMA-GEMMs -> cbn NHWC --
__global__ __launch_bounds__(256) void k_cb_mfma(const unsigned short* __restrict__ vnb,
    const unsigned short* __restrict__ wcb, const float* __restrict__ bias,
    unsigned short* __restrict__ cbn){
  __shared__ unsigned short A[64*104];
  int blk = blockIdx.x, tid = threadIdx.x;
  int b = blk/144, p0 = (blk - b*144)*64;
  int wid = tid>>6, lane = tid&63, lr = lane&15, lg = lane>>4;
  for (int gch = 0; gch < 2; ++gch) {
    f4v z = {0.f,0.f,0.f,0.f};
    f4v acc[6];
    #pragma unroll
    for (int cc = 0; cc < 6; ++cc) acc[cc] = z;
    for (int tap = 0; tap < 9; ++tap) {
      int dh = tap/3 - 1, dw = tap - (tap/3)*3 - 1;
      __syncthreads();
      for (int idx = tid; idx < 64*96; idx += 256) {
        int i = idx/96, k = idx - i*96;
        int p = p0 + i;
        int hh = p/96 + dh, ww = (p - (p/96)*96) + dw;
        unsigned short val = 0;
        if (k < 90 && hh >= 0 && hh < 96 && ww >= 0 && ww < 96)
          val = vnb[(size_t)(b*9216 + hh*96 + ww)*192 + gch*90 + k];
        A[i*104 + k] = val;
      }
      __syncthreads();
      const unsigned short* wb = wcb + (size_t)(gch*9 + tap)*96*96;
      const unsigned short* arow = A + (16*wid + lr)*104 + lg*8;
      #pragma unroll
      for (int k0 = 0; k0 < 3; ++k0) {
        s8v a = *(const s8v*)(arow + k0*32);
        #pragma unroll
        for (int cc = 0; cc < 6; ++cc) {
          s8v bb = *(const s8v*)(wb + (size_t)(cc*16 + lr)*96 + k0*32 + lg*8);
          acc[cc] = mfma16(a, bb, acc[cc]);
        }
      }
    }
    #pragma unroll
    for (int cc = 0; cc < 6; ++cc) {
      int c = cc*16 + lr;
      if (c < 90) {
        int o = gch*90 + c;
        float bv = bias[o];
        #pragma unroll
        for (int i = 0; i < 4; ++i) {
          int px = 16*wid + lg*4 + i;
          cbn[(size_t)(b*9216 + p0 + px)*192 + o] = f2b(acc[cc][i] + bv);
        }
      }
    }
  }
  for (int idx = tid; idx < 64*12; idx += 256) {
    int px = idx/12, j = idx - (idx/12)*12;
    cbn[(size_t)(b*9216 + p0 + px)*192 + 180 + j] = 0;
  }
}

// ---------------- pe: cbn @ Wpe^T + x1 residual -> d_out f32 -----------------
__global__ __launch_bounds__(256) void k_pe_mfma(const unsigned short* __restrict__ cbn,
    const unsigned short* __restrict__ wpe, const float* __restrict__ bias,
    const float* __restrict__ x1, float* __restrict__ outp){
  __shared__ unsigned short A[64*200];
  int blk = blockIdx.x, tid = threadIdx.x;
  int b = blk/144, p0 = (blk - b*144)*64;
  for (int idx = tid; idx < 64*192; idx += 256) {
    int i = idx/192, k = idx - i*192;
    A[i*200 + k] = cbn[(size_t)(b*9216 + p0 + i)*192 + k];
  }
  __syncthreads();
  int wid = tid>>6, lane = tid&63, lr = lane&15, lg = lane>>4;
  const unsigned short* arow = A + (16*wid + lr)*200 + lg*8;
  #pragma unroll
  for (int pp = 0; pp < 6; ++pp) {
    int c0 = pp*32;
    f4v acc0 = {0.f,0.f,0.f,0.f}, acc1 = {0.f,0.f,0.f,0.f};
    #pragma unroll
    for (int k0 = 0; k0 < 6; ++k0) {
      s8v a  = *(const s8v*)(arow + k0*32);
      s8v b0 = *(const s8v*)(wpe + (size_t)(c0 + lr)*192 + k0*32 + lg*8);
      s8v b1 = *(const s8v*)(wpe + (size_t)(c0 + 16 + lr)*192 + k0*32 + lg*8);
      acc0 = mfma16(a, b0, acc0);
      acc1 = mfma16(a, b1, acc1);
    }
    #pragma unroll
    for (int i = 0; i < 4; ++i) {
      int px = 16*wid + lg*4 + i;
      size_t rowo = (size_t)(b*9216 + p0 + px)*180;
      int c = c0 + lr;
      if (c < 180) outp[rowo + c] = x1[rowo + c] + acc0[i] + bias[c];
      int c2 = c0 + 16 + lr;
      if (c2 < 180) outp[rowo + c2] = x1[rowo + c2] + acc1[i] + bias[c2];
    }
  }
}

// ---------------- fc1 + gelu -> hbuf bf16 [NROW][736] (zero-padded) ----------
__global__ __launch_bounds__(256) void k_fc1_mfma(const float* __restrict__ xo,
    const unsigned short* __restrict__ wf1, const float* __restrict__ bias,
    unsigned short* __restrict__ hbuf){
  __shared__ unsigned short A[64*200];
  int blk = blockIdx.x, tid = threadIdx.x;
  int r0 = blk*64;
  for (int idx = tid; idx < 64*192; idx += 256) {
    int i = idx/192, k = idx - i*192;
    A[i*200 + k] = (k < 180) ? f2b(xo[(size_t)(r0 + i)*180 + k]) : (unsigned short)0;
  }
  __syncthreads();
  int wid = tid>>6, lane = tid&63, lr = lane&15, lg = lane>>4;
  const unsigned short* arow = A + (16*wid + lr)*200 + lg*8;
  for (int pp = 0; pp < 23; ++pp) {
    int c0 = pp*32;
    f4v acc0 = {0.f,0.f,0.f,0.f}, acc1 = {0.f,0.f,0.f,0.f};
    #pragma unroll
    for (int k0 = 0; k0 < 6; ++k0) {
      s8v a  = *(const s8v*)(arow + k0*32);
      s8v b0 = *(const s8v*)(wf1 + (size_t)(c0 + lr)*192 + k0*32 + lg*8);
      s8v b1 = *(const s8v*)(wf1 + (size_t)(c0 + 16 + lr)*192 + k0*32 + lg*8);
      acc0 = mfma16(a, b0, acc0);
      acc1 = mfma16(a, b1, acc1);
    }
    int c  = c0 + lr, c2 = c0 + 16 + lr;
    #pragma unroll
    for (int i = 0; i < 4; ++i) {
      size_t r = (size_t)r0 + 16*wid + lg*4 + i;
      hbuf[r*736 + c ] = (c  < 720) ? f2b(geluf(acc0[i] + bias[c ])) : (unsigned short)0;
      hbuf[r*736 + c2] = (c2 < 720) ? f2b(geluf(acc1[i] + bias[c2])) : (unsigned short)0;
    }
  }
}

// ---------------- fc2 + norm2 LN (in-register) + residual -> d_out -----------
__global__ __launch_bounds__(256) void k_fc2_mfma(const unsigned short* __restrict__ hbuf,
    const unsigned short* __restrict__ wf2, const float* __restrict__ bias,
    const float* __restrict__ g2, const float* __restrict__ b2,
    float* __restrict__ outp){
  int blk = blockIdx.x, tid = threadIdx.x;
  int r0 = blk*64;
  int wid = tid>>6, lane = tid&63, lr = lane&15, lg = lane>>4;
  const unsigned short* arow = hbuf + (size_t)(r0 + 16*wid + lr)*736 + lg*8;
  f4v z = {0.f,0.f,0.f,0.f};
  f4v acc[12];
  #pragma unroll
  for (int cc = 0; cc < 12; ++cc) acc[cc] = z;
  for (int k0 = 0; k0 < 23; ++k0) {
    s8v a = *(const s8v*)(arow + k0*32);
    #pragma unroll
    for (int cc = 0; cc < 12; ++cc) {
      s8v b = *(const s8v*)(wf2 + (size_t)(cc*16 + lr)*736 + k0*32 + lg*8);
      acc[cc] = mfma16(a, b, acc[cc]);
    }
  }
  float psum[4] = {0,0,0,0}, psq[4] = {0,0,0,0};
  #pragma unroll
  for (int cc = 0; cc < 12; ++cc) {
    int c = cc*16 + lr;
    float bv = (c < 180) ? bias[c] : 0.f;
    #pragma unroll
    for (int i = 0; i < 4; ++i) {
      float v = (c < 180) ? acc[cc][i] + bv : 0.f;
      acc[cc][i] = v;
      psum[i] += v; psq[i] += v*v;
    }
  }
  float m[4], rs[4];
  #pragma unroll
  for (int i = 0; i < 4; ++i) {
    float s = rsum16(psum[i]), s2 = rsum16(psq[i]);
    m[i] = s*(1.f/180.f);
    float var = fmaxf(s2*(1.f/180.f) - m[i]*m[i], 0.f);
    rs[i] = rsqrtf(var + 1e-5f);
  }
  #pragma unroll
  for (int cc = 0; cc < 12; ++cc) {
    int c = cc*16 + lr;
    if (c < 180) {
      #pragma unroll
      for (int i = 0; i < 4; ++i) {
        size_t o = (size_t)(r0 + 16*wid + lg*4 + i)*180 + c;
        outp[o] = outp[o] + (acc[cc][i] - m[i])*rs[i]*g2[c] + b2[c];
      }
    }
  }
}

// ---------------- launch ----------------
extern "C" void kernel_launch(void* const* d_in, const int* in_sizes, int n_in,
                              void* d_out, int out_size, void* d_ws, size_t ws_size,
                              hipStream_t stream) {
  const float* x      = (const float*)d_in[0];
  const float* qkv_w  = (const float*)d_in[1];
  const float* q_bias = (const float*)d_in[2];
  const float* v_bias = (const float*)d_in[3];
  const float* lsc    = (const float*)d_in[4];
  const float* cpb_w1 = (const float*)d_in[5];
  const float* cpb_b1 = (const float*)d_in[6];
  const float* cpb_w2 = (const float*)d_in[7];
  const float* proj_w = (const float*)d_in[8];
  const float* proj_b = (const float*)d_in[9];
  const float* n1g    = (const float*)d_in[10];
  const float* n1b    = (const float*)d_in[11];
  const float* n2g    = (const float*)d_in[12];
  const float* n2b    = (const float*)d_in[13];
  const float* fc1w   = (const float*)d_in[14];
  const float* fc1b   = (const float*)d_in[15];
  const float* fc2w   = (const float*)d_in[16];
  const float* fc2b   = (const float*)d_in[17];
  const float* p1w    = (const float*)d_in[18];
  const float* p1b    = (const float*)d_in[19];
  const float* pww    = (const float*)d_in[20];
  const float* pwb    = (const float*)d_in[21];
  const float* dww    = (const float*)d_in[22];
  const float* dwb    = (const float*)d_in[23];
  const float* ddw    = (const float*)d_in[24];
  const float* ddb    = (const float*)d_in[25];
  const float* p2w    = (const float*)d_in[26];
  const float* p2b    = (const float*)d_in[27];
  const float* vlng   = (const float*)d_in[28];
  const float* vlnb   = (const float*)d_in[29];
  const float* cbw    = (const float*)d_in[30];
  const float* cbb    = (const float*)d_in[31];
  const float* pew    = (const float*)d_in[32];
  const float* peb    = (const float*)d_in[33];
  float* out = (float*)d_out;
  char* ws = (char*)d_ws;

  unsigned short* qkv  = (unsigned short*)(ws + OFF_QKV);
  unsigned short* awin = (unsigned short*)(ws + OFF_AWIN);
  float* x1   = (float*)(ws + OFF_X1);
  float* v1   = (float*)(ws + OFF_V1);
  float* ab1  = (float*)(ws + OFF_AB1);
  float* ab2  = (float*)(ws + OFF_AB2);
  unsigned short* vnb = (unsigned short*)(ws + OFF_VNB);
  unsigned short* cbn = (unsigned short*)(ws + OFF_CBN);
  unsigned short* hbf = (unsigned short*)(ws + OFF_H);
  float* tbl   = (float*)(ws + O_TBL);
  float* biasA = (float*)(ws + O_BIASA);
  unsigned short* wq  = (unsigned short*)(ws + O_WQ);
  unsigned short* wpj = (unsigned short*)(ws + O_WPJ);
  unsigned short* wpe = (unsigned short*)(ws + O_WPE);
  unsigned short* wp1 = (unsigned short*)(ws + O_WP1);
  unsigned short* wpw = (unsigned short*)(ws + O_WPW);
  unsigned short* wp2 = (unsigned short*)(ws + O_WP2);
  unsigned short* wf1 = (unsigned short*)(ws + O_WF1);
  unsigned short* wf2 = (unsigned short*)(ws + O_WF2);
  unsigned short* wcb = (unsigned short*)(ws + O_WCB);

  // prep
  k_cpb_tbl<<<225, 512, 0, stream>>>(cpb_w1, cpb_b1, cpb_w2, tbl);
  k_cpb_bias<<<96, 256, 0, stream>>>(tbl, biasA);
  k_cvtpad<<<(544*192+255)/256, 256, 0, stream>>>(qkv_w, wq, 540, 180, 192, 544*192);
  k_cvtpad<<<(192*192+255)/256, 256, 0, stream>>>(proj_w, wpj, 180, 180, 192, 192*192);
  k_cvtpad<<<(192*192+255)/256, 256, 0, stream>>>(pew, wpe, 180, 180, 192, 192*192);
  k_cvtpad<<<(96*192+255)/256, 256, 0, stream>>>(p1w, wp1, 96, 180, 192, 96*192);
  k_cvtpad<<<(96*96+255)/256, 256, 0, stream>>>(pww, wpw, 96, 96, 96, 96*96);
  k_cvtpad<<<(192*96+255)/256, 256, 0, stream>>>(p2w, wp2, 180, 96, 96, 192*96);
  k_cvtpad<<<(736*192+255)/256, 256, 0, stream>>>(fc1w, wf1, 720, 180, 192, 736*192);
  k_cvtpad<<<(192*736+255)/256, 256, 0, stream>>>(fc2w, wf2, 180, 720, 736, 192*736);
  k_cvt_wcb<<<(18*96*96+255)/256, 256, 0, stream>>>(cbw, wcb);
  // main chain
  k_qkv_mfma<<<NWIN, 256, 0, stream>>>(x, wq, q_bias, v_bias, qkv);
  k_attn<<<NWIN*6, 256, 0, stream>>>((const __hip_bfloat16*)qkv, biasA, lsc,
                                     (__hip_bfloat16*)awin);
  k_proj_mfma<<<NWIN, 256, 0, stream>>>(awin, wpj, proj_b, n1g, n1b, x, x1);
  k_p1_mfma<<<NWIN, 256, 0, stream>>>(x1, wp1, p1b, v1);
  k_pw_mfma<<<NWIN, 256, 0, stream>>>(v1, wpw, pwb, ab1);
  k_dwc<<<27648, 256, 0, stream>>>(ab1, dww, dwb, ab2, 1);
  k_dwc<<<27648, 256, 0, stream>>>(ab2, ddw, ddb, ab1, 3);
  k_p2ln_mfma<<<NWIN, 256, 0, stream>>>(v1, ab1, x1, wp2, p2b, vlng, vlnb, vnb);
  k_cb_mfma<<<NWIN, 256, 0, stream>>>(vnb, wcb, cbb, cbn);
  k_pe_mfma<<<NWIN, 256, 0, stream>>>(cbn, wpe, peb, x1, out);
  k_fc1_mfma<<<NWIN, 256, 0, stream>>>(out, wf1, fc1b, hbf);
  k_fc2_mfma<<<NWIN, 256, 0, stream>>>(hbf, wf2, fc2b, n2g, n2b, out);
}

// Round 3
// 1227.708 us; speedup vs baseline: 4.0557x; 1.1725x over previous
//
#include <hip/hip_runtime.h>
#include <hip/hip_bf16.h>

#define DEV __device__ __forceinline__

typedef __attribute__((ext_vector_type(8))) short s8v;   // 8 bf16 (4 VGPR)
typedef __attribute__((ext_vector_type(4))) float f4v;   // MFMA acc

static constexpr int NWIN = 1152;
static constexpr int NROW = 73728;

// ---------------- workspace layout (peak < 185.8 MB) ----
static constexpr size_t OFF_QKV  = 0;            // bf16 [NROW][540]  (dead after attn)
static constexpr size_t OFF_AWIN = 79626240;     // bf16 [NROW][180]  (dead after proj)
static constexpr size_t OFF_X1   = 132710400;    // f32  [NROW][180]  (live until pe/p2)
static constexpr size_t OFF_V1   = 0;            // f32  NCHW [8*96][9216]
static constexpr size_t OFF_AB1  = 28311552;     // f32  NCHW
static constexpr size_t OFF_AB2  = 56623104;     // f32  NCHW
static constexpr size_t OFF_VNB  = 56623104;     // bf16 NHWC [NROW][192] (over ab2, dead)
static constexpr size_t OFF_CBN  = 0;            // bf16 NHWC [NROW][192] (over v1, dead)
static constexpr size_t OFF_H    = 0;            // bf16 [NROW][736]  (over conv temps, dead)
static constexpr size_t WB       = 130613248;
static constexpr size_t O_TBL    = WB;                    // f32 [225][6]
static constexpr size_t O_BIASA  = WB + 8192;             // f32 [6][64][64]
static constexpr size_t O_WQ     = WB + 106496;           // bf16 [544][192]
static constexpr size_t O_WPJ    = O_WQ  + 208896;        // bf16 [192][192]
static constexpr size_t O_WPE    = O_WPJ + 73728;         // bf16 [192][192]
static constexpr size_t O_WP1    = O_WPE + 73728;         // bf16 [96][192]
static constexpr size_t O_WPW    = O_WP1 + 36864;         // bf16 [96][96]
static constexpr size_t O_WP2    = O_WPW + 18432;         // bf16 [192][96]
static constexpr size_t O_WF1    = O_WP2 + 36864;         // bf16 [736][192]
static constexpr size_t O_WF2    = O_WF1 + 282624;        // bf16 [192][736]
static constexpr size_t O_WCB    = O_WF2 + 282624;        // bf16 [18][96][96]

DEV float geluf(float x){ return 0.5f*x*(1.f + erff(x*0.70710678118654752f)); }

DEV unsigned short f2b(float v){
  union { __hip_bfloat16 h; unsigned short u; } x;
  x.h = __float2bfloat16(v);
  return x.u;
}

DEV float b2f(unsigned short u){
  union { float f; unsigned u; } x;
  x.u = ((unsigned)u) << 16;
  return x.f;
}

DEV f4v mfma16(s8v a, s8v b, f4v c){
  return __builtin_amdgcn_mfma_f32_16x16x32_bf16(a, b, c, 0, 0, 0);
}

DEV float rsum16(float v){
  v += __shfl_xor(v, 1); v += __shfl_xor(v, 2);
  v += __shfl_xor(v, 4); v += __shfl_xor(v, 8);
  return v;
}

DEV float rmax16(float v){
  v = fmaxf(v, __shfl_xor(v, 1)); v = fmaxf(v, __shfl_xor(v, 2));
  v = fmaxf(v, __shfl_xor(v, 4)); v = fmaxf(v, __shfl_xor(v, 8));
  return v;
}

DEV float qkvbias(int c, const float* qb, const float* vb){
  return (c < 180) ? qb[c] : (c < 360 ? 0.f : vb[c-360]);
}

// ---------------- CPB MLP table ----------------
__global__ __launch_bounds__(512) void k_cpb_tbl(const float* __restrict__ w1,
    const float* __restrict__ b1, const float* __restrict__ w2, float* __restrict__ tbl){
  int m = blockIdx.x, tid = threadIdx.x;
  int i = m/15, j = m - (m/15)*15;
  float t0 = (float)(i-7)*(8.f/7.f), t1 = (float)(j-7)*(8.f/7.f);
  float f0 = log2f(fabsf(t0)+1.f)*(1.f/3.f); if (t0 < 0.f) f0 = -f0;
  float f1 = log2f(fabsf(t1)+1.f)*(1.f/3.f); if (t1 < 0.f) f1 = -f1;
  float hv = fmaxf(f0*w1[2*tid] + f1*w1[2*tid+1] + b1[tid], 0.f);
  __shared__ float red[6][8];
  int lane = tid & 63, wv = tid >> 6;
  for (int h = 0; h < 6; ++h) {
    float p = hv * w2[h*512 + tid];
    for (int off = 32; off; off >>= 1) p += __shfl_down(p, off);
    if (lane == 0) red[h][wv] = p;
  }
  __syncthreads();
  if (tid < 6) {
    float s = 0.f;
    for (int w = 0; w < 8; ++w) s += red[tid][w];
    tbl[m*6 + tid] = s;
  }
}

__global__ __launch_bounds__(256) void k_cpb_bias(const float* __restrict__ tbl,
    float* __restrict__ biasA){
  int idx = blockIdx.x*256 + threadIdx.x;
  if (idx >= 6*64*64) return;
  int h = idx >> 12, n = (idx >> 6) & 63, m = idx & 63;
  int dh = (n>>3) - (m>>3) + 7, dw = (n&7) - (m&7) + 7;
  float v = tbl[(dh*15 + dw)*6 + h];
  biasA[idx] = 16.f / (1.f + expf(-v));
}

// ---------------- weight convert + pad ----------------
__global__ __launch_bounds__(256) void k_cvtpad(const float* __restrict__ src,
    unsigned short* __restrict__ dst, int R, int K, int Kp, int total){
  int idx = blockIdx.x*256 + threadIdx.x;
  if (idx >= total) return;
  int r = idx / Kp, k = idx - r*Kp;
  float v = (r < R && k < K) ? src[r*K + k] : 0.f;
  dst[idx] = f2b(v);
}

__global__ __launch_bounds__(256) void k_cvt_wcb(const float* __restrict__ cbw,
    unsigned short* __restrict__ dst){
  int idx = blockIdx.x*256 + threadIdx.x;
  if (idx >= 18*96*96) return;
  int row = idx/96, ci = idx - row*96;
  int g9 = row/96, o = row - g9*96;
  int gch = g9/9, tap = g9 - gch*9;
  float v = (o < 90 && ci < 90) ? cbw[((gch*90 + o)*90 + ci)*9 + tap] : 0.f;
  dst[idx] = f2b(v);
}

// ---------------- qkv: x(win-gathered) @ Wq^T -> qkv bf16 [NROW][540] --------
__global__ __launch_bounds__(256) void k_qkv_mfma(const float* __restrict__ x,
    const unsigned short* __restrict__ wq, const float* __restrict__ qb,
    const float* __restrict__ vb, unsigned short* __restrict__ qkv){
  __shared__ unsigned short A[64*200];
  __shared__ int rowOff[64];
  int win = blockIdx.x, tid = threadIdx.x;
  if (tid < 64) {
    int b = win/144, rem = win - b*144, wh = rem/12, ww = rem - (rem/12)*12;
    int l = (wh*8 + (tid>>3))*96 + ww*8 + (tid&7);
    rowOff[tid] = (b*9216 + l)*180;
  }
  __syncthreads();
  for (int idx = tid; idx < 64*192; idx += 256) {
    int i = idx/192, k = idx - i*192;
    A[i*200 + k] = (k < 180) ? f2b(x[rowOff[i] + k]) : (unsigned short)0;
  }
  __syncthreads();
  int wid = tid>>6, lane = tid&63, lr = lane&15, lg = lane>>4;
  const unsigned short* arow = A + (16*wid + lr)*200 + lg*8;
  for (int pp = 0; pp < 17; ++pp) {
    int c0 = pp*32;
    f4v acc0 = {0.f,0.f,0.f,0.f}, acc1 = {0.f,0.f,0.f,0.f};
    const unsigned short* b0p = wq + (size_t)(c0 + lr)*192 + lg*8;
    const unsigned short* b1p = b0p + 16*192;
    #pragma unroll
    for (int k0 = 0; k0 < 6; ++k0) {
      s8v a  = *(const s8v*)(arow + k0*32);
      s8v b0 = *(const s8v*)(b0p + k0*32);
      s8v b1 = *(const s8v*)(b1p + k0*32);
      acc0 = mfma16(a, b0, acc0);
      acc1 = mfma16(a, b1, acc1);
    }
    size_t rbase = (size_t)win*64 + 16*wid + lg*4;
    #pragma unroll
    for (int i = 0; i < 4; ++i) {
      size_t r = rbase + i;
      int c = c0 + lr;
      if (c < 540) qkv[r*540 + c] = f2b(acc0[i] + qkvbias(c, qb, vb));
      int c2 = c0 + 16 + lr;
      if (c2 < 540) qkv[r*540 + c2] = f2b(acc1[i] + qkvbias(c2, qb, vb));
    }
  }
}

// ---------------- attention (MFMA) per (window, head) -> awin bf16 -----------
// S = (q.k) * invq[n] * invk[m] * scale + bias;  P = softmax(S);  O = P V
__global__ __launch_bounds__(256) void k_attn_mfma(const unsigned short* __restrict__ qkv,
    const float* __restrict__ biasA, const float* __restrict__ lsc,
    unsigned short* __restrict__ awin){
  __shared__ __align__(16) unsigned short Qs[64*40];   // [n][d] stride 40
  __shared__ __align__(16) unsigned short Ks[64*40];   // [m][d] stride 40
  __shared__ __align__(16) unsigned short Vt[32*72];   // [d][m] stride 72
  __shared__ __align__(16) unsigned short Ps[64*72];   // [n][m] stride 72
  __shared__ float invq[64], invk[64];
  int blk = blockIdx.x;
  int win = blk/6, h = blk - win*6;
  int tid = threadIdx.x;
  // ---- stage q,k,v (d padded 30->32 with zeros), v transposed ----
  for (int idx = tid; idx < 2048; idx += 256) {
    int n = idx >> 5, d = idx & 31;
    unsigned short qv = 0, kv = 0, vv = 0;
    if (d < 30) {
      size_t row = (size_t)(win*64 + n)*540;
      qv = qkv[row + h*30 + d];
      kv = qkv[row + 180 + h*30 + d];
      vv = qkv[row + 360 + h*30 + d];
    }
    Qs[n*40 + d] = qv; Ks[n*40 + d] = kv; Vt[d*72 + n] = vv;
  }
  __syncthreads();
  // ---- per-row L2 norms of q and k ----
  if (tid < 128) {
    int n = tid & 63;
    const unsigned short* base = (tid < 64) ? (Qs + n*40) : (Ks + n*40);
    float s = 0.f;
    for (int d = 0; d < 30; ++d) { float v = b2f(base[d]); s += v*v; }
    float inv = 1.f / fmaxf(sqrtf(s), 1e-12f);
    if (tid < 64) invq[n] = inv; else invk[n] = inv;
  }
  __syncthreads();
  int wid = tid>>6, lane = tid&63, lr = lane&15, lg = lane>>4;
  float scale = __expf(fminf(lsc[h], 4.6051701859880914f));
  // ---- QK^T: wave wid owns 16-row block; one K-step (d=32) ----
  f4v z = {0.f,0.f,0.f,0.f};
  s8v aq = *(const s8v*)(Qs + (16*wid + lr)*40 + lg*8);
  f4v sacc[4];
  #pragma unroll
  for (int tc = 0; tc < 4; ++tc) {
    s8v bk = *(const s8v*)(Ks + (16*tc + lr)*40 + lg*8);
    sacc[tc] = mfma16(aq, bk, z);
  }
  // ---- logits + softmax in-register (row n = 16*wid + lg*4 + i) ----
  float iq[4], ikv[4];
  #pragma unroll
  for (int i = 0; i < 4; ++i) iq[i] = invq[16*wid + lg*4 + i] * scale;
  #pragma unroll
  for (int tc = 0; tc < 4; ++tc) ikv[tc] = invk[16*tc + lr];
  float p[4][4];   // [tc][i]
  #pragma unroll
  for (int tc = 0; tc < 4; ++tc) {
    int col = 16*tc + lr;
    #pragma unroll
    for (int i = 0; i < 4; ++i) {
      int row = 16*wid + lg*4 + i;
      p[tc][i] = sacc[tc][i]*iq[i]*ikv[tc] + biasA[((h*64 + row) << 6) + col];
    }
  }
  float rin[4];
  #pragma unroll
  for (int i = 0; i < 4; ++i) {
    float mx = fmaxf(fmaxf(p[0][i], p[1][i]), fmaxf(p[2][i], p[3][i]));
    mx = rmax16(mx);
    float sum = 0.f;
    #pragma unroll
    for (int tc = 0; tc < 4; ++tc) { p[tc][i] = __expf(p[tc][i] - mx); sum += p[tc][i]; }
    sum = rsum16(sum);
    rin[i] = 1.f / sum;
  }
  #pragma unroll
  for (int tc = 0; tc < 4; ++tc)
    #pragma unroll
    for (int i = 0; i < 4; ++i)
      Ps[(16*wid + lg*4 + i)*72 + 16*tc + lr] = f2b(p[tc][i]*rin[i]);
  __syncthreads();
  // ---- PV: O[16x32] per wave = P[16x64] @ V[64x32] ----
  f4v o0 = z, o1 = z;
  #pragma unroll
  for (int k0 = 0; k0 < 2; ++k0) {
    s8v pa = *(const s8v*)(Ps + (16*wid + lr)*72 + k0*32 + lg*8);
    s8v b0 = *(const s8v*)(Vt + lr*72        + k0*32 + lg*8);
    s8v b1 = *(const s8v*)(Vt + (16 + lr)*72 + k0*32 + lg*8);
    o0 = mfma16(pa, b0, o0);
    o1 = mfma16(pa, b1, o1);
  }
  #pragma unroll
  for (int i = 0; i < 4; ++i) {
    int row = 16*wid + lg*4 + i;
    size_t base = (size_t)(win*64 + row)*180 + h*30;
    awin[base + lr] = f2b(o0[i]);
    int c1 = 16 + lr;
    if (c1 < 30) awin[base + c1] = f2b(o1[i]);
  }
}

// ---------------- proj + norm1 LN (in-register) + residual + win-reverse -----
__global__ __launch_bounds__(256) void k_proj_mfma(const unsigned short* __restrict__ awin,
    const unsigned short* __restrict__ wpj, const float* __restrict__ pb,
    const float* __restrict__ g1, const float* __restrict__ b1,
    const float* __restrict__ x, float* __restrict__ x1){
  __shared__ unsigned short A[64*200];
  int win = blockIdx.x, tid = threadIdx.x;
  size_t rb = (size_t)win*64;
  for (int idx = tid; idx < 64*192; idx += 256) {
    int i = idx/192, k = idx - i*192;
    A[i*200 + k] = (k < 180) ? awin[(rb + i)*180 + k] : (unsigned short)0;
  }
  __syncthreads();
  int wid = tid>>6, lane = tid&63, lr = lane&15, lg = lane>>4;
  const unsigned short* arow = A + (16*wid + lr)*200 + lg*8;
  f4v z = {0.f,0.f,0.f,0.f};
  f4v acc[12];
  #pragma unroll
  for (int cc = 0; cc < 12; ++cc) acc[cc] = z;
  #pragma unroll
  for (int k0 = 0; k0 < 6; ++k0) {
    s8v a = *(const s8v*)(arow + k0*32);
    #pragma unroll
    for (int cc = 0; cc < 12; ++cc) {
      s8v b = *(const s8v*)(wpj + (size_t)(cc*16 + lr)*192 + k0*32 + lg*8);
      acc[cc] = mfma16(a, b, acc[cc]);
    }
  }
  float psum[4] = {0,0,0,0}, psq[4] = {0,0,0,0};
  #pragma unroll
  for (int cc = 0; cc < 12; ++cc) {
    int c = cc*16 + lr;
    float bias = (c < 180) ? pb[c] : 0.f;
    #pragma unroll
    for (int i = 0; i < 4; ++i) {
      float v = (c < 180) ? acc[cc][i] + bias : 0.f;
      acc[cc][i] = v;
      psum[i] += v; psq[i] += v*v;
    }
  }
  float m[4], rs[4];
  #pragma unroll
  for (int i = 0; i < 4; ++i) {
    float s = rsum16(psum[i]), s2 = rsum16(psq[i]);
    m[i] = s*(1.f/180.f);
    float var = fmaxf(s2*(1.f/180.f) - m[i]*m[i], 0.f);
    rs[i] = rsqrtf(var + 1e-5f);
  }
  int b = win/144, rem = win - b*144, wh = rem/12, ww = rem - (rem/12)*12;
  #pragma unroll
  for (int cc = 0; cc < 12; ++cc) {
    int c = cc*16 + lr;
    if (c < 180) {
      #pragma unroll
      for (int i = 0; i < 4; ++i) {
        int r = 16*wid + lg*4 + i;
        int l = (wh*8 + (r>>3))*96 + ww*8 + (r&7);
        size_t o = (size_t)(b*9216 + l)*180 + c;
        x1[o] = x[o] + (acc[cc][i] - m[i])*rs[i]*g1[c] + b1[c];
      }
    }
  }
}

// ---------------- VAB p1 ----------------
__global__ __launch_bounds__(256) void k_p1_mfma(const float* __restrict__ x1,
    const unsigned short* __restrict__ wp1, const float* __restrict__ bias,
    float* __restrict__ v1){
  __shared__ unsigned short A[64*200];
  int blk = blockIdx.x, tid = threadIdx.x;
  int b = blk/144, p0 = (blk - b*144)*64;
  int rowb = b*9216 + p0;
  for (int idx = tid; idx < 64*192; idx += 256) {
    int i = idx/192, k = idx - i*192;
    A[i*200 + k] = (k < 180) ? f2b(x1[(size_t)(rowb + i)*180 + k]) : (unsigned short)0;
  }
  __syncthreads();
  int wid = tid>>6, lane = tid&63, lr = lane&15, lg = lane>>4;
  const unsigned short* arow = A + (16*wid + lr)*200 + lg*8;
  #pragma unroll
  for (int pp = 0; pp < 3; ++pp) {
    int c0 = pp*32;
    f4v acc0 = {0.f,0.f,0.f,0.f}, acc1 = {0.f,0.f,0.f,0.f};
    #pragma unroll
    for (int k0 = 0; k0 < 6; ++k0) {
      s8v a  = *(const s8v*)(arow + k0*32);
      s8v b0 = *(const s8v*)(wp1 + (size_t)(c0 + lr)*192 + k0*32 + lg*8);
      s8v b1 = *(const s8v*)(wp1 + (size_t)(c0 + 16 + lr)*192 + k0*32 + lg*8);
      acc0 = mfma16(a, b0, acc0);
      acc1 = mfma16(a, b1, acc1);
    }
    int c  = c0 + lr, c2 = c0 + 16 + lr;
    float bv = bias[c], bv2 = bias[c2];
    #pragma unroll
    for (int i = 0; i < 4; ++i) {
      int px = 16*wid + lg*4 + i;
      v1[(size_t)(b*96 + c )*9216 + p0 + px] = geluf(acc0[i] + bv );
      v1[(size_t)(b*96 + c2)*9216 + p0 + px] = geluf(acc1[i] + bv2);
    }
  }
}

// ---------------- VAB pw ----------------
__global__ __launch_bounds__(256) void k_pw_mfma(const float* __restrict__ v1,
    const unsigned short* __restrict__ wpw, const float* __restrict__ bias,
    float* __restrict__ outp){
  __shared__ unsigned short A[64*104];
  int blk = blockIdx.x, tid = threadIdx.x;
  int b = blk/144, p0 = (blk - b*144)*64;
  for (int idx = tid; idx < 96*64; idx += 256) {
    int k = idx >> 6, i = idx & 63;
    A[i*104 + k] = f2b(v1[(size_t)(b*96 + k)*9216 + p0 + i]);
  }
  __syncthreads();
  int wid = tid>>6, lane = tid&63, lr = lane&15, lg = lane>>4;
  const unsigned short* arow = A + (16*wid + lr)*104 + lg*8;
  #pragma unroll
  for (int pp = 0; pp < 3; ++pp) {
    int c0 = pp*32;
    f4v acc0 = {0.f,0.f,0.f,0.f}, acc1 = {0.f,0.f,0.f,0.f};
    #pragma unroll
    for (int k0 = 0; k0 < 3; ++k0) {
      s8v a  = *(const s8v*)(arow + k0*32);
      s8v b0 = *(const s8v*)(wpw + (size_t)(c0 + lr)*96 + k0*32 + lg*8);
      s8v b1 = *(const s8v*)(wpw + (size_t)(c0 + 16 + lr)*96 + k0*32 + lg*8);
      acc0 = mfma16(a, b0, acc0);
      acc1 = mfma16(a, b1, acc1);
    }
    int c  = c0 + lr, c2 = c0 + 16 + lr;
    float bv = bias[c], bv2 = bias[c2];
    #pragma unroll
    for (int i = 0; i < 4; ++i) {
      int px = 16*wid + lg*4 + i;
      outp[(size_t)(b*96 + c )*9216 + p0 + px] = acc0[i] + bv;
      outp[(size_t)(b*96 + c2)*9216 + p0 + px] = acc1[i] + bv2;
    }
  }
}

// ---------------- depthwise 5x5 ----------------
__global__ __launch_bounds__(256) void k_dwc(const float* __restrict__ in,
    const float* __restrict__ w, const float* __restrict__ bias,
    float* __restrict__ out, int dil){
  int blk = blockIdx.x, tid = threadIdx.x;
  int bc = blk/36, pc = blk - bc*36;
  int c = bc - (bc/96)*96;
  int p = pc*256 + tid;
  int hh = p/96, ww = p - hh*96;
  float acc = bias[c];
  const float* wc = w + c*25;
  const float* inb = in + (size_t)bc*9216;
  #pragma unroll
  for (int i = 0; i < 5; ++i) {
    int y = hh + dil*(i-2);
    if (y < 0 || y >= 96) continue;
    #pragma unroll
    for (int j = 0; j < 5; ++j) {
      int xq = ww + dil*(j-2);
      if (xq >= 0 && xq < 96) acc += inb[y*96 + xq]*wc[i*5 + j];
    }
  }
  out[(size_t)bc*9216 + p] = acc;
}

// ---------------- p2 + residual + VAB-LN -> vnb NHWC bf16 --------------------
__global__ __launch_bounds__(256) void k_p2ln_mfma(const float* __restrict__ v1,
    const float* __restrict__ a3, const float* __restrict__ x1,
    const unsigned short* __restrict__ wp2, const float* __restrict__ bias,
    const float* __restrict__ lng, const float* __restrict__ lnb,
    unsigned short* __restrict__ vnb){
  __shared__ unsigned short A[64*104];
  int blk = blockIdx.x, tid = threadIdx.x;
  int b = blk/144, p0 = (blk - b*144)*64;
  for (int idx = tid; idx < 96*64; idx += 256) {
    int k = idx >> 6, i = idx & 63;
    size_t o = (size_t)(b*96 + k)*9216 + p0 + i;
    A[i*104 + k] = f2b(v1[o]*a3[o]);
  }
  __syncthreads();
  int wid = tid>>6, lane = tid&63, lr = lane&15, lg = lane>>4;
  const unsigned short* arow = A + (16*wid + lr)*104 + lg*8;
  f4v z = {0.f,0.f,0.f,0.f};
  f4v acc[12];
  #pragma unroll
  for (int cc = 0; cc < 12; ++cc) acc[cc] = z;
  #pragma unroll
  for (int k0 = 0; k0 < 3; ++k0) {
    s8v a = *(const s8v*)(arow + k0*32);
    #pragma unroll
    for (int cc = 0; cc < 12; ++cc) {
      s8v bb = *(const s8v*)(wp2 + (size_t)(cc*16 + lr)*96 + k0*32 + lg*8);
      acc[cc] = mfma16(a, bb, acc[cc]);
    }
  }
  float psum[4] = {0,0,0,0}, psq[4] = {0,0,0,0};
  #pragma unroll
  for (int cc = 0; cc < 12; ++cc) {
    int c = cc*16 + lr;
    float bv = (c < 180) ? bias[c] : 0.f;
    #pragma unroll
    for (int i = 0; i < 4; ++i) {
      int px = 16*wid + lg*4 + i;
      float v = 0.f;
      if (c < 180) v = acc[cc][i] + bv + x1[(size_t)(b*9216 + p0 + px)*180 + c];
      acc[cc][i] = v;
      psum[i] += v; psq[i] += v*v;
    }
  }
  float m[4], rs[4];
  #pragma unroll
  for (int i = 0; i < 4; ++i) {
    float s = rsum16(psum[i]), s2 = rsum16(psq[i]);
    m[i] = s*(1.f/180.f);
    float var = fmaxf(s2*(1.f/180.f) - m[i]*m[i], 0.f);
    rs[i] = rsqrtf(var + 1e-5f);
  }
  #pragma unroll
  for (int cc = 0; cc < 12; ++cc) {
    int c = cc*16 + lr;
    if (c < 180) {
      #pragma unroll
      for (int i = 0; i < 4; ++i) {
        int px = 16*wid + lg*4 + i;
        vnb[(size_t)(b*9216 + p0 + px)*192 + c] =
            f2b((acc[cc][i] - m[i])*rs[i]*lng[c] + lnb[c]);
      }
    }
  }
  for (int idx = tid; idx < 64*12; idx += 256) {
    int px = idx/12, j = idx - (idx/12)*12;
    vnb[(size_t)(b*9216 + p0 + px)*192 + 180 + j] = 0;
  }
}

// ---------------- convbody ----------------
__global__ __launch_bounds__(256) void k_cb_mfma(const unsigned short* __restrict__ vnb,
    const unsigned short* __restrict__ wcb, const float* __restrict__ bias,
    unsigned short* __restrict__ cbn){
  __shared__ unsigned short A[64*104];
  int blk = blockIdx.x, tid = threadIdx.x;
  int b = blk/144, p0 = (blk - b*144)*64;
  int wid = tid>>6, lane = tid&63, lr = lane&15, lg = lane>>4;
  for (int gch = 0; gch < 2; ++gch) {
    f4v z = {0.f,0.f,0.f,0.f};
    f4v acc[6];
    #pragma unroll
    for (int cc = 0; cc < 6; ++cc) acc[cc] = z;
    for (int tap = 0; tap < 9; ++tap) {
      int dh = tap/3 - 1, dw = tap - (tap/3)*3 - 1;
      __syncthreads();
      for (int idx = tid; idx < 64*96; idx += 256) {
        int i = idx/96, k = idx - i*96;
        int p = p0 + i;
        int hh = p/96 + dh, ww = (p - (p/96)*96) + dw;
        unsigned short val = 0;
        if (k < 90 && hh >= 0 && hh < 96 && ww >= 0 && ww < 96)
          val = vnb[(size_t)(b*9216 + hh*96 + ww)*192 + gch*90 + k];
        A[i*104 + k] = val;
      }
      __syncthreads();
      const unsigned short* wb = wcb + (size_t)(gch*9 + tap)*96*96;
      const unsigned short* arow = A + (16*wid + lr)*104 + lg*8;
      #pragma unroll
      for (int k0 = 0; k0 < 3; ++k0) {
        s8v a = *(const s8v*)(arow + k0*32);
        #pragma unroll
        for (int cc = 0; cc < 6; ++cc) {
          s8v bb = *(const s8v*)(wb + (size_t)(cc*16 + lr)*96 + k0*32 + lg*8);
          acc[cc] = mfma16(a, bb, acc[cc]);
        }
      }
    }
    #pragma unroll
    for (int cc = 0; cc < 6; ++cc) {
      int c = cc*16 + lr;
      if (c < 90) {
        int o = gch*90 + c;
        float bv = bias[o];
        #pragma unroll
        for (int i = 0; i < 4; ++i) {
          int px = 16*wid + lg*4 + i;
          cbn[(size_t)(b*9216 + p0 + px)*192 + o] = f2b(acc[cc][i] + bv);
        }
      }
    }
  }
  for (int idx = tid; idx < 64*12; idx += 256) {
    int px = idx/12, j = idx - (idx/12)*12;
    cbn[(size_t)(b*9216 + p0 + px)*192 + 180 + j] = 0;
  }
}

// ---------------- pe ----------------
__global__ __launch_bounds__(256) void k_pe_mfma(const unsigned short* __restrict__ cbn,
    const unsigned short* __restrict__ wpe, const float* __restrict__ bias,
    const float* __restrict__ x1, float* __restrict__ outp){
  __shared__ unsigned short A[64*200];
  int blk = blockIdx.x, tid = threadIdx.x;
  int b = blk/144, p0 = (blk - b*144)*64;
  for (int idx = tid; idx < 64*192; idx += 256) {
    int i = idx/192, k = idx - i*192;
    A[i*200 + k] = cbn[(size_t)(b*9216 + p0 + i)*192 + k];
  }
  __syncthreads();
  int wid = tid>>6, lane = tid&63, lr = lane&15, lg = lane>>4;
  const unsigned short* arow = A + (16*wid + lr)*200 + lg*8;
  #pragma unroll
  for (int pp = 0; pp < 6; ++pp) {
    int c0 = pp*32;
    f4v acc0 = {0.f,0.f,0.f,0.f}, acc1 = {0.f,0.f,0.f,0.f};
    #pragma unroll
    for (int k0 = 0; k0 < 6; ++k0) {
      s8v a  = *(const s8v*)(arow + k0*32);
      s8v b0 = *(const s8v*)(wpe + (size_t)(c0 + lr)*192 + k0*32 + lg*8);
      s8v b1 = *(const s8v*)(wpe + (size_t)(c0 + 16 + lr)*192 + k0*32 + lg*8);
      acc0 = mfma16(a, b0, acc0);
      acc1 = mfma16(a, b1, acc1);
    }
    #pragma unroll
    for (int i = 0; i < 4; ++i) {
      int px = 16*wid + lg*4 + i;
      size_t rowo = (size_t)(b*9216 + p0 + px)*180;
      int c = c0 + lr;
      if (c < 180) outp[rowo + c] = x1[rowo + c] + acc0[i] + bias[c];
      int c2 = c0 + 16 + lr;
      if (c2 < 180) outp[rowo + c2] = x1[rowo + c2] + acc1[i] + bias[c2];
    }
  }
}

// ---------------- fc1 + gelu ----------------
__global__ __launch_bounds__(256) void k_fc1_mfma(const float* __restrict__ xo,
    const unsigned short* __restrict__ wf1, const float* __restrict__ bias,
    unsigned short* __restrict__ hbuf){
  __shared__ unsigned short A[64*200];
  int blk = blockIdx.x, tid = threadIdx.x;
  int r0 = blk*64;
  for (int idx = tid; idx < 64*192; idx += 256) {
    int i = idx/192, k = idx - i*192;
    A[i*200 + k] = (k < 180) ? f2b(xo[(size_t)(r0 + i)*180 + k]) : (unsigned short)0;
  }
  __syncthreads();
  int wid = tid>>6, lane = tid&63, lr = lane&15, lg = lane>>4;
  const unsigned short* arow = A + (16*wid + lr)*200 + lg*8;
  for (int pp = 0; pp < 23; ++pp) {
    int c0 = pp*32;
    f4v acc0 = {0.f,0.f,0.f,0.f}, acc1 = {0.f,0.f,0.f,0.f};
    #pragma unroll
    for (int k0 = 0; k0 < 6; ++k0) {
      s8v a  = *(const s8v*)(arow + k0*32);
      s8v b0 = *(const s8v*)(wf1 + (size_t)(c0 + lr)*192 + k0*32 + lg*8);
      s8v b1 = *(const s8v*)(wf1 + (size_t)(c0 + 16 + lr)*192 + k0*32 + lg*8);
      acc0 = mfma16(a, b0, acc0);
      acc1 = mfma16(a, b1, acc1);
    }
    int c  = c0 + lr, c2 = c0 + 16 + lr;
    #pragma unroll
    for (int i = 0; i < 4; ++i) {
      size_t r = (size_t)r0 + 16*wid + lg*4 + i;
      hbuf[r*736 + c ] = (c  < 720) ? f2b(geluf(acc0[i] + bias[c ])) : (unsigned short)0;
      hbuf[r*736 + c2] = (c2 < 720) ? f2b(geluf(acc1[i] + bias[c2])) : (unsigned short)0;
    }
  }
}

// ---------------- fc2 + norm2 LN + residual ----------------
__global__ __launch_bounds__(256) void k_fc2_mfma(const unsigned short* __restrict__ hbuf,
    const unsigned short* __restrict__ wf2, const float* __restrict__ bias,
    const float* __restrict__ g2, const float* __restrict__ b2,
    float* __restrict__ outp){
  int blk = blockIdx.x, tid = threadIdx.x;
  int r0 = blk*64;
  int wid = tid>>6, lane = tid&63, lr = lane&15, lg = lane>>4;
  const unsigned short* arow = hbuf + (size_t)(r0 + 16*wid + lr)*736 + lg*8;
  f4v z = {0.f,0.f,0.f,0.f};
  f4v acc[12];
  #pragma unroll
  for (int cc = 0; cc < 12; ++cc) acc[cc] = z;
  for (int k0 = 0; k0 < 23; ++k0) {
    s8v a = *(const s8v*)(arow + k0*32);
    #pragma unroll
    for (int cc = 0; cc < 12; ++cc) {
      s8v b = *(const s8v*)(wf2 + (size_t)(cc*16 + lr)*736 + k0*32 + lg*8);
      acc[cc] = mfma16(a, b, acc[cc]);
    }
  }
  float psum[4] = {0,0,0,0}, psq[4] = {0,0,0,0};
  #pragma unroll
  for (int cc = 0; cc < 12; ++cc) {
    int c = cc*16 + lr;
    float bv = (c < 180) ? bias[c] : 0.f;
    #pragma unroll
    for (int i = 0; i < 4; ++i) {
      float v = (c < 180) ? acc[cc][i] + bv : 0.f;
      acc[cc][i] = v;
      psum[i] += v; psq[i] += v*v;
    }
  }
  float m[4], rs[4];
  #pragma unroll
  for (int i = 0; i < 4; ++i) {
    float s = rsum16(psum[i]), s2 = rsum16(psq[i]);
    m[i] = s*(1.f/180.f);
    float var = fmaxf(s2*(1.f/180.f) - m[i]*m[i], 0.f);
    rs[i] = rsqrtf(var + 1e-5f);
  }
  #pragma unroll
  for (int cc = 0; cc < 12; ++cc) {
    int c = cc*16 + lr;
    if (c < 180) {
      #pragma unroll
      for (int i = 0; i < 4; ++i) {
        size_t o = (size_t)(r0 + 16*wid + lg*4 + i)*180 + c;
        outp[o] = outp[o] + (acc[cc][i] - m[i])*rs[i]*g2[c] + b2[c];
      }
    }
  }
}

// ---------------- launch ----------------
extern "C" void kernel_launch(void* const* d_in, const int* in_sizes, int n_in,
                              void* d_out, int out_size, void* d_ws, size_t ws_size,
                              hipStream_t stream) {
  const float* x      = (const float*)d_in[0];
  const float* qkv_w  = (const float*)d_in[1];
  const float* q_bias = (const float*)d_in[2];
  const float* v_bias = (const float*)d_in[3];
  const float* lsc    = (const float*)d_in[4];
  const float* cpb_w1 = (const float*)d_in[5];
  const float* cpb_b1 = (const float*)d_in[6];
  const float* cpb_w2 = (const float*)d_in[7];
  const float* proj_w = (const float*)d_in[8];
  const float* proj_b = (const float*)d_in[9];
  const float* n1g    = (const float*)d_in[10];
  const float* n1b    = (const float*)d_in[11];
  const float* n2g    = (const float*)d_in[12];
  const float* n2b    = (const float*)d_in[13];
  const float* fc1w   = (const float*)d_in[14];
  const float* fc1b   = (const float*)d_in[15];
  const float* fc2w   = (const float*)d_in[16];
  const float* fc2b   = (const float*)d_in[17];
  const float* p1w    = (const float*)d_in[18];
  const float* p1b    = (const float*)d_in[19];
  const float* pww    = (const float*)d_in[20];
  const float* pwb    = (const float*)d_in[21];
  const float* dww    = (const float*)d_in[22];
  const float* dwb    = (const float*)d_in[23];
  const float* ddw    = (const float*)d_in[24];
  const float* ddb    = (const float*)d_in[25];
  const float* p2w    = (const float*)d_in[26];
  const float* p2b    = (const float*)d_in[27];
  const float* vlng   = (const float*)d_in[28];
  const float* vlnb   = (const float*)d_in[29];
  const float* cbw    = (const float*)d_in[30];
  const float* cbb    = (const float*)d_in[31];
  const float* pew    = (const float*)d_in[32];
  const float* peb    = (const float*)d_in[33];
  float* out = (float*)d_out;
  char* ws = (char*)d_ws;

  unsigned short* qkv  = (unsigned short*)(ws + OFF_QKV);
  unsigned short* awin = (unsigned short*)(ws + OFF_AWIN);
  float* x1   = (float*)(ws + OFF_X1);
  float* v1   = (float*)(ws + OFF_V1);
  float* ab1  = (float*)(ws + OFF_AB1);
  float* ab2  = (float*)(ws + OFF_AB2);
  unsigned short* vnb = (unsigned short*)(ws + OFF_VNB);
  unsigned short* cbn = (unsigned short*)(ws + OFF_CBN);
  unsigned short* hbf = (unsigned short*)(ws + OFF_H);
  float* tbl   = (float*)(ws + O_TBL);
  float* biasA = (float*)(ws + O_BIASA);
  unsigned short* wq  = (unsigned short*)(ws + O_WQ);
  unsigned short* wpj = (unsigned short*)(ws + O_WPJ);
  unsigned short* wpe = (unsigned short*)(ws + O_WPE);
  unsigned short* wp1 = (unsigned short*)(ws + O_WP1);
  unsigned short* wpw = (unsigned short*)(ws + O_WPW);
  unsigned short* wp2 = (unsigned short*)(ws + O_WP2);
  unsigned short* wf1 = (unsigned short*)(ws + O_WF1);
  unsigned short* wf2 = (unsigned short*)(ws + O_WF2);
  unsigned short* wcb = (unsigned short*)(ws + O_WCB);

  // prep
  k_cpb_tbl<<<225, 512, 0, stream>>>(cpb_w1, cpb_b1, cpb_w2, tbl);
  k_cpb_bias<<<96, 256, 0, stream>>>(tbl, biasA);
  k_cvtpad<<<(544*192+255)/256, 256, 0, stream>>>(qkv_w, wq, 540, 180, 192, 544*192);
  k_cvtpad<<<(192*192+255)/256, 256, 0, stream>>>(proj_w, wpj, 180, 180, 192, 192*192);
  k_cvtpad<<<(192*192+255)/256, 256, 0, stream>>>(pew, wpe, 180, 180, 192, 192*192);
  k_cvtpad<<<(96*192+255)/256, 256, 0, stream>>>(p1w, wp1, 96, 180, 192, 96*192);
  k_cvtpad<<<(96*96+255)/256, 256, 0, stream>>>(pww, wpw, 96, 96, 96, 96*96);
  k_cvtpad<<<(192*96+255)/256, 256, 0, stream>>>(p2w, wp2, 180, 96, 96, 192*96);
  k_cvtpad<<<(736*192+255)/256, 256, 0, stream>>>(fc1w, wf1, 720, 180, 192, 736*192);
  k_cvtpad<<<(192*736+255)/256, 256, 0, stream>>>(fc2w, wf2, 180, 720, 736, 192*736);
  k_cvt_wcb<<<(18*96*96+255)/256, 256, 0, stream>>>(cbw, wcb);
  // main chain
  k_qkv_mfma<<<NWIN, 256, 0, stream>>>(x, wq, q_bias, v_bias, qkv);
  k_attn_mfma<<<NWIN*6, 256, 0, stream>>>(qkv, biasA, lsc, awin);
  k_proj_mfma<<<NWIN, 256, 0, stream>>>(awin, wpj, proj_b, n1g, n1b, x, x1);
  k_p1_mfma<<<NWIN, 256, 0, stream>>>(x1, wp1, p1b, v1);
  k_pw_mfma<<<NWIN, 256, 0, stream>>>(v1, wpw, pwb, ab1);
  k_dwc<<<27648, 256, 0, stream>>>(ab1, dww, dwb, ab2, 1);
  k_dwc<<<27648, 256, 0, stream>>>(ab2, ddw, ddb, ab1, 3);
  k_p2ln_mfma<<<NWIN, 256, 0, stream>>>(v1, ab1, x1, wp2, p2b, vlng, vlnb, vnb);
  k_cb_mfma<<<NWIN, 256, 0, stream>>>(vnb, wcb, cbb, cbn);
  k_pe_mfma<<<NWIN, 256, 0, stream>>>(cbn, wpe, peb, x1, out);
  k_fc1_mfma<<<NWIN, 256, 0, stream>>>(out, wf1, fc1b, hbf);
  k_fc2_mfma<<<NWIN, 256, 0, stream>>>(hbf, wf2, fc2b, n2g, n2b, out);
}

// Round 6
// 1137.091 us; speedup vs baseline: 4.3789x; 1.0797x over previous
//
#include <hip/hip_runtime.h>
#include <hip/hip_bf16.h>

#define DEV __device__ __forceinline__

typedef __attribute__((ext_vector_type(8))) short s8v;   // 8 bf16 (4 VGPR)
typedef __attribute__((ext_vector_type(4))) float f4v;   // MFMA acc

static constexpr int NWIN = 1152;
static constexpr int NROW = 73728;

// ---------------- workspace layout (peak < 185.8 MB) ----
static constexpr size_t OFF_QKV  = 0;            // bf16 [NROW][540]  (dead after attn)
static constexpr size_t OFF_AWIN = 79626240;     // bf16 [NROW][180]  (dead after proj)
static constexpr size_t OFF_X1   = 132710400;    // f32  [NROW][180]  (live until pe/p2)
static constexpr size_t OFF_V1   = 0;            // f32  NCHW [8*96][9216]
static constexpr size_t OFF_AB1  = 28311552;     // f32  NCHW
static constexpr size_t OFF_AB2  = 56623104;     // f32  NCHW
static constexpr size_t OFF_VNB  = 56623104;     // bf16 NHWC [NROW][192] (over ab2, dead) — group-padded layout
static constexpr size_t OFF_CBN  = 0;            // bf16 NHWC [NROW][192] (over v1, dead)
static constexpr size_t OFF_H    = 0;            // bf16 [NROW][736]  (over conv temps, dead)
static constexpr size_t WB       = 130613248;
static constexpr size_t O_TBL    = WB;                    // f32 [225][6]
static constexpr size_t O_BIASA  = WB + 8192;             // f32 [6][64][64]
static constexpr size_t O_WQ     = WB + 106496;           // bf16 [544][192]
static constexpr size_t O_WPJ    = O_WQ  + 208896;        // bf16 [192][192]
static constexpr size_t O_WPE    = O_WPJ + 73728;         // bf16 [192][192]
static constexpr size_t O_WP1    = O_WPE + 73728;         // bf16 [96][192]
static constexpr size_t O_WPW    = O_WP1 + 36864;         // bf16 [96][96]
static constexpr size_t O_WP2    = O_WPW + 18432;         // bf16 [192][96]
static constexpr size_t O_WF1    = O_WP2 + 36864;         // bf16 [736][192]
static constexpr size_t O_WF2    = O_WF1 + 282624;        // bf16 [192][736]
static constexpr size_t O_WCB    = O_WF2 + 282624;        // bf16 [18][96][96]

DEV float geluf(float x){ return 0.5f*x*(1.f + erff(x*0.70710678118654752f)); }

DEV unsigned short f2b(float v){
  union { __hip_bfloat16 h; unsigned short u; } x;
  x.h = __float2bfloat16(v);
  return x.u;
}

DEV float b2f(unsigned short u){
  union { float f; unsigned u; } x;
  x.u = ((unsigned)u) << 16;
  return x.f;
}

DEV f4v mfma16(s8v a, s8v b, f4v c){
  return __builtin_amdgcn_mfma_f32_16x16x32_bf16(a, b, c, 0, 0, 0);
}

DEV float rsum16(float v){
  v += __shfl_xor(v, 1); v += __shfl_xor(v, 2);
  v += __shfl_xor(v, 4); v += __shfl_xor(v, 8);
  return v;
}

DEV float rmax16(float v){
  v = fmaxf(v, __shfl_xor(v, 1)); v = fmaxf(v, __shfl_xor(v, 2));
  v = fmaxf(v, __shfl_xor(v, 4)); v = fmaxf(v, __shfl_xor(v, 8));
  return v;
}

DEV float qkvbias(int c, const float* qb, const float* vb){
  return (c < 180) ? qb[c] : (c < 360 ? 0.f : vb[c-360]);
}

// ---------------- CPB MLP table ----------------
__global__ __launch_bounds__(512) void k_cpb_tbl(const float* __restrict__ w1,
    const float* __restrict__ b1, const float* __restrict__ w2, float* __restrict__ tbl){
  int m = blockIdx.x, tid = threadIdx.x;
  int i = m/15, j = m - (m/15)*15;
  float t0 = (float)(i-7)*(8.f/7.f), t1 = (float)(j-7)*(8.f/7.f);
  float f0 = log2f(fabsf(t0)+1.f)*(1.f/3.f); if (t0 < 0.f) f0 = -f0;
  float f1 = log2f(fabsf(t1)+1.f)*(1.f/3.f); if (t1 < 0.f) f1 = -f1;
  float hv = fmaxf(f0*w1[2*tid] + f1*w1[2*tid+1] + b1[tid], 0.f);
  __shared__ float red[6][8];
  int lane = tid & 63, wv = tid >> 6;
  for (int h = 0; h < 6; ++h) {
    float p = hv * w2[h*512 + tid];
    for (int off = 32; off; off >>= 1) p += __shfl_down(p, off);
    if (lane == 0) red[h][wv] = p;
  }
  __syncthreads();
  if (tid < 6) {
    float s = 0.f;
    for (int w = 0; w < 8; ++w) s += red[tid][w];
    tbl[m*6 + tid] = s;
  }
}

__global__ __launch_bounds__(256) void k_cpb_bias(const float* __restrict__ tbl,
    float* __restrict__ biasA){
  int idx = blockIdx.x*256 + threadIdx.x;
  if (idx >= 6*64*64) return;
  int h = idx >> 12, n = (idx >> 6) & 63, m = idx & 63;
  int dh = (n>>3) - (m>>3) + 7, dw = (n&7) - (m&7) + 7;
  float v = tbl[(dh*15 + dw)*6 + h];
  biasA[idx] = 16.f / (1.f + expf(-v));
}

// ---------------- weight convert + pad ----------------
__global__ __launch_bounds__(256) void k_cvtpad(const float* __restrict__ src,
    unsigned short* __restrict__ dst, int R, int K, int Kp, int total){
  int idx = blockIdx.x*256 + threadIdx.x;
  if (idx >= total) return;
  int r = idx / Kp, k = idx - r*Kp;
  float v = (r < R && k < K) ? src[r*K + k] : 0.f;
  dst[idx] = f2b(v);
}

__global__ __launch_bounds__(256) void k_cvt_wcb(const float* __restrict__ cbw,
    unsigned short* __restrict__ dst){
  int idx = blockIdx.x*256 + threadIdx.x;
  if (idx >= 18*96*96) return;
  int row = idx/96, ci = idx - row*96;
  int g9 = row/96, o = row - g9*96;
  int gch = g9/9, tap = g9 - gch*9;
  float v = (o < 90 && ci < 90) ? cbw[((gch*90 + o)*90 + ci)*9 + tap] : 0.f;
  dst[idx] = f2b(v);
}

// ---------------- qkv: x(win-gathered) @ Wq^T -> qkv bf16 [NROW][540] --------
__global__ __launch_bounds__(256) void k_qkv_mfma(const float* __restrict__ x,
    const unsigned short* __restrict__ wq, const float* __restrict__ qb,
    const float* __restrict__ vb, unsigned short* __restrict__ qkv){
  __shared__ unsigned short A[64*200];
  __shared__ int rowOff[64];
  int win = blockIdx.x, tid = threadIdx.x;
  if (tid < 64) {
    int b = win/144, rem = win - b*144, wh = rem/12, ww = rem - (rem/12)*12;
    int l = (wh*8 + (tid>>3))*96 + ww*8 + (tid&7);
    rowOff[tid] = (b*9216 + l)*180;
  }
  __syncthreads();
  for (int idx = tid; idx < 64*192; idx += 256) {
    int i = idx/192, k = idx - i*192;
    A[i*200 + k] = (k < 180) ? f2b(x[rowOff[i] + k]) : (unsigned short)0;
  }
  __syncthreads();
  int wid = tid>>6, lane = tid&63, lr = lane&15, lg = lane>>4;
  const unsigned short* arow = A + (16*wid + lr)*200 + lg*8;
  for (int pp = 0; pp < 17; ++pp) {
    int c0 = pp*32;
    f4v acc0 = {0.f,0.f,0.f,0.f}, acc1 = {0.f,0.f,0.f,0.f};
    const unsigned short* b0p = wq + (size_t)(c0 + lr)*192 + lg*8;
    const unsigned short* b1p = b0p + 16*192;
    #pragma unroll
    for (int k0 = 0; k0 < 6; ++k0) {
      s8v a  = *(const s8v*)(arow + k0*32);
      s8v b0 = *(const s8v*)(b0p + k0*32);
      s8v b1 = *(const s8v*)(b1p + k0*32);
      acc0 = mfma16(a, b0, acc0);
      acc1 = mfma16(a, b1, acc1);
    }
    size_t rbase = (size_t)win*64 + 16*wid + lg*4;
    #pragma unroll
    for (int i = 0; i < 4; ++i) {
      size_t r = rbase + i;
      int c = c0 + lr;
      if (c < 540) qkv[r*540 + c] = f2b(acc0[i] + qkvbias(c, qb, vb));
      int c2 = c0 + 16 + lr;
      if (c2 < 540) qkv[r*540 + c2] = f2b(acc1[i] + qkvbias(c2, qb, vb));
    }
  }
}

// ---------------- attention (MFMA) per (window, head) -> awin bf16 -----------
__global__ __launch_bounds__(256) void k_attn_mfma(const unsigned short* __restrict__ qkv,
    const float* __restrict__ biasA, const float* __restrict__ lsc,
    unsigned short* __restrict__ awin){
  __shared__ __align__(16) unsigned short Qs[64*40];   // [n][d] stride 40
  __shared__ __align__(16) unsigned short Ks[64*40];   // [m][d] stride 40
  __shared__ __align__(16) unsigned short Vt[32*72];   // [d][m] stride 72
  __shared__ __align__(16) unsigned short Ps[64*72];   // [n][m] stride 72
  __shared__ float invq[64], invk[64];
  int blk = blockIdx.x;
  int win = blk/6, h = blk - win*6;
  int tid = threadIdx.x;
  for (int idx = tid; idx < 2048; idx += 256) {
    int n = idx >> 5, d = idx & 31;
    unsigned short qv = 0, kv = 0, vv = 0;
    if (d < 30) {
      size_t row = (size_t)(win*64 + n)*540;
      qv = qkv[row + h*30 + d];
      kv = qkv[row + 180 + h*30 + d];
      vv = qkv[row + 360 + h*30 + d];
    }
    Qs[n*40 + d] = qv; Ks[n*40 + d] = kv; Vt[d*72 + n] = vv;
  }
  __syncthreads();
  if (tid < 128) {
    int n = tid & 63;
    const unsigned short* base = (tid < 64) ? (Qs + n*40) : (Ks + n*40);
    float s = 0.f;
    for (int d = 0; d < 30; ++d) { float v = b2f(base[d]); s += v*v; }
    float inv = 1.f / fmaxf(sqrtf(s), 1e-12f);
    if (tid < 64) invq[n] = inv; else invk[n] = inv;
  }
  __syncthreads();
  int wid = tid>>6, lane = tid&63, lr = lane&15, lg = lane>>4;
  float scale = __expf(fminf(lsc[h], 4.6051701859880914f));
  f4v z = {0.f,0.f,0.f,0.f};
  s8v aq = *(const s8v*)(Qs + (16*wid + lr)*40 + lg*8);
  f4v sacc[4];
  #pragma unroll
  for (int tc = 0; tc < 4; ++tc) {
    s8v bk = *(const s8v*)(Ks + (16*tc + lr)*40 + lg*8);
    sacc[tc] = mfma16(aq, bk, z);
  }
  float iq[4], ikv[4];
  #pragma unroll
  for (int i = 0; i < 4; ++i) iq[i] = invq[16*wid + lg*4 + i] * scale;
  #pragma unroll
  for (int tc = 0; tc < 4; ++tc) ikv[tc] = invk[16*tc + lr];
  float p[4][4];   // [tc][i]
  #pragma unroll
  for (int tc = 0; tc < 4; ++tc) {
    int col = 16*tc + lr;
    #pragma unroll
    for (int i = 0; i < 4; ++i) {
      int row = 16*wid + lg*4 + i;
      p[tc][i] = sacc[tc][i]*iq[i]*ikv[tc] + biasA[((h*64 + row) << 6) + col];
    }
  }
  float rin[4];
  #pragma unroll
  for (int i = 0; i < 4; ++i) {
    float mx = fmaxf(fmaxf(p[0][i], p[1][i]), fmaxf(p[2][i], p[3][i]));
    mx = rmax16(mx);
    float sum = 0.f;
    #pragma unroll
    for (int tc = 0; tc < 4; ++tc) { p[tc][i] = __expf(p[tc][i] - mx); sum += p[tc][i]; }
    sum = rsum16(sum);
    rin[i] = 1.f / sum;
  }
  #pragma unroll
  for (int tc = 0; tc < 4; ++tc)
    #pragma unroll
    for (int i = 0; i < 4; ++i)
      Ps[(16*wid + lg*4 + i)*72 + 16*tc + lr] = f2b(p[tc][i]*rin[i]);
  __syncthreads();
  f4v o0 = z, o1 = z;
  #pragma unroll
  for (int k0 = 0; k0 < 2; ++k0) {
    s8v pa = *(const s8v*)(Ps + (16*wid + lr)*72 + k0*32 + lg*8);
    s8v b0 = *(const s8v*)(Vt + lr*72        + k0*32 + lg*8);
    s8v b1 = *(const s8v*)(Vt + (16 + lr)*72 + k0*32 + lg*8);
    o0 = mfma16(pa, b0, o0);
    o1 = mfma16(pa, b1, o1);
  }
  #pragma unroll
  for (int i = 0; i < 4; ++i) {
    int row = 16*wid + lg*4 + i;
    size_t base = (size_t)(win*64 + row)*180 + h*30;
    awin[base + lr] = f2b(o0[i]);
    int c1 = 16 + lr;
    if (c1 < 30) awin[base + c1] = f2b(o1[i]);
  }
}

// ---------------- proj + norm1 LN (in-register) + residual + win-reverse -----
__global__ __launch_bounds__(256) void k_proj_mfma(const unsigned short* __restrict__ awin,
    const unsigned short* __restrict__ wpj, const float* __restrict__ pb,
    const float* __restrict__ g1, const float* __restrict__ b1,
    const float* __restrict__ x, float* __restrict__ x1){
  __shared__ unsigned short A[64*200];
  int win = blockIdx.x, tid = threadIdx.x;
  size_t rb = (size_t)win*64;
  for (int idx = tid; idx < 64*192; idx += 256) {
    int i = idx/192, k = idx - i*192;
    A[i*200 + k] = (k < 180) ? awin[(rb + i)*180 + k] : (unsigned short)0;
  }
  __syncthreads();
  int wid = tid>>6, lane = tid&63, lr = lane&15, lg = lane>>4;
  const unsigned short* arow = A + (16*wid + lr)*200 + lg*8;
  f4v z = {0.f,0.f,0.f,0.f};
  f4v acc[12];
  #pragma unroll
  for (int cc = 0; cc < 12; ++cc) acc[cc] = z;
  #pragma unroll
  for (int k0 = 0; k0 < 6; ++k0) {
    s8v a = *(const s8v*)(arow + k0*32);
    #pragma unroll
    for (int cc = 0; cc < 12; ++cc) {
      s8v b = *(const s8v*)(wpj + (size_t)(cc*16 + lr)*192 + k0*32 + lg*8);
      acc[cc] = mfma16(a, b, acc[cc]);
    }
  }
  float psum[4] = {0,0,0,0}, psq[4] = {0,0,0,0};
  #pragma unroll
  for (int cc = 0; cc < 12; ++cc) {
    int c = cc*16 + lr;
    float bias = (c < 180) ? pb[c] : 0.f;
    #pragma unroll
    for (int i = 0; i < 4; ++i) {
      float v = (c < 180) ? acc[cc][i] + bias : 0.f;
      acc[cc][i] = v;
      psum[i] += v; psq[i] += v*v;
    }
  }
  float m[4], rs[4];
  #pragma unroll
  for (int i = 0; i < 4; ++i) {
    float s = rsum16(psum[i]), s2 = rsum16(psq[i]);
    m[i] = s*(1.f/180.f);
    float var = fmaxf(s2*(1.f/180.f) - m[i]*m[i], 0.f);
    rs[i] = rsqrtf(var + 1e-5f);
  }
  int b = win/144, rem = win - b*144, wh = rem/12, ww = rem - (rem/12)*12;
  #pragma unroll
  for (int cc = 0; cc < 12; ++cc) {
    int c = cc*16 + lr;
    if (c < 180) {
      #pragma unroll
      for (int i = 0; i < 4; ++i) {
        int r = 16*wid + lg*4 + i;
        int l = (wh*8 + (r>>3))*96 + ww*8 + (r&7);
        size_t o = (size_t)(b*9216 + l)*180 + c;
        x1[o] = x[o] + (acc[cc][i] - m[i])*rs[i]*g1[c] + b1[c];
      }
    }
  }
}

// ---------------- VAB p1 ----------------
__global__ __launch_bounds__(256) void k_p1_mfma(const float* __restrict__ x1,
    const unsigned short* __restrict__ wp1, const float* __restrict__ bias,
    float* __restrict__ v1){
  __shared__ unsigned short A[64*200];
  int blk = blockIdx.x, tid = threadIdx.x;
  int b = blk/144, p0 = (blk - b*144)*64;
  int rowb = b*9216 + p0;
  for (int idx = tid; idx < 64*192; idx += 256) {
    int i = idx/192, k = idx - i*192;
    A[i*200 + k] = (k < 180) ? f2b(x1[(size_t)(rowb + i)*180 + k]) : (unsigned short)0;
  }
  __syncthreads();
  int wid = tid>>6, lane = tid&63, lr = lane&15, lg = lane>>4;
  const unsigned short* arow = A + (16*wid + lr)*200 + lg*8;
  #pragma unroll
  for (int pp = 0; pp < 3; ++pp) {
    int c0 = pp*32;
    f4v acc0 = {0.f,0.f,0.f,0.f}, acc1 = {0.f,0.f,0.f,0.f};
    #pragma unroll
    for (int k0 = 0; k0 < 6; ++k0) {
      s8v a  = *(const s8v*)(arow + k0*32);
      s8v b0 = *(const s8v*)(wp1 + (size_t)(c0 + lr)*192 + k0*32 + lg*8);
      s8v b1 = *(const s8v*)(wp1 + (size_t)(c0 + 16 + lr)*192 + k0*32 + lg*8);
      acc0 = mfma16(a, b0, acc0);
      acc1 = mfma16(a, b1, acc1);
    }
    int c  = c0 + lr, c2 = c0 + 16 + lr;
    float bv = bias[c], bv2 = bias[c2];
    #pragma unroll
    for (int i = 0; i < 4; ++i) {
      int px = 16*wid + lg*4 + i;
      v1[(size_t)(b*96 + c )*9216 + p0 + px] = geluf(acc0[i] + bv );
      v1[(size_t)(b*96 + c2)*9216 + p0 + px] = geluf(acc1[i] + bv2);
    }
  }
}

// ---------------- VAB pw ----------------
__global__ __launch_bounds__(256) void k_pw_mfma(const float* __restrict__ v1,
    const unsigned short* __restrict__ wpw, const float* __restrict__ bias,
    float* __restrict__ outp){
  __shared__ unsigned short A[64*104];
  int blk = blockIdx.x, tid = threadIdx.x;
  int b = blk/144, p0 = (blk - b*144)*64;
  for (int idx = tid; idx < 96*64; idx += 256) {
    int k = idx >> 6, i = idx & 63;
    A[i*104 + k] = f2b(v1[(size_t)(b*96 + k)*9216 + p0 + i]);
  }
  __syncthreads();
  int wid = tid>>6, lane = tid&63, lr = lane&15, lg = lane>>4;
  const unsigned short* arow = A + (16*wid + lr)*104 + lg*8;
  #pragma unroll
  for (int pp = 0; pp < 3; ++pp) {
    int c0 = pp*32;
    f4v acc0 = {0.f,0.f,0.f,0.f}, acc1 = {0.f,0.f,0.f,0.f};
    #pragma unroll
    for (int k0 = 0; k0 < 3; ++k0) {
      s8v a  = *(const s8v*)(arow + k0*32);
      s8v b0 = *(const s8v*)(wpw + (size_t)(c0 + lr)*96 + k0*32 + lg*8);
      s8v b1 = *(const s8v*)(wpw + (size_t)(c0 + 16 + lr)*96 + k0*32 + lg*8);
      acc0 = mfma16(a, b0, acc0);
      acc1 = mfma16(a, b1, acc1);
    }
    int c  = c0 + lr, c2 = c0 + 16 + lr;
    float bv = bias[c], bv2 = bias[c2];
    #pragma unroll
    for (int i = 0; i < 4; ++i) {
      int px = 16*wid + lg*4 + i;
      outp[(size_t)(b*96 + c )*9216 + p0 + px] = acc0[i] + bv;
      outp[(size_t)(b*96 + c2)*9216 + p0 + px] = acc1[i] + bv2;
    }
  }
}

// ---------------- depthwise 5x5 ----------------
__global__ __launch_bounds__(256) void k_dwc(const float* __restrict__ in,
    const float* __restrict__ w, const float* __restrict__ bias,
    float* __restrict__ out, int dil){
  int blk = blockIdx.x, tid = threadIdx.x;
  int bc = blk/36, pc = blk - bc*36;
  int c = bc - (bc/96)*96;
  int p = pc*256 + tid;
  int hh = p/96, ww = p - hh*96;
  float acc = bias[c];
  const float* wc = w + c*25;
  const float* inb = in + (size_t)bc*9216;
  #pragma unroll
  for (int i = 0; i < 5; ++i) {
    int y = hh + dil*(i-2);
    if (y < 0 || y >= 96) continue;
    #pragma unroll
    for (int j = 0; j < 5; ++j) {
      int xq = ww + dil*(j-2);
      if (xq >= 0 && xq < 96) acc += inb[y*96 + xq]*wc[i*5 + j];
    }
  }
  out[(size_t)bc*9216 + p] = acc;
}

// ---------------- p2 + residual + VAB-LN -> vnb NHWC bf16 (group-padded) -----
// vnb slot layout per row: ch 0..89 -> 0..89, zeros 90..95, ch 90..179 -> 96..185, zeros 186..191
__global__ __launch_bounds__(256) void k_p2ln_mfma(const float* __restrict__ v1,
    const float* __restrict__ a3, const float* __restrict__ x1,
    const unsigned short* __restrict__ wp2, const float* __restrict__ bias,
    const float* __restrict__ lng, const float* __restrict__ lnb,
    unsigned short* __restrict__ vnb){
  __shared__ unsigned short A[64*104];
  int blk = blockIdx.x, tid = threadIdx.x;
  int b = blk/144, p0 = (blk - b*144)*64;
  for (int idx = tid; idx < 96*64; idx += 256) {
    int k = idx >> 6, i = idx & 63;
    size_t o = (size_t)(b*96 + k)*9216 + p0 + i;
    A[i*104 + k] = f2b(v1[o]*a3[o]);
  }
  __syncthreads();
  int wid = tid>>6, lane = tid&63, lr = lane&15, lg = lane>>4;
  const unsigned short* arow = A + (16*wid + lr)*104 + lg*8;
  f4v z = {0.f,0.f,0.f,0.f};
  f4v acc[12];
  #pragma unroll
  for (int cc = 0; cc < 12; ++cc) acc[cc] = z;
  #pragma unroll
  for (int k0 = 0; k0 < 3; ++k0) {
    s8v a = *(const s8v*)(arow + k0*32);
    #pragma unroll
    for (int cc = 0; cc < 12; ++cc) {
      s8v bb = *(const s8v*)(wp2 + (size_t)(cc*16 + lr)*96 + k0*32 + lg*8);
      acc[cc] = mfma16(a, bb, acc[cc]);
    }
  }
  float psum[4] = {0,0,0,0}, psq[4] = {0,0,0,0};
  #pragma unroll
  for (int cc = 0; cc < 12; ++cc) {
    int c = cc*16 + lr;
    float bv = (c < 180) ? bias[c] : 0.f;
    #pragma unroll
    for (int i = 0; i < 4; ++i) {
      int px = 16*wid + lg*4 + i;
      float v = 0.f;
      if (c < 180) v = acc[cc][i] + bv + x1[(size_t)(b*9216 + p0 + px)*180 + c];
      acc[cc][i] = v;
      psum[i] += v; psq[i] += v*v;
    }
  }
  float m[4], rs[4];
  #pragma unroll
  for (int i = 0; i < 4; ++i) {
    float s = rsum16(psum[i]), s2 = rsum16(psq[i]);
    m[i] = s*(1.f/180.f);
    float var = fmaxf(s2*(1.f/180.f) - m[i]*m[i], 0.f);
    rs[i] = rsqrtf(var + 1e-5f);
  }
  #pragma unroll
  for (int cc = 0; cc < 12; ++cc) {
    int c = cc*16 + lr;
    if (c < 180) {
      int cpos = c + (c >= 90 ? 6 : 0);
      #pragma unroll
      for (int i = 0; i < 4; ++i) {
        int px = 16*wid + lg*4 + i;
        vnb[(size_t)(b*9216 + p0 + px)*192 + cpos] =
            f2b((acc[cc][i] - m[i])*rs[i]*lng[c] + lnb[c]);
      }
    }
  }
  // zero-fill pad slots 90..95 and 186..191
  for (int idx = tid; idx < 64*12; idx += 256) {
    int px = idx/12, j = idx - (idx/12)*12;
    int pos = (j < 6) ? (90 + j) : (180 + j);
    vnb[(size_t)(b*9216 + p0 + px)*192 + pos] = 0;
  }
}

// ---------------- convbody: 8x8 tile, halo staged ONCE, 9 shifted MFMA-GEMMs -
__global__ __launch_bounds__(256) void k_cb_mfma(const unsigned short* __restrict__ vnb,
    const unsigned short* __restrict__ wcb, const float* __restrict__ bias,
    unsigned short* __restrict__ cbn){
  __shared__ __align__(16) unsigned short S[100*200];   // 10x10 halo x 192ch, stride 200
  int blk = blockIdx.x, tid = threadIdx.x;
  int b = blk/144, t = blk - b*144;
  int th = t/12, tw = t - (t/12)*12;
  int h0 = th*8, w0 = tw*8;
  // stage halo tile once (group-padded channel layout matches vnb)
  for (int idx = tid; idx < 2400; idx += 256) {
    int pix = idx/24, chunk = idx - pix*24;
    int hp = pix/10, wp = pix - hp*10;
    int h = h0 + hp - 1, w = w0 + wp - 1;
    s8v v = {0,0,0,0,0,0,0,0};
    if (h >= 0 && h < 96 && w >= 0 && w < 96)
      v = *(const s8v*)(vnb + (size_t)(b*9216 + h*96 + w)*192 + chunk*8);
    *(s8v*)(S + pix*200 + chunk*8) = v;
  }
  __syncthreads();
  int wid = tid>>6, lane = tid&63, lr = lane&15, lg = lane>>4;
  int ai = 16*wid + lr;            // A-row = pixel index in 8x8 tile
  int spBase = ((ai>>3) + 1)*10 + (ai&7) + 1;
  f4v z = {0.f,0.f,0.f,0.f};
  for (int gch = 0; gch < 2; ++gch) {
    f4v acc[6];
    #pragma unroll
    for (int cc = 0; cc < 6; ++cc) acc[cc] = z;
    #pragma unroll
    for (int tap = 0; tap < 9; ++tap) {
      int dh = tap/3 - 1, dw = tap - (tap/3)*3 - 1;
      const unsigned short* arow = S + (spBase + dh*10 + dw)*200 + gch*96 + lg*8;
      const unsigned short* wb = wcb + (size_t)(gch*9 + tap)*96*96;
      #pragma unroll
      for (int k0 = 0; k0 < 3; ++k0) {
        s8v a = *(const s8v*)(arow + k0*32);
        #pragma unroll
        for (int cc = 0; cc < 6; ++cc) {
          s8v bb = *(const s8v*)(wb + (size_t)(cc*16 + lr)*96 + k0*32 + lg*8);
          acc[cc] = mfma16(a, bb, acc[cc]);
        }
      }
    }
    #pragma unroll
    for (int cc = 0; cc < 6; ++cc) {
      int c = cc*16 + lr;
      if (c < 90) {
        int o = gch*90 + c;
        float bv = bias[o];
        #pragma unroll
        for (int i = 0; i < 4; ++i) {
          int oi = 16*wid + lg*4 + i;
          int oy = oi>>3, ox = oi&7;
          cbn[(size_t)(b*9216 + (h0+oy)*96 + (w0+ox))*192 + o] = f2b(acc[cc][i] + bv);
        }
      }
    }
  }
  for (int idx = tid; idx < 64*12; idx += 256) {
    int pxi = idx/12, j = idx - (idx/12)*12;
    int oy = pxi>>3, ox = pxi&7;
    cbn[(size_t)(b*9216 + (h0+oy)*96 + (w0+ox))*192 + 180 + j] = 0;
  }
}

// ---------------- pe ----------------
__global__ __launch_bounds__(256) void k_pe_mfma(const unsigned short* __restrict__ cbn,
    const unsigned short* __restrict__ wpe, const float* __restrict__ bias,
    const float* __restrict__ x1, float* __restrict__ outp){
  __shared__ unsigned short A[64*200];
  int blk = blockIdx.x, tid = threadIdx.x;
  int b = blk/144, p0 = (blk - b*144)*64;
  for (int idx = tid; idx < 64*192; idx += 256) {
    int i = idx/192, k = idx - i*192;
    A[i*200 + k] = cbn[(size_t)(b*9216 + p0 + i)*192 + k];
  }
  __syncthreads();
  int wid = tid>>6, lane = tid&63, lr = lane&15, lg = lane>>4;
  const unsigned short* arow = A + (16*wid + lr)*200 + lg*8;
  #pragma unroll
  for (int pp = 0; pp < 6; ++pp) {
    int c0 = pp*32;
    f4v acc0 = {0.f,0.f,0.f,0.f}, acc1 = {0.f,0.f,0.f,0.f};
    #pragma unroll
    for (int k0 = 0; k0 < 6; ++k0) {
      s8v a  = *(const s8v*)(arow + k0*32);
      s8v b0 = *(const s8v*)(wpe + (size_t)(c0 + lr)*192 + k0*32 + lg*8);
      s8v b1 = *(const s8v*)(wpe + (size_t)(c0 + 16 + lr)*192 + k0*32 + lg*8);
      acc0 = mfma16(a, b0, acc0);
      acc1 = mfma16(a, b1, acc1);
    }
    #pragma unroll
    for (int i = 0; i < 4; ++i) {
      int px = 16*wid + lg*4 + i;
      size_t rowo = (size_t)(b*9216 + p0 + px)*180;
      int c = c0 + lr;
      if (c < 180) outp[rowo + c] = x1[rowo + c] + acc0[i] + bias[c];
      int c2 = c0 + 16 + lr;
      if (c2 < 180) outp[rowo + c2] = x1[rowo + c2] + acc1[i] + bias[c2];
    }
  }
}

// ---------------- fc1 + gelu ----------------
__global__ __launch_bounds__(256) void k_fc1_mfma(const float* __restrict__ xo,
    const unsigned short* __restrict__ wf1, const float* __restrict__ bias,
    unsigned short* __restrict__ hbuf){
  __shared__ unsigned short A[64*200];
  int blk = blockIdx.x, tid = threadIdx.x;
  int r0 = blk*64;
  for (int idx = tid; idx < 64*192; idx += 256) {
    int i = idx/192, k = idx - i*192;
    A[i*200 + k] = (k < 180) ? f2b(xo[(size_t)(r0 + i)*180 + k]) : (unsigned short)0;
  }
  __syncthreads();
  int wid = tid>>6, lane = tid&63, lr = lane&15, lg = lane>>4;
  const unsigned short* arow = A + (16*wid + lr)*200 + lg*8;
  for (int pp = 0; pp < 23; ++pp) {
    int c0 = pp*32;
    f4v acc0 = {0.f,0.f,0.f,0.f}, acc1 = {0.f,0.f,0.f,0.f};
    #pragma unroll
    for (int k0 = 0; k0 < 6; ++k0) {
      s8v a  = *(const s8v*)(arow + k0*32);
      s8v b0 = *(const s8v*)(wf1 + (size_t)(c0 + lr)*192 + k0*32 + lg*8);
      s8v b1 = *(const s8v*)(wf1 + (size_t)(c0 + 16 + lr)*192 + k0*32 + lg*8);
      acc0 = mfma16(a, b0, acc0);
      acc1 = mfma16(a, b1, acc1);
    }
    int c  = c0 + lr, c2 = c0 + 16 + lr;
    #pragma unroll
    for (int i = 0; i < 4; ++i) {
      size_t r = (size_t)r0 + 16*wid + lg*4 + i;
      hbuf[r*736 + c ] = (c  < 720) ? f2b(geluf(acc0[i] + bias[c ])) : (unsigned short)0;
      hbuf[r*736 + c2] = (c2 < 720) ? f2b(geluf(acc1[i] + bias[c2])) : (unsigned short)0;
    }
  }
}

// ---------------- fc2 + norm2 LN + residual ----------------
__global__ __launch_bounds__(256) void k_fc2_mfma(const unsigned short* __restrict__ hbuf,
    const unsigned short* __restrict__ wf2, const float* __restrict__ bias,
    const float* __restrict__ g2, const float* __restrict__ b2,
    float* __restrict__ outp){
  int blk = blockIdx.x, tid = threadIdx.x;
  int r0 = blk*64;
  int wid = tid>>6, lane = tid&63, lr = lane&15, lg = lane>>4;
  const unsigned short* arow = hbuf + (size_t)(r0 + 16*wid + lr)*736 + lg*8;
  f4v z = {0.f,0.f,0.f,0.f};
  f4v acc[12];
  #pragma unroll
  for (int cc = 0; cc < 12; ++cc) acc[cc] = z;
  for (int k0 = 0; k0 < 23; ++k0) {
    s8v a = *(const s8v*)(arow + k0*32);
    #pragma unroll
    for (int cc = 0; cc < 12; ++cc) {
      s8v b = *(const s8v*)(wf2 + (size_t)(cc*16 + lr)*736 + k0*32 + lg*8);
      acc[cc] = mfma16(a, b, acc[cc]);
    }
  }
  float psum[4] = {0,0,0,0}, psq[4] = {0,0,0,0};
  #pragma unroll
  for (int cc = 0; cc < 12; ++cc) {
    int c = cc*16 + lr;
    float bv = (c < 180) ? bias[c] : 0.f;
    #pragma unroll
    for (int i = 0; i < 4; ++i) {
      float v = (c < 180) ? acc[cc][i] + bv : 0.f;
      acc[cc][i] = v;
      psum[i] += v; psq[i] += v*v;
    }
  }
  float m[4], rs[4];
  #pragma unroll
  for (int i = 0; i < 4; ++i) {
    float s = rsum16(psum[i]), s2 = rsum16(psq[i]);
    m[i] = s*(1.f/180.f);
    float var = fmaxf(s2*(1.f/180.f) - m[i]*m[i], 0.f);
    rs[i] = rsqrtf(var + 1e-5f);
  }
  #pragma unroll
  for (int cc = 0; cc < 12; ++cc) {
    int c = cc*16 + lr;
    if (c < 180) {
      #pragma unroll
      for (int i = 0; i < 4; ++i) {
        size_t o = (size_t)(r0 + 16*wid + lg*4 + i)*180 + c;
        outp[o] = outp[o] + (acc[cc][i] - m[i])*rs[i]*g2[c] + b2[c];
      }
    }
  }
}

// ---------------- launch ----------------
extern "C" void kernel_launch(void* const* d_in, const int* in_sizes, int n_in,
                              void* d_out, int out_size, void* d_ws, size_t ws_size,
                              hipStream_t stream) {
  const float* x      = (const float*)d_in[0];
  const float* qkv_w  = (const float*)d_in[1];
  const float* q_bias = (const float*)d_in[2];
  const float* v_bias = (const float*)d_in[3];
  const float* lsc    = (const float*)d_in[4];
  const float* cpb_w1 = (const float*)d_in[5];
  const float* cpb_b1 = (const float*)d_in[6];
  const float* cpb_w2 = (const float*)d_in[7];
  const float* proj_w = (const float*)d_in[8];
  const float* proj_b = (const float*)d_in[9];
  const float* n1g    = (const float*)d_in[10];
  const float* n1b    = (const float*)d_in[11];
  const float* n2g    = (const float*)d_in[12];
  const float* n2b    = (const float*)d_in[13];
  const float* fc1w   = (const float*)d_in[14];
  const float* fc1b   = (const float*)d_in[15];
  const float* fc2w   = (const float*)d_in[16];
  const float* fc2b   = (const float*)d_in[17];
  const float* p1w    = (const float*)d_in[18];
  const float* p1b    = (const float*)d_in[19];
  const float* pww    = (const float*)d_in[20];
  const float* pwb    = (const float*)d_in[21];
  const float* dww    = (const float*)d_in[22];
  const float* dwb    = (const float*)d_in[23];
  const float* ddw    = (const float*)d_in[24];
  const float* ddb    = (const float*)d_in[25];
  const float* p2w    = (const float*)d_in[26];
  const float* p2b    = (const float*)d_in[27];
  const float* vlng   = (const float*)d_in[28];
  const float* vlnb   = (const float*)d_in[29];
  const float* cbw    = (const float*)d_in[30];
  const float* cbb    = (const float*)d_in[31];
  const float* pew    = (const float*)d_in[32];
  const float* peb    = (const float*)d_in[33];
  float* out = (float*)d_out;
  char* ws = (char*)d_ws;

  unsigned short* qkv  = (unsigned short*)(ws + OFF_QKV);
  unsigned short* awin = (unsigned short*)(ws + OFF_AWIN);
  float* x1   = (float*)(ws + OFF_X1);
  float* v1   = (float*)(ws + OFF_V1);
  float* ab1  = (float*)(ws + OFF_AB1);
  float* ab2  = (float*)(ws + OFF_AB2);
  unsigned short* vnb = (unsigned short*)(ws + OFF_VNB);
  unsigned short* cbn = (unsigned short*)(ws + OFF_CBN);
  unsigned short* hbf = (unsigned short*)(ws + OFF_H);
  float* tbl   = (float*)(ws + O_TBL);
  float* biasA = (float*)(ws + O_BIASA);
  unsigned short* wq  = (unsigned short*)(ws + O_WQ);
  unsigned short* wpj = (unsigned short*)(ws + O_WPJ);
  unsigned short* wpe = (unsigned short*)(ws + O_WPE);
  unsigned short* wp1 = (unsigned short*)(ws + O_WP1);
  unsigned short* wpw = (unsigned short*)(ws + O_WPW);
  unsigned short* wp2 = (unsigned short*)(ws + O_WP2);
  unsigned short* wf1 = (unsigned short*)(ws + O_WF1);
  unsigned short* wf2 = (unsigned short*)(ws + O_WF2);
  unsigned short* wcb = (unsigned short*)(ws + O_WCB);

  // prep
  k_cpb_tbl<<<225, 512, 0, stream>>>(cpb_w1, cpb_b1, cpb_w2, tbl);
  k_cpb_bias<<<96, 256, 0, stream>>>(tbl, biasA);
  k_cvtpad<<<(544*192+255)/256, 256, 0, stream>>>(qkv_w, wq, 540, 180, 192, 544*192);
  k_cvtpad<<<(192*192+255)/256, 256, 0, stream>>>(proj_w, wpj, 180, 180, 192, 192*192);
  k_cvtpad<<<(192*192+255)/256, 256, 0, stream>>>(pew, wpe, 180, 180, 192, 192*192);
  k_cvtpad<<<(96*192+255)/256, 256, 0, stream>>>(p1w, wp1, 96, 180, 192, 96*192);
  k_cvtpad<<<(96*96+255)/256, 256, 0, stream>>>(pww, wpw, 96, 96, 96, 96*96);
  k_cvtpad<<<(192*96+255)/256, 256, 0, stream>>>(p2w, wp2, 180, 96, 96, 192*96);
  k_cvtpad<<<(736*192+255)/256, 256, 0, stream>>>(fc1w, wf1, 720, 180, 192, 736*192);
  k_cvtpad<<<(192*736+255)/256, 256, 0, stream>>>(fc2w, wf2, 180, 720, 736, 192*736);
  k_cvt_wcb<<<(18*96*96+255)/256, 256, 0, stream>>>(cbw, wcb);
  // main chain
  k_qkv_mfma<<<NWIN, 256, 0, stream>>>(x, wq, q_bias, v_bias, qkv);
  k_attn_mfma<<<NWIN*6, 256, 0, stream>>>(qkv, biasA, lsc, awin);
  k_proj_mfma<<<NWIN, 256, 0, stream>>>(awin, wpj, proj_b, n1g, n1b, x, x1);
  k_p1_mfma<<<NWIN, 256, 0, stream>>>(x1, wp1, p1b, v1);
  k_pw_mfma<<<NWIN, 256, 0, stream>>>(v1, wpw, pwb, ab1);
  k_dwc<<<27648, 256, 0, stream>>>(ab1, dww, dwb, ab2, 1);
  k_dwc<<<27648, 256, 0, stream>>>(ab2, ddw, ddb, ab1, 3);
  k_p2ln_mfma<<<NWIN, 256, 0, stream>>>(v1, ab1, x1, wp2, p2b, vlng, vlnb, vnb);
  k_cb_mfma<<<NWIN, 256, 0, stream>>>(vnb, wcb, cbb, cbn);
  k_pe_mfma<<<NWIN, 256, 0, stream>>>(cbn, wpe, peb, x1, out);
  k_fc1_mfma<<<NWIN, 256, 0, stream>>>(out, wf1, fc1b, hbf);
  k_fc2_mfma<<<NWIN, 256, 0, stream>>>(hbf, wf2, fc2b, n2g, n2b, out);
}

// Round 7
// 982.642 us; speedup vs baseline: 5.0672x; 1.1572x over previous
//
#include <hip/hip_runtime.h>
#include <hip/hip_bf16.h>

#define DEV __device__ __forceinline__

typedef __attribute__((ext_vector_type(8))) short s8v;   // 8 bf16 (4 VGPR)
typedef __attribute__((ext_vector_type(4))) float f4v;   // MFMA acc

static constexpr int NWIN = 1152;
static constexpr int NROW = 73728;

// ---------------- workspace layout (peak < 185.8 MB) ----
static constexpr size_t OFF_QKV  = 0;            // bf16 [NROW][540]  (dead after attn)
static constexpr size_t OFF_AWIN = 79626240;     // bf16 [NROW][180]  (dead after proj)
static constexpr size_t OFF_X1   = 132710400;    // f32  [NROW][180]  (live until pe/p2)
static constexpr size_t OFF_V1   = 0;            // f32  NCHW [8*96][9216]
static constexpr size_t OFF_AB1  = 28311552;     // f32  NCHW
static constexpr size_t OFF_AB2  = 56623104;     // f32  NCHW
static constexpr size_t OFF_VNB  = 56623104;     // bf16 NHWC [NROW][192] (over ab2, dead) — group-padded layout
static constexpr size_t OFF_CBN  = 0;            // bf16 NHWC [NROW][192] (over v1, dead)
static constexpr size_t OFF_H    = 0;            // bf16 [NROW][736]  (over conv temps, dead)
static constexpr size_t WB       = 130613248;
static constexpr size_t O_TBL    = WB;                    // f32 [225][6]
static constexpr size_t O_BIASA  = WB + 8192;             // f32 [6][64][64]
static constexpr size_t O_WQ     = WB + 106496;           // bf16 packed frag-major [34*6*512]
static constexpr size_t O_WPJ    = O_WQ  + 208896;        // bf16 [192][192]
static constexpr size_t O_WPE    = O_WPJ + 73728;         // bf16 [192][192]
static constexpr size_t O_WP1    = O_WPE + 73728;         // bf16 [96][192]
static constexpr size_t O_WPW    = O_WP1 + 36864;         // bf16 [96][96]
static constexpr size_t O_WP2    = O_WPW + 18432;         // bf16 [192][96]
static constexpr size_t O_WF1    = O_WP2 + 36864;         // bf16 packed frag-major [45*6*512]
static constexpr size_t O_WF2    = O_WF1 + 282624;        // bf16 [192][736]
static constexpr size_t O_WCB    = O_WF2 + 282624;        // bf16 [18][96][96]

DEV float geluf(float x){ return 0.5f*x*(1.f + erff(x*0.70710678118654752f)); }

DEV unsigned short f2b(float v){
  union { __hip_bfloat16 h; unsigned short u; } x;
  x.h = __float2bfloat16(v);
  return x.u;
}

DEV float b2f(unsigned short u){
  union { float f; unsigned u; } x;
  x.u = ((unsigned)u) << 16;
  return x.f;
}

DEV f4v mfma16(s8v a, s8v b, f4v c){
  return __builtin_amdgcn_mfma_f32_16x16x32_bf16(a, b, c, 0, 0, 0);
}

DEV float rsum16(float v){
  v += __shfl_xor(v, 1); v += __shfl_xor(v, 2);
  v += __shfl_xor(v, 4); v += __shfl_xor(v, 8);
  return v;
}

DEV float rmax16(float v){
  v = fmaxf(v, __shfl_xor(v, 1)); v = fmaxf(v, __shfl_xor(v, 2));
  v = fmaxf(v, __shfl_xor(v, 4)); v = fmaxf(v, __shfl_xor(v, 8));
  return v;
}

DEV float qkvbias(int c, const float* qb, const float* vb){
  return (c < 180) ? qb[c] : (c < 360 ? 0.f : vb[c-360]);
}

// ---------------- CPB MLP table ----------------
__global__ __launch_bounds__(512) void k_cpb_tbl(const float* __restrict__ w1,
    const float* __restrict__ b1, const float* __restrict__ w2, float* __restrict__ tbl){
  int m = blockIdx.x, tid = threadIdx.x;
  int i = m/15, j = m - (m/15)*15;
  float t0 = (float)(i-7)*(8.f/7.f), t1 = (float)(j-7)*(8.f/7.f);
  float f0 = log2f(fabsf(t0)+1.f)*(1.f/3.f); if (t0 < 0.f) f0 = -f0;
  float f1 = log2f(fabsf(t1)+1.f)*(1.f/3.f); if (t1 < 0.f) f1 = -f1;
  float hv = fmaxf(f0*w1[2*tid] + f1*w1[2*tid+1] + b1[tid], 0.f);
  __shared__ float red[6][8];
  int lane = tid & 63, wv = tid >> 6;
  for (int h = 0; h < 6; ++h) {
    float p = hv * w2[h*512 + tid];
    for (int off = 32; off; off >>= 1) p += __shfl_down(p, off);
    if (lane == 0) red[h][wv] = p;
  }
  __syncthreads();
  if (tid < 6) {
    float s = 0.f;
    for (int w = 0; w < 8; ++w) s += red[tid][w];
    tbl[m*6 + tid] = s;
  }
}

__global__ __launch_bounds__(256) void k_cpb_bias(const float* __restrict__ tbl,
    float* __restrict__ biasA){
  int idx = blockIdx.x*256 + threadIdx.x;
  if (idx >= 6*64*64) return;
  int h = idx >> 12, n = (idx >> 6) & 63, m = idx & 63;
  int dh = (n>>3) - (m>>3) + 7, dw = (n&7) - (m&7) + 7;
  float v = tbl[(dh*15 + dw)*6 + h];
  biasA[idx] = 16.f / (1.f + expf(-v));
}

// ---------------- weight convert + pad (row-major [col][k]) ----------------
__global__ __launch_bounds__(256) void k_cvtpad(const float* __restrict__ src,
    unsigned short* __restrict__ dst, int R, int K, int Kp, int total){
  int idx = blockIdx.x*256 + threadIdx.x;
  if (idx >= total) return;
  int r = idx / Kp, k = idx - r*Kp;
  float v = (r < R && k < K) ? src[r*K + k] : 0.f;
  dst[idx] = f2b(v);
}

// ---------------- weight pack: fragment-major for coalesced B-fragment loads -
// dst[((ct*KS + ks)*64 + l)*8 + j] = W[ct*16 + (l&15)][ks*32 + (l>>4)*8 + j]
__global__ __launch_bounds__(256) void k_pack(const float* __restrict__ src,
    unsigned short* __restrict__ dst, int Ncols, int K, int CT, int KS){
  int idx = blockIdx.x*256 + threadIdx.x;
  int total = CT*KS*512;
  if (idx >= total) return;
  int j = idx & 7, l = (idx >> 3) & 63, f = idx >> 9;
  int ks = f - (f/KS)*KS, ct = f/KS;
  int col = ct*16 + (l & 15);
  int k = ks*32 + (l >> 4)*8 + j;
  float v = (col < Ncols && k < K) ? src[col*K + k] : 0.f;
  dst[idx] = f2b(v);
}

__global__ __launch_bounds__(256) void k_cvt_wcb(const float* __restrict__ cbw,
    unsigned short* __restrict__ dst){
  int idx = blockIdx.x*256 + threadIdx.x;
  if (idx >= 18*96*96) return;
  int row = idx/96, ci = idx - row*96;
  int g9 = row/96, o = row - g9*96;
  int gch = g9/9, tap = g9 - gch*9;
  float v = (o < 90 && ci < 90) ? cbw[((gch*90 + o)*90 + ci)*9 + tap] : 0.f;
  dst[idx] = f2b(v);
}

// ---------------- qkv: wave-owns-columns + packed B -> qkv bf16 [NROW][540] --
__global__ __launch_bounds__(256) void k_qkv_mfma(const float* __restrict__ x,
    const unsigned short* __restrict__ wqp, const float* __restrict__ qb,
    const float* __restrict__ vb, unsigned short* __restrict__ qkv){
  __shared__ unsigned short A[64*200];
  __shared__ int rowOff[64];
  int win = blockIdx.x, tid = threadIdx.x;
  if (tid < 64) {
    int b = win/144, rem = win - b*144, wh = rem/12, ww = rem - (rem/12)*12;
    int l = (wh*8 + (tid>>3))*96 + ww*8 + (tid&7);
    rowOff[tid] = (b*9216 + l)*180;
  }
  __syncthreads();
  for (int idx = tid; idx < 64*192; idx += 256) {
    int i = idx/192, k = idx - i*192;
    A[i*200 + k] = (k < 180) ? f2b(x[rowOff[i] + k]) : (unsigned short)0;
  }
  __syncthreads();
  int wid = tid>>6, lane = tid&63, lr = lane&15, lg = lane>>4;
  f4v z = {0.f,0.f,0.f,0.f};
  for (int ct = wid; ct < 34; ct += 4) {
    f4v acc[4];
    #pragma unroll
    for (int rg = 0; rg < 4; ++rg) acc[rg] = z;
    #pragma unroll
    for (int k0 = 0; k0 < 6; ++k0) {
      s8v b = *(const s8v*)(wqp + (size_t)((ct*6 + k0)*64 + lane)*8);
      #pragma unroll
      for (int rg = 0; rg < 4; ++rg) {
        s8v a = *(const s8v*)(A + (16*rg + lr)*200 + k0*32 + lg*8);
        acc[rg] = mfma16(a, b, acc[rg]);
      }
    }
    int c = ct*16 + lr;
    if (c < 540) {
      float bias = qkvbias(c, qb, vb);
      #pragma unroll
      for (int rg = 0; rg < 4; ++rg)
        #pragma unroll
        for (int i = 0; i < 4; ++i)
          qkv[(size_t)(win*64 + 16*rg + lg*4 + i)*540 + c] = f2b(acc[rg][i] + bias);
    }
  }
}

// ---------------- attention (MFMA) per (window, head) -> awin bf16 -----------
__global__ __launch_bounds__(256) void k_attn_mfma(const unsigned short* __restrict__ qkv,
    const float* __restrict__ biasA, const float* __restrict__ lsc,
    unsigned short* __restrict__ awin){
  __shared__ __align__(16) unsigned short Qs[64*40];   // [n][d] stride 40
  __shared__ __align__(16) unsigned short Ks[64*40];   // [m][d] stride 40
  __shared__ __align__(16) unsigned short Vt[32*72];   // [d][m] stride 72
  __shared__ __align__(16) unsigned short Ps[64*72];   // [n][m] stride 72
  __shared__ float invq[64], invk[64];
  int blk = blockIdx.x;
  int win = blk/6, h = blk - win*6;
  int tid = threadIdx.x;
  for (int idx = tid; idx < 2048; idx += 256) {
    int n = idx >> 5, d = idx & 31;
    unsigned short qv = 0, kv = 0, vv = 0;
    if (d < 30) {
      size_t row = (size_t)(win*64 + n)*540;
      qv = qkv[row + h*30 + d];
      kv = qkv[row + 180 + h*30 + d];
      vv = qkv[row + 360 + h*30 + d];
    }
    Qs[n*40 + d] = qv; Ks[n*40 + d] = kv; Vt[d*72 + n] = vv;
  }
  __syncthreads();
  if (tid < 128) {
    int n = tid & 63;
    const unsigned short* base = (tid < 64) ? (Qs + n*40) : (Ks + n*40);
    float s = 0.f;
    for (int d = 0; d < 30; ++d) { float v = b2f(base[d]); s += v*v; }
    float inv = 1.f / fmaxf(sqrtf(s), 1e-12f);
    if (tid < 64) invq[n] = inv; else invk[n] = inv;
  }
  __syncthreads();
  int wid = tid>>6, lane = tid&63, lr = lane&15, lg = lane>>4;
  float scale = __expf(fminf(lsc[h], 4.6051701859880914f));
  f4v z = {0.f,0.f,0.f,0.f};
  s8v aq = *(const s8v*)(Qs + (16*wid + lr)*40 + lg*8);
  f4v sacc[4];
  #pragma unroll
  for (int tc = 0; tc < 4; ++tc) {
    s8v bk = *(const s8v*)(Ks + (16*tc + lr)*40 + lg*8);
    sacc[tc] = mfma16(aq, bk, z);
  }
  float iq[4], ikv[4];
  #pragma unroll
  for (int i = 0; i < 4; ++i) iq[i] = invq[16*wid + lg*4 + i] * scale;
  #pragma unroll
  for (int tc = 0; tc < 4; ++tc) ikv[tc] = invk[16*tc + lr];
  float p[4][4];   // [tc][i]
  #pragma unroll
  for (int tc = 0; tc < 4; ++tc) {
    int col = 16*tc + lr;
    #pragma unroll
    for (int i = 0; i < 4; ++i) {
      int row = 16*wid + lg*4 + i;
      p[tc][i] = sacc[tc][i]*iq[i]*ikv[tc] + biasA[((h*64 + row) << 6) + col];
    }
  }
  float rin[4];
  #pragma unroll
  for (int i = 0; i < 4; ++i) {
    float mx = fmaxf(fmaxf(p[0][i], p[1][i]), fmaxf(p[2][i], p[3][i]));
    mx = rmax16(mx);
    float sum = 0.f;
    #pragma unroll
    for (int tc = 0; tc < 4; ++tc) { p[tc][i] = __expf(p[tc][i] - mx); sum += p[tc][i]; }
    sum = rsum16(sum);
    rin[i] = 1.f / sum;
  }
  #pragma unroll
  for (int tc = 0; tc < 4; ++tc)
    #pragma unroll
    for (int i = 0; i < 4; ++i)
      Ps[(16*wid + lg*4 + i)*72 + 16*tc + lr] = f2b(p[tc][i]*rin[i]);
  __syncthreads();
  f4v o0 = z, o1 = z;
  #pragma unroll
  for (int k0 = 0; k0 < 2; ++k0) {
    s8v pa = *(const s8v*)(Ps + (16*wid + lr)*72 + k0*32 + lg*8);
    s8v b0 = *(const s8v*)(Vt + lr*72        + k0*32 + lg*8);
    s8v b1 = *(const s8v*)(Vt + (16 + lr)*72 + k0*32 + lg*8);
    o0 = mfma16(pa, b0, o0);
    o1 = mfma16(pa, b1, o1);
  }
  #pragma unroll
  for (int i = 0; i < 4; ++i) {
    int row = 16*wid + lg*4 + i;
    size_t base = (size_t)(win*64 + row)*180 + h*30;
    awin[base + lr] = f2b(o0[i]);
    int c1 = 16 + lr;
    if (c1 < 30) awin[base + c1] = f2b(o1[i]);
  }
}

// ---------------- proj + norm1 LN (in-register) + residual + win-reverse -----
__global__ __launch_bounds__(256) void k_proj_mfma(const unsigned short* __restrict__ awin,
    const unsigned short* __restrict__ wpj, const float* __restrict__ pb,
    const float* __restrict__ g1, const float* __restrict__ b1,
    const float* __restrict__ x, float* __restrict__ x1){
  __shared__ unsigned short A[64*200];
  int win = blockIdx.x, tid = threadIdx.x;
  size_t rb = (size_t)win*64;
  for (int idx = tid; idx < 64*192; idx += 256) {
    int i = idx/192, k = idx - i*192;
    A[i*200 + k] = (k < 180) ? awin[(rb + i)*180 + k] : (unsigned short)0;
  }
  __syncthreads();
  int wid = tid>>6, lane = tid&63, lr = lane&15, lg = lane>>4;
  const unsigned short* arow = A + (16*wid + lr)*200 + lg*8;
  f4v z = {0.f,0.f,0.f,0.f};
  f4v acc[12];
  #pragma unroll
  for (int cc = 0; cc < 12; ++cc) acc[cc] = z;
  #pragma unroll
  for (int k0 = 0; k0 < 6; ++k0) {
    s8v a = *(const s8v*)(arow + k0*32);
    #pragma unroll
    for (int cc = 0; cc < 12; ++cc) {
      s8v b = *(const s8v*)(wpj + (size_t)(cc*16 + lr)*192 + k0*32 + lg*8);
      acc[cc] = mfma16(a, b, acc[cc]);
    }
  }
  float psum[4] = {0,0,0,0}, psq[4] = {0,0,0,0};
  #pragma unroll
  for (int cc = 0; cc < 12; ++cc) {
    int c = cc*16 + lr;
    float bias = (c < 180) ? pb[c] : 0.f;
    #pragma unroll
    for (int i = 0; i < 4; ++i) {
      float v = (c < 180) ? acc[cc][i] + bias : 0.f;
      acc[cc][i] = v;
      psum[i] += v; psq[i] += v*v;
    }
  }
  float m[4], rs[4];
  #pragma unroll
  for (int i = 0; i < 4; ++i) {
    float s = rsum16(psum[i]), s2 = rsum16(psq[i]);
    m[i] = s*(1.f/180.f);
    float var = fmaxf(s2*(1.f/180.f) - m[i]*m[i], 0.f);
    rs[i] = rsqrtf(var + 1e-5f);
  }
  int b = win/144, rem = win - b*144, wh = rem/12, ww = rem - (rem/12)*12;
  #pragma unroll
  for (int cc = 0; cc < 12; ++cc) {
    int c = cc*16 + lr;
    if (c < 180) {
      #pragma unroll
      for (int i = 0; i < 4; ++i) {
        int r = 16*wid + lg*4 + i;
        int l = (wh*8 + (r>>3))*96 + ww*8 + (r&7);
        size_t o = (size_t)(b*9216 + l)*180 + c;
        x1[o] = x[o] + (acc[cc][i] - m[i])*rs[i]*g1[c] + b1[c];
      }
    }
  }
}

// ---------------- VAB p1 ----------------
__global__ __launch_bounds__(256) void k_p1_mfma(const float* __restrict__ x1,
    const unsigned short* __restrict__ wp1, const float* __restrict__ bias,
    float* __restrict__ v1){
  __shared__ unsigned short A[64*200];
  int blk = blockIdx.x, tid = threadIdx.x;
  int b = blk/144, p0 = (blk - b*144)*64;
  int rowb = b*9216 + p0;
  for (int idx = tid; idx < 64*192; idx += 256) {
    int i = idx/192, k = idx - i*192;
    A[i*200 + k] = (k < 180) ? f2b(x1[(size_t)(rowb + i)*180 + k]) : (unsigned short)0;
  }
  __syncthreads();
  int wid = tid>>6, lane = tid&63, lr = lane&15, lg = lane>>4;
  const unsigned short* arow = A + (16*wid + lr)*200 + lg*8;
  #pragma unroll
  for (int pp = 0; pp < 3; ++pp) {
    int c0 = pp*32;
    f4v acc0 = {0.f,0.f,0.f,0.f}, acc1 = {0.f,0.f,0.f,0.f};
    #pragma unroll
    for (int k0 = 0; k0 < 6; ++k0) {
      s8v a  = *(const s8v*)(arow + k0*32);
      s8v b0 = *(const s8v*)(wp1 + (size_t)(c0 + lr)*192 + k0*32 + lg*8);
      s8v b1 = *(const s8v*)(wp1 + (size_t)(c0 + 16 + lr)*192 + k0*32 + lg*8);
      acc0 = mfma16(a, b0, acc0);
      acc1 = mfma16(a, b1, acc1);
    }
    int c  = c0 + lr, c2 = c0 + 16 + lr;
    float bv = bias[c], bv2 = bias[c2];
    #pragma unroll
    for (int i = 0; i < 4; ++i) {
      int px = 16*wid + lg*4 + i;
      v1[(size_t)(b*96 + c )*9216 + p0 + px] = geluf(acc0[i] + bv );
      v1[(size_t)(b*96 + c2)*9216 + p0 + px] = geluf(acc1[i] + bv2);
    }
  }
}

// ---------------- VAB pw ----------------
__global__ __launch_bounds__(256) void k_pw_mfma(const float* __restrict__ v1,
    const unsigned short* __restrict__ wpw, const float* __restrict__ bias,
    float* __restrict__ outp){
  __shared__ unsigned short A[64*104];
  int blk = blockIdx.x, tid = threadIdx.x;
  int b = blk/144, p0 = (blk - b*144)*64;
  for (int idx = tid; idx < 96*64; idx += 256) {
    int k = idx >> 6, i = idx & 63;
    A[i*104 + k] = f2b(v1[(size_t)(b*96 + k)*9216 + p0 + i]);
  }
  __syncthreads();
  int wid = tid>>6, lane = tid&63, lr = lane&15, lg = lane>>4;
  const unsigned short* arow = A + (16*wid + lr)*104 + lg*8;
  #pragma unroll
  for (int pp = 0; pp < 3; ++pp) {
    int c0 = pp*32;
    f4v acc0 = {0.f,0.f,0.f,0.f}, acc1 = {0.f,0.f,0.f,0.f};
    #pragma unroll
    for (int k0 = 0; k0 < 3; ++k0) {
      s8v a  = *(const s8v*)(arow + k0*32);
      s8v b0 = *(const s8v*)(wpw + (size_t)(c0 + lr)*96 + k0*32 + lg*8);
      s8v b1 = *(const s8v*)(wpw + (size_t)(c0 + 16 + lr)*96 + k0*32 + lg*8);
      acc0 = mfma16(a, b0, acc0);
      acc1 = mfma16(a, b1, acc1);
    }
    int c  = c0 + lr, c2 = c0 + 16 + lr;
    float bv = bias[c], bv2 = bias[c2];
    #pragma unroll
    for (int i = 0; i < 4; ++i) {
      int px = 16*wid + lg*4 + i;
      outp[(size_t)(b*96 + c )*9216 + p0 + px] = acc0[i] + bv;
      outp[(size_t)(b*96 + c2)*9216 + p0 + px] = acc1[i] + bv2;
    }
  }
}

// ---------------- depthwise 5x5 ----------------
__global__ __launch_bounds__(256) void k_dwc(const float* __restrict__ in,
    const float* __restrict__ w, const float* __restrict__ bias,
    float* __restrict__ out, int dil){
  int blk = blockIdx.x, tid = threadIdx.x;
  int bc = blk/36, pc = blk - bc*36;
  int c = bc - (bc/96)*96;
  int p = pc*256 + tid;
  int hh = p/96, ww = p - hh*96;
  float acc = bias[c];
  const float* wc = w + c*25;
  const float* inb = in + (size_t)bc*9216;
  #pragma unroll
  for (int i = 0; i < 5; ++i) {
    int y = hh + dil*(i-2);
    if (y < 0 || y >= 96) continue;
    #pragma unroll
    for (int j = 0; j < 5; ++j) {
      int xq = ww + dil*(j-2);
      if (xq >= 0 && xq < 96) acc += inb[y*96 + xq]*wc[i*5 + j];
    }
  }
  out[(size_t)bc*9216 + p] = acc;
}

// ---------------- p2 + residual + VAB-LN -> vnb NHWC bf16 (group-padded) -----
__global__ __launch_bounds__(256) void k_p2ln_mfma(const float* __restrict__ v1,
    const float* __restrict__ a3, const float* __restrict__ x1,
    const unsigned short* __restrict__ wp2, const float* __restrict__ bias,
    const float* __restrict__ lng, const float* __restrict__ lnb,
    unsigned short* __restrict__ vnb){
  __shared__ unsigned short A[64*104];
  int blk = blockIdx.x, tid = threadIdx.x;
  int b = blk/144, p0 = (blk - b*144)*64;
  for (int idx = tid; idx < 96*64; idx += 256) {
    int k = idx >> 6, i = idx & 63;
    size_t o = (size_t)(b*96 + k)*9216 + p0 + i;
    A[i*104 + k] = f2b(v1[o]*a3[o]);
  }
  __syncthreads();
  int wid = tid>>6, lane = tid&63, lr = lane&15, lg = lane>>4;
  const unsigned short* arow = A + (16*wid + lr)*104 + lg*8;
  f4v z = {0.f,0.f,0.f,0.f};
  f4v acc[12];
  #pragma unroll
  for (int cc = 0; cc < 12; ++cc) acc[cc] = z;
  #pragma unroll
  for (int k0 = 0; k0 < 3; ++k0) {
    s8v a = *(const s8v*)(arow + k0*32);
    #pragma unroll
    for (int cc = 0; cc < 12; ++cc) {
      s8v bb = *(const s8v*)(wp2 + (size_t)(cc*16 + lr)*96 + k0*32 + lg*8);
      acc[cc] = mfma16(a, bb, acc[cc]);
    }
  }
  float psum[4] = {0,0,0,0}, psq[4] = {0,0,0,0};
  #pragma unroll
  for (int cc = 0; cc < 12; ++cc) {
    int c = cc*16 + lr;
    float bv = (c < 180) ? bias[c] : 0.f;
    #pragma unroll
    for (int i = 0; i < 4; ++i) {
      int px = 16*wid + lg*4 + i;
      float v = 0.f;
      if (c < 180) v = acc[cc][i] + bv + x1[(size_t)(b*9216 + p0 + px)*180 + c];
      acc[cc][i] = v;
      psum[i] += v; psq[i] += v*v;
    }
  }
  float m[4], rs[4];
  #pragma unroll
  for (int i = 0; i < 4; ++i) {
    float s = rsum16(psum[i]), s2 = rsum16(psq[i]);
    m[i] = s*(1.f/180.f);
    float var = fmaxf(s2*(1.f/180.f) - m[i]*m[i], 0.f);
    rs[i] = rsqrtf(var + 1e-5f);
  }
  #pragma unroll
  for (int cc = 0; cc < 12; ++cc) {
    int c = cc*16 + lr;
    if (c < 180) {
      int cpos = c + (c >= 90 ? 6 : 0);
      #pragma unroll
      for (int i = 0; i < 4; ++i) {
        int px = 16*wid + lg*4 + i;
        vnb[(size_t)(b*9216 + p0 + px)*192 + cpos] =
            f2b((acc[cc][i] - m[i])*rs[i]*lng[c] + lnb[c]);
      }
    }
  }
  // zero-fill pad slots 90..95 and 186..191
  for (int idx = tid; idx < 64*12; idx += 256) {
    int px = idx/12, j = idx - (idx/12)*12;
    int pos = (j < 6) ? (90 + j) : (180 + j);
    vnb[(size_t)(b*9216 + p0 + px)*192 + pos] = 0;
  }
}

// ---------------- convbody: 8x8 tile, halo staged ONCE, 9 shifted MFMA-GEMMs -
__global__ __launch_bounds__(256) void k_cb_mfma(const unsigned short* __restrict__ vnb,
    const unsigned short* __restrict__ wcb, const float* __restrict__ bias,
    unsigned short* __restrict__ cbn){
  __shared__ __align__(16) unsigned short S[100*200];   // 10x10 halo x 192ch, stride 200
  int blk = blockIdx.x, tid = threadIdx.x;
  int b = blk/144, t = blk - b*144;
  int th = t/12, tw = t - (t/12)*12;
  int h0 = th*8, w0 = tw*8;
  for (int idx = tid; idx < 2400; idx += 256) {
    int pix = idx/24, chunk = idx - pix*24;
    int hp = pix/10, wp = pix - hp*10;
    int h = h0 + hp - 1, w = w0 + wp - 1;
    s8v v = {0,0,0,0,0,0,0,0};
    if (h >= 0 && h < 96 && w >= 0 && w < 96)
      v = *(const s8v*)(vnb + (size_t)(b*9216 + h*96 + w)*192 + chunk*8);
    *(s8v*)(S + pix*200 + chunk*8) = v;
  }
  __syncthreads();
  int wid = tid>>6, lane = tid&63, lr = lane&15, lg = lane>>4;
  int ai = 16*wid + lr;
  int spBase = ((ai>>3) + 1)*10 + (ai&7) + 1;
  f4v z = {0.f,0.f,0.f,0.f};
  for (int gch = 0; gch < 2; ++gch) {
    f4v acc[6];
    #pragma unroll
    for (int cc = 0; cc < 6; ++cc) acc[cc] = z;
    #pragma unroll
    for (int tap = 0; tap < 9; ++tap) {
      int dh = tap/3 - 1, dw = tap - (tap/3)*3 - 1;
      const unsigned short* arow = S + (spBase + dh*10 + dw)*200 + gch*96 + lg*8;
      const unsigned short* wb = wcb + (size_t)(gch*9 + tap)*96*96;
      #pragma unroll
      for (int k0 = 0; k0 < 3; ++k0) {
        s8v a = *(const s8v*)(arow + k0*32);
        #pragma unroll
        for (int cc = 0; cc < 6; ++cc) {
          s8v bb = *(const s8v*)(wb + (size_t)(cc*16 + lr)*96 + k0*32 + lg*8);
          acc[cc] = mfma16(a, bb, acc[cc]);
        }
      }
    }
    #pragma unroll
    for (int cc = 0; cc < 6; ++cc) {
      int c = cc*16 + lr;
      if (c < 90) {
        int o = gch*90 + c;
        float bv = bias[o];
        #pragma unroll
        for (int i = 0; i < 4; ++i) {
          int oi = 16*wid + lg*4 + i;
          int oy = oi>>3, ox = oi&7;
          cbn[(size_t)(b*9216 + (h0+oy)*96 + (w0+ox))*192 + o] = f2b(acc[cc][i] + bv);
        }
      }
    }
  }
  for (int idx = tid; idx < 64*12; idx += 256) {
    int pxi = idx/12, j = idx - (idx/12)*12;
    int oy = pxi>>3, ox = pxi&7;
    cbn[(size_t)(b*9216 + (h0+oy)*96 + (w0+ox))*192 + 180 + j] = 0;
  }
}

// ---------------- pe ----------------
__global__ __launch_bounds__(256) void k_pe_mfma(const unsigned short* __restrict__ cbn,
    const unsigned short* __restrict__ wpe, const float* __restrict__ bias,
    const float* __restrict__ x1, float* __restrict__ outp){
  __shared__ unsigned short A[64*200];
  int blk = blockIdx.x, tid = threadIdx.x;
  int b = blk/144, p0 = (blk - b*144)*64;
  for (int idx = tid; idx < 64*192; idx += 256) {
    int i = idx/192, k = idx - i*192;
    A[i*200 + k] = cbn[(size_t)(b*9216 + p0 + i)*192 + k];
  }
  __syncthreads();
  int wid = tid>>6, lane = tid&63, lr = lane&15, lg = lane>>4;
  const unsigned short* arow = A + (16*wid + lr)*200 + lg*8;
  #pragma unroll
  for (int pp = 0; pp < 6; ++pp) {
    int c0 = pp*32;
    f4v acc0 = {0.f,0.f,0.f,0.f}, acc1 = {0.f,0.f,0.f,0.f};
    #pragma unroll
    for (int k0 = 0; k0 < 6; ++k0) {
      s8v a  = *(const s8v*)(arow + k0*32);
      s8v b0 = *(const s8v*)(wpe + (size_t)(c0 + lr)*192 + k0*32 + lg*8);
      s8v b1 = *(const s8v*)(wpe + (size_t)(c0 + 16 + lr)*192 + k0*32 + lg*8);
      acc0 = mfma16(a, b0, acc0);
      acc1 = mfma16(a, b1, acc1);
    }
    #pragma unroll
    for (int i = 0; i < 4; ++i) {
      int px = 16*wid + lg*4 + i;
      size_t rowo = (size_t)(b*9216 + p0 + px)*180;
      int c = c0 + lr;
      if (c < 180) outp[rowo + c] = x1[rowo + c] + acc0[i] + bias[c];
      int c2 = c0 + 16 + lr;
      if (c2 < 180) outp[rowo + c2] = x1[rowo + c2] + acc1[i] + bias[c2];
    }
  }
}

// ---------------- fc1: wave-owns-columns + packed B + gelu -> hbuf -----------
__global__ __launch_bounds__(256) void k_fc1_mfma(const float* __restrict__ xo,
    const unsigned short* __restrict__ wf1p, const float* __restrict__ bias,
    unsigned short* __restrict__ hbuf){
  __shared__ unsigned short A[64*200];
  int blk = blockIdx.x, tid = threadIdx.x;
  int r0 = blk*64;
  for (int idx = tid; idx < 64*192; idx += 256) {
    int i = idx/192, k = idx - i*192;
    A[i*200 + k] = (k < 180) ? f2b(xo[(size_t)(r0 + i)*180 + k]) : (unsigned short)0;
  }
  __syncthreads();
  int wid = tid>>6, lane = tid&63, lr = lane&15, lg = lane>>4;
  f4v z = {0.f,0.f,0.f,0.f};
  for (int ct = wid; ct < 45; ct += 4) {
    f4v acc[4];
    #pragma unroll
    for (int rg = 0; rg < 4; ++rg) acc[rg] = z;
    #pragma unroll
    for (int k0 = 0; k0 < 6; ++k0) {
      s8v b = *(const s8v*)(wf1p + (size_t)((ct*6 + k0)*64 + lane)*8);
      #pragma unroll
      for (int rg = 0; rg < 4; ++rg) {
        s8v a = *(const s8v*)(A + (16*rg + lr)*200 + k0*32 + lg*8);
        acc[rg] = mfma16(a, b, acc[rg]);
      }
    }
    int c = ct*16 + lr;              // always < 720 (45*16 == 720)
    float bv = bias[c];
    #pragma unroll
    for (int rg = 0; rg < 4; ++rg)
      #pragma unroll
      for (int i = 0; i < 4; ++i)
        hbuf[(size_t)(r0 + 16*rg + lg*4 + i)*736 + c] = f2b(geluf(acc[rg][i] + bv));
  }
  // zero pad cols 720..735
  for (int idx = tid; idx < 64*16; idx += 256) {
    int r = idx >> 4, j = idx & 15;
    hbuf[(size_t)(r0 + r)*736 + 720 + j] = 0;
  }
}

// ---------------- fc2 + norm2 LN + residual ----------------
__global__ __launch_bounds__(256) void k_fc2_mfma(const unsigned short* __restrict__ hbuf,
    const unsigned short* __restrict__ wf2, const float* __restrict__ bias,
    const float* __restrict__ g2, const float* __restrict__ b2,
    float* __restrict__ outp){
  int blk = blockIdx.x, tid = threadIdx.x;
  int r0 = blk*64;
  int wid = tid>>6, lane = tid&63, lr = lane&15, lg = lane>>4;
  const unsigned short* arow = hbuf + (size_t)(r0 + 16*wid + lr)*736 + lg*8;
  f4v z = {0.f,0.f,0.f,0.f};
  f4v acc[12];
  #pragma unroll
  for (int cc = 0; cc < 12; ++cc) acc[cc] = z;
  for (int k0 = 0; k0 < 23; ++k0) {
    s8v a = *(const s8v*)(arow + k0*32);
    #pragma unroll
    for (int cc = 0; cc < 12; ++cc) {
      s8v b = *(const s8v*)(wf2 + (size_t)(cc*16 + lr)*736 + k0*32 + lg*8);
      acc[cc] = mfma16(a, b, acc[cc]);
    }
  }
  float psum[4] = {0,0,0,0}, psq[4] = {0,0,0,0};
  #pragma unroll
  for (int cc = 0; cc < 12; ++cc) {
    int c = cc*16 + lr;
    float bv = (c < 180) ? bias[c] : 0.f;
    #pragma unroll
    for (int i = 0; i < 4; ++i) {
      float v = (c < 180) ? acc[cc][i] + bv : 0.f;
      acc[cc][i] = v;
      psum[i] += v; psq[i] += v*v;
    }
  }
  float m[4], rs[4];
  #pragma unroll
  for (int i = 0; i < 4; ++i) {
    float s = rsum16(psum[i]), s2 = rsum16(psq[i]);
    m[i] = s*(1.f/180.f);
    float var = fmaxf(s2*(1.f/180.f) - m[i]*m[i], 0.f);
    rs[i] = rsqrtf(var + 1e-5f);
  }
  #pragma unroll
  for (int cc = 0; cc < 12; ++cc) {
    int c = cc*16 + lr;
    if (c < 180) {
      #pragma unroll
      for (int i = 0; i < 4; ++i) {
        size_t o = (size_t)(r0 + 16*wid + lg*4 + i)*180 + c;
        outp[o] = outp[o] + (acc[cc][i] - m[i])*rs[i]*g2[c] + b2[c];
      }
    }
  }
}

// ---------------- launch ----------------
extern "C" void kernel_launch(void* const* d_in, const int* in_sizes, int n_in,
                              void* d_out, int out_size, void* d_ws, size_t ws_size,
                              hipStream_t stream) {
  const float* x      = (const float*)d_in[0];
  const float* qkv_w  = (const float*)d_in[1];
  const float* q_bias = (const float*)d_in[2];
  const float* v_bias = (const float*)d_in[3];
  const float* lsc    = (const float*)d_in[4];
  const float* cpb_w1 = (const float*)d_in[5];
  const float* cpb_b1 = (const float*)d_in[6];
  const float* cpb_w2 = (const float*)d_in[7];
  const float* proj_w = (const float*)d_in[8];
  const float* proj_b = (const float*)d_in[9];
  const float* n1g    = (const float*)d_in[10];
  const float* n1b    = (const float*)d_in[11];
  const float* n2g    = (const float*)d_in[12];
  const float* n2b    = (const float*)d_in[13];
  const float* fc1w   = (const float*)d_in[14];
  const float* fc1b   = (const float*)d_in[15];
  const float* fc2w   = (const float*)d_in[16];
  const float* fc2b   = (const float*)d_in[17];
  const float* p1w    = (const float*)d_in[18];
  const float* p1b    = (const float*)d_in[19];
  const float* pww    = (const float*)d_in[20];
  const float* pwb    = (const float*)d_in[21];
  const float* dww    = (const float*)d_in[22];
  const float* dwb    = (const float*)d_in[23];
  const float* ddw    = (const float*)d_in[24];
  const float* ddb    = (const float*)d_in[25];
  const float* p2w    = (const float*)d_in[26];
  const float* p2b    = (const float*)d_in[27];
  const float* vlng   = (const float*)d_in[28];
  const float* vlnb   = (const float*)d_in[29];
  const float* cbw    = (const float*)d_in[30];
  const float* cbb    = (const float*)d_in[31];
  const float* pew    = (const float*)d_in[32];
  const float* peb    = (const float*)d_in[33];
  float* out = (float*)d_out;
  char* ws = (char*)d_ws;

  unsigned short* qkv  = (unsigned short*)(ws + OFF_QKV);
  unsigned short* awin = (unsigned short*)(ws + OFF_AWIN);
  float* x1   = (float*)(ws + OFF_X1);
  float* v1   = (float*)(ws + OFF_V1);
  float* ab1  = (float*)(ws + OFF_AB1);
  float* ab2  = (float*)(ws + OFF_AB2);
  unsigned short* vnb = (unsigned short*)(ws + OFF_VNB);
  unsigned short* cbn = (unsigned short*)(ws + OFF_CBN);
  unsigned short* hbf = (unsigned short*)(ws + OFF_H);
  float* tbl   = (float*)(ws + O_TBL);
  float* biasA = (float*)(ws + O_BIASA);
  unsigned short* wqp = (unsigned short*)(ws + O_WQ);
  unsigned short* wpj = (unsigned short*)(ws + O_WPJ);
  unsigned short* wpe = (unsigned short*)(ws + O_WPE);
  unsigned short* wp1 = (unsigned short*)(ws + O_WP1);
  unsigned short* wpw = (unsigned short*)(ws + O_WPW);
  unsigned short* wp2 = (unsigned short*)(ws + O_WP2);
  unsigned short* wf1p = (unsigned short*)(ws + O_WF1);
  unsigned short* wf2 = (unsigned short*)(ws + O_WF2);
  unsigned short* wcb = (unsigned short*)(ws + O_WCB);

  // prep
  k_cpb_tbl<<<225, 512, 0, stream>>>(cpb_w1, cpb_b1, cpb_w2, tbl);
  k_cpb_bias<<<96, 256, 0, stream>>>(tbl, biasA);
  k_pack<<<(34*6*512+255)/256, 256, 0, stream>>>(qkv_w, wqp, 540, 180, 34, 6);
  k_cvtpad<<<(192*192+255)/256, 256, 0, stream>>>(proj_w, wpj, 180, 180, 192, 192*192);
  k_cvtpad<<<(192*192+255)/256, 256, 0, stream>>>(pew, wpe, 180, 180, 192, 192*192);
  k_cvtpad<<<(96*192+255)/256, 256, 0, stream>>>(p1w, wp1, 96, 180, 192, 96*192);
  k_cvtpad<<<(96*96+255)/256, 256, 0, stream>>>(pww, wpw, 96, 96, 96, 96*96);
  k_cvtpad<<<(192*96+255)/256, 256, 0, stream>>>(p2w, wp2, 180, 96, 96, 192*96);
  k_pack<<<(45*6*512+255)/256, 256, 0, stream>>>(fc1w, wf1p, 720, 180, 45, 6);
  k_cvtpad<<<(192*736+255)/256, 256, 0, stream>>>(fc2w, wf2, 180, 720, 736, 192*736);
  k_cvt_wcb<<<(18*96*96+255)/256, 256, 0, stream>>>(cbw, wcb);
  // main chain
  k_qkv_mfma<<<NWIN, 256, 0, stream>>>(x, wqp, q_bias, v_bias, qkv);
  k_attn_mfma<<<NWIN*6, 256, 0, stream>>>(qkv, biasA, lsc, awin);
  k_proj_mfma<<<NWIN, 256, 0, stream>>>(awin, wpj, proj_b, n1g, n1b, x, x1);
  k_p1_mfma<<<NWIN, 256, 0, stream>>>(x1, wp1, p1b, v1);
  k_pw_mfma<<<NWIN, 256, 0, stream>>>(v1, wpw, pwb, ab1);
  k_dwc<<<27648, 256, 0, stream>>>(ab1, dww, dwb, ab2, 1);
  k_dwc<<<27648, 256, 0, stream>>>(ab2, ddw, ddb, ab1, 3);
  k_p2ln_mfma<<<NWIN, 256, 0, stream>>>(v1, ab1, x1, wp2, p2b, vlng, vlnb, vnb);
  k_cb_mfma<<<NWIN, 256, 0, stream>>>(vnb, wcb, cbb, cbn);
  k_pe_mfma<<<NWIN, 256, 0, stream>>>(cbn, wpe, peb, x1, out);
  k_fc1_mfma<<<NWIN, 256, 0, stream>>>(out, wf1p, fc1b, hbf);
  k_fc2_mfma<<<NWIN, 256, 0, stream>>>(hbf, wf2, fc2b, n2g, n2b, out);
}

// Round 8
// 898.658 us; speedup vs baseline: 5.5407x; 1.0935x over previous
//
#include <hip/hip_runtime.h>
#include <hip/hip_bf16.h>

#define DEV __device__ __forceinline__

typedef __attribute__((ext_vector_type(8))) short s8v;   // 8 bf16 (4 VGPR)
typedef __attribute__((ext_vector_type(4))) float f4v;   // MFMA acc

static constexpr int NWIN = 1152;
static constexpr int NROW = 73728;

// ---------------- workspace layout (peak < 185.8 MB) ----
static constexpr size_t OFF_QKV  = 0;            // bf16 [NROW][540]  (dead after attn)
static constexpr size_t OFF_AWIN = 79626240;     // bf16 [NROW][180]  (dead after proj)
static constexpr size_t OFF_X1   = 132710400;    // f32  [NROW][180]  (live until pe/p2)
static constexpr size_t OFF_V1   = 0;            // f32  NCHW [8*96][9216]
static constexpr size_t OFF_AB1  = 28311552;     // f32  NCHW
static constexpr size_t OFF_AB2  = 56623104;     // f32  NCHW
static constexpr size_t OFF_VNB  = 56623104;     // bf16 NHWC [NROW][192] (over ab2, dead) — group-padded layout
static constexpr size_t OFF_CBN  = 0;            // bf16 NHWC [NROW][192] (over v1, dead)
static constexpr size_t OFF_H    = 0;            // bf16 [NROW][736]  (over conv temps, dead)
static constexpr size_t WB       = 130613248;
static constexpr size_t O_TBL    = WB;                    // f32 [225][6]
static constexpr size_t O_BIASA  = WB + 8192;             // f32 [6][64][64]
static constexpr size_t O_WQ     = WB + 106496;           // bf16 packed frag-major [34*6*512]
static constexpr size_t O_WPJ    = O_WQ  + 208896;        // bf16 [192][192]
static constexpr size_t O_WPE    = O_WPJ + 73728;         // bf16 [192][192]
static constexpr size_t O_WP1    = O_WPE + 73728;         // bf16 [96][192]
static constexpr size_t O_WPW    = O_WP1 + 36864;         // bf16 [96][96]
static constexpr size_t O_WP2    = O_WPW + 18432;         // bf16 [192][96]
static constexpr size_t O_WF1    = O_WP2 + 36864;         // bf16 packed frag-major [45*6*512]
static constexpr size_t O_WF2    = O_WF1 + 282624;        // bf16 [192][736]
static constexpr size_t O_WCB    = O_WF2 + 282624;        // bf16 packed frag-major [2*9*6*3*512]

DEV float geluf(float x){ return 0.5f*x*(1.f + erff(x*0.70710678118654752f)); }

DEV unsigned short f2b(float v){
  union { __hip_bfloat16 h; unsigned short u; } x;
  x.h = __float2bfloat16(v);
  return x.u;
}

DEV float b2f(unsigned short u){
  union { float f; unsigned u; } x;
  x.u = ((unsigned)u) << 16;
  return x.f;
}

DEV f4v mfma16(s8v a, s8v b, f4v c){
  return __builtin_amdgcn_mfma_f32_16x16x32_bf16(a, b, c, 0, 0, 0);
}

DEV float rsum16(float v){
  v += __shfl_xor(v, 1); v += __shfl_xor(v, 2);
  v += __shfl_xor(v, 4); v += __shfl_xor(v, 8);
  return v;
}

DEV float rmax16(float v){
  v = fmaxf(v, __shfl_xor(v, 1)); v = fmaxf(v, __shfl_xor(v, 2));
  v = fmaxf(v, __shfl_xor(v, 4)); v = fmaxf(v, __shfl_xor(v, 8));
  return v;
}

DEV float qkvbias(int c, const float* qb, const float* vb){
  return (c < 180) ? qb[c] : (c < 360 ? 0.f : vb[c-360]);
}

// ---------------- CPB MLP table ----------------
__global__ __launch_bounds__(512) void k_cpb_tbl(const float* __restrict__ w1,
    const float* __restrict__ b1, const float* __restrict__ w2, float* __restrict__ tbl){
  int m = blockIdx.x, tid = threadIdx.x;
  int i = m/15, j = m - (m/15)*15;
  float t0 = (float)(i-7)*(8.f/7.f), t1 = (float)(j-7)*(8.f/7.f);
  float f0 = log2f(fabsf(t0)+1.f)*(1.f/3.f); if (t0 < 0.f) f0 = -f0;
  float f1 = log2f(fabsf(t1)+1.f)*(1.f/3.f); if (t1 < 0.f) f1 = -f1;
  float hv = fmaxf(f0*w1[2*tid] + f1*w1[2*tid+1] + b1[tid], 0.f);
  __shared__ float red[6][8];
  int lane = tid & 63, wv = tid >> 6;
  for (int h = 0; h < 6; ++h) {
    float p = hv * w2[h*512 + tid];
    for (int off = 32; off; off >>= 1) p += __shfl_down(p, off);
    if (lane == 0) red[h][wv] = p;
  }
  __syncthreads();
  if (tid < 6) {
    float s = 0.f;
    for (int w = 0; w < 8; ++w) s += red[tid][w];
    tbl[m*6 + tid] = s;
  }
}

__global__ __launch_bounds__(256) void k_cpb_bias(const float* __restrict__ tbl,
    float* __restrict__ biasA){
  int idx = blockIdx.x*256 + threadIdx.x;
  if (idx >= 6*64*64) return;
  int h = idx >> 12, n = (idx >> 6) & 63, m = idx & 63;
  int dh = (n>>3) - (m>>3) + 7, dw = (n&7) - (m&7) + 7;
  float v = tbl[(dh*15 + dw)*6 + h];
  biasA[idx] = 16.f / (1.f + expf(-v));
}

// ---------------- weight convert + pad (row-major [col][k]) ----------------
__global__ __launch_bounds__(256) void k_cvtpad(const float* __restrict__ src,
    unsigned short* __restrict__ dst, int R, int K, int Kp, int total){
  int idx = blockIdx.x*256 + threadIdx.x;
  if (idx >= total) return;
  int r = idx / Kp, k = idx - r*Kp;
  float v = (r < R && k < K) ? src[r*K + k] : 0.f;
  dst[idx] = f2b(v);
}

// ---------------- weight pack: fragment-major for coalesced B-fragment loads -
// dst[((ct*KS + ks)*64 + l)*8 + j] = W[ct*16 + (l&15)][ks*32 + (l>>4)*8 + j]
__global__ __launch_bounds__(256) void k_pack(const float* __restrict__ src,
    unsigned short* __restrict__ dst, int Ncols, int K, int CT, int KS){
  int idx = blockIdx.x*256 + threadIdx.x;
  int total = CT*KS*512;
  if (idx >= total) return;
  int j = idx & 7, l = (idx >> 3) & 63, f = idx >> 9;
  int ks = f - (f/KS)*KS, ct = f/KS;
  int col = ct*16 + (l & 15);
  int k = ks*32 + (l >> 4)*8 + j;
  float v = (col < Ncols && k < K) ? src[col*K + k] : 0.f;
  dst[idx] = f2b(v);
}

// ---------------- convbody weight pack: fragment-major per (g,tap,cc,k0) -----
// dst[((((g*9+tap)*6+cc)*3+k0)*64 + l)*8 + j] = Wcb[g][col=cc*16+(l&15)][k=k0*32+(l>>4)*8+j][tap]
__global__ __launch_bounds__(256) void k_pack_cb(const float* __restrict__ cbw,
    unsigned short* __restrict__ dst){
  int idx = blockIdx.x*256 + threadIdx.x;
  if (idx >= 2*9*6*3*512) return;
  int j = idx & 7, l = (idx >> 3) & 63, f = idx >> 9;
  int k0 = f % 3; f /= 3;
  int cc = f % 6; f /= 6;
  int tap = f % 9; int g = f/9;
  int col = cc*16 + (l & 15);
  int k = k0*32 + (l >> 4)*8 + j;
  float v = (col < 90 && k < 90) ? cbw[((g*90 + col)*90 + k)*9 + tap] : 0.f;
  dst[idx] = f2b(v);
}

// ---------------- qkv: wave-owns-columns + packed B -> qkv bf16 [NROW][540] --
__global__ __launch_bounds__(256) void k_qkv_mfma(const float* __restrict__ x,
    const unsigned short* __restrict__ wqp, const float* __restrict__ qb,
    const float* __restrict__ vb, unsigned short* __restrict__ qkv){
  __shared__ unsigned short A[64*200];
  __shared__ int rowOff[64];
  int win = blockIdx.x, tid = threadIdx.x;
  if (tid < 64) {
    int b = win/144, rem = win - b*144, wh = rem/12, ww = rem - (rem/12)*12;
    int l = (wh*8 + (tid>>3))*96 + ww*8 + (tid&7);
    rowOff[tid] = (b*9216 + l)*180;
  }
  __syncthreads();
  for (int idx = tid; idx < 64*192; idx += 256) {
    int i = idx/192, k = idx - i*192;
    A[i*200 + k] = (k < 180) ? f2b(x[rowOff[i] + k]) : (unsigned short)0;
  }
  __syncthreads();
  int wid = tid>>6, lane = tid&63, lr = lane&15, lg = lane>>4;
  f4v z = {0.f,0.f,0.f,0.f};
  for (int ct = wid; ct < 34; ct += 4) {
    f4v acc[4];
    #pragma unroll
    for (int rg = 0; rg < 4; ++rg) acc[rg] = z;
    #pragma unroll
    for (int k0 = 0; k0 < 6; ++k0) {
      s8v b = *(const s8v*)(wqp + (size_t)((ct*6 + k0)*64 + lane)*8);
      #pragma unroll
      for (int rg = 0; rg < 4; ++rg) {
        s8v a = *(const s8v*)(A + (16*rg + lr)*200 + k0*32 + lg*8);
        acc[rg] = mfma16(a, b, acc[rg]);
      }
    }
    int c = ct*16 + lr;
    if (c < 540) {
      float bias = qkvbias(c, qb, vb);
      #pragma unroll
      for (int rg = 0; rg < 4; ++rg)
        #pragma unroll
        for (int i = 0; i < 4; ++i)
          qkv[(size_t)(win*64 + 16*rg + lg*4 + i)*540 + c] = f2b(acc[rg][i] + bias);
    }
  }
}

// ---------------- attention (MFMA) per (window, head) -> awin bf16 -----------
__global__ __launch_bounds__(256) void k_attn_mfma(const unsigned short* __restrict__ qkv,
    const float* __restrict__ biasA, const float* __restrict__ lsc,
    unsigned short* __restrict__ awin){
  __shared__ __align__(16) unsigned short Qs[64*40];   // [n][d] stride 40
  __shared__ __align__(16) unsigned short Ks[64*40];   // [m][d] stride 40
  __shared__ __align__(16) unsigned short Vt[32*72];   // [d][m] stride 72
  __shared__ __align__(16) unsigned short Ps[64*72];   // [n][m] stride 72
  __shared__ float invq[64], invk[64];
  int blk = blockIdx.x;
  int win = blk/6, h = blk - win*6;
  int tid = threadIdx.x;
  for (int idx = tid; idx < 2048; idx += 256) {
    int n = idx >> 5, d = idx & 31;
    unsigned short qv = 0, kv = 0, vv = 0;
    if (d < 30) {
      size_t row = (size_t)(win*64 + n)*540;
      qv = qkv[row + h*30 + d];
      kv = qkv[row + 180 + h*30 + d];
      vv = qkv[row + 360 + h*30 + d];
    }
    Qs[n*40 + d] = qv; Ks[n*40 + d] = kv; Vt[d*72 + n] = vv;
  }
  __syncthreads();
  if (tid < 128) {
    int n = tid & 63;
    const unsigned short* base = (tid < 64) ? (Qs + n*40) : (Ks + n*40);
    float s = 0.f;
    for (int d = 0; d < 30; ++d) { float v = b2f(base[d]); s += v*v; }
    float inv = 1.f / fmaxf(sqrtf(s), 1e-12f);
    if (tid < 64) invq[n] = inv; else invk[n] = inv;
  }
  __syncthreads();
  int wid = tid>>6, lane = tid&63, lr = lane&15, lg = lane>>4;
  float scale = __expf(fminf(lsc[h], 4.6051701859880914f));
  f4v z = {0.f,0.f,0.f,0.f};
  s8v aq = *(const s8v*)(Qs + (16*wid + lr)*40 + lg*8);
  f4v sacc[4];
  #pragma unroll
  for (int tc = 0; tc < 4; ++tc) {
    s8v bk = *(const s8v*)(Ks + (16*tc + lr)*40 + lg*8);
    sacc[tc] = mfma16(aq, bk, z);
  }
  float iq[4], ikv[4];
  #pragma unroll
  for (int i = 0; i < 4; ++i) iq[i] = invq[16*wid + lg*4 + i] * scale;
  #pragma unroll
  for (int tc = 0; tc < 4; ++tc) ikv[tc] = invk[16*tc + lr];
  float p[4][4];   // [tc][i]
  #pragma unroll
  for (int tc = 0; tc < 4; ++tc) {
    int col = 16*tc + lr;
    #pragma unroll
    for (int i = 0; i < 4; ++i) {
      int row = 16*wid + lg*4 + i;
      p[tc][i] = sacc[tc][i]*iq[i]*ikv[tc] + biasA[((h*64 + row) << 6) + col];
    }
  }
  float rin[4];
  #pragma unroll
  for (int i = 0; i < 4; ++i) {
    float mx = fmaxf(fmaxf(p[0][i], p[1][i]), fmaxf(p[2][i], p[3][i]));
    mx = rmax16(mx);
    float sum = 0.f;
    #pragma unroll
    for (int tc = 0; tc < 4; ++tc) { p[tc][i] = __expf(p[tc][i] - mx); sum += p[tc][i]; }
    sum = rsum16(sum);
    rin[i] = 1.f / sum;
  }
  #pragma unroll
  for (int tc = 0; tc < 4; ++tc)
    #pragma unroll
    for (int i = 0; i < 4; ++i)
      Ps[(16*wid + lg*4 + i)*72 + 16*tc + lr] = f2b(p[tc][i]*rin[i]);
  __syncthreads();
  f4v o0 = z, o1 = z;
  #pragma unroll
  for (int k0 = 0; k0 < 2; ++k0) {
    s8v pa = *(const s8v*)(Ps + (16*wid + lr)*72 + k0*32 + lg*8);
    s8v b0 = *(const s8v*)(Vt + lr*72        + k0*32 + lg*8);
    s8v b1 = *(const s8v*)(Vt + (16 + lr)*72 + k0*32 + lg*8);
    o0 = mfma16(pa, b0, o0);
    o1 = mfma16(pa, b1, o1);
  }
  #pragma unroll
  for (int i = 0; i < 4; ++i) {
    int row = 16*wid + lg*4 + i;
    size_t base = (size_t)(win*64 + row)*180 + h*30;
    awin[base + lr] = f2b(o0[i]);
    int c1 = 16 + lr;
    if (c1 < 30) awin[base + c1] = f2b(o1[i]);
  }
}

// ---------------- proj + norm1 LN (in-register) + residual + win-reverse -----
__global__ __launch_bounds__(256) void k_proj_mfma(const unsigned short* __restrict__ awin,
    const unsigned short* __restrict__ wpj, const float* __restrict__ pb,
    const float* __restrict__ g1, const float* __restrict__ b1,
    const float* __restrict__ x, float* __restrict__ x1){
  __shared__ unsigned short A[64*200];
  int win = blockIdx.x, tid = threadIdx.x;
  size_t rb = (size_t)win*64;
  for (int idx = tid; idx < 64*192; idx += 256) {
    int i = idx/192, k = idx - i*192;
    A[i*200 + k] = (k < 180) ? awin[(rb + i)*180 + k] : (unsigned short)0;
  }
  __syncthreads();
  int wid = tid>>6, lane = tid&63, lr = lane&15, lg = lane>>4;
  const unsigned short* arow = A + (16*wid + lr)*200 + lg*8;
  f4v z = {0.f,0.f,0.f,0.f};
  f4v acc[12];
  #pragma unroll
  for (int cc = 0; cc < 12; ++cc) acc[cc] = z;
  #pragma unroll
  for (int k0 = 0; k0 < 6; ++k0) {
    s8v a = *(const s8v*)(arow + k0*32);
    #pragma unroll
    for (int cc = 0; cc < 12; ++cc) {
      s8v b = *(const s8v*)(wpj + (size_t)(cc*16 + lr)*192 + k0*32 + lg*8);
      acc[cc] = mfma16(a, b, acc[cc]);
    }
  }
  float psum[4] = {0,0,0,0}, psq[4] = {0,0,0,0};
  #pragma unroll
  for (int cc = 0; cc < 12; ++cc) {
    int c = cc*16 + lr;
    float bias = (c < 180) ? pb[c] : 0.f;
    #pragma unroll
    for (int i = 0; i < 4; ++i) {
      float v = (c < 180) ? acc[cc][i] + bias : 0.f;
      acc[cc][i] = v;
      psum[i] += v; psq[i] += v*v;
    }
  }
  float m[4], rs[4];
  #pragma unroll
  for (int i = 0; i < 4; ++i) {
    float s = rsum16(psum[i]), s2 = rsum16(psq[i]);
    m[i] = s*(1.f/180.f);
    float var = fmaxf(s2*(1.f/180.f) - m[i]*m[i], 0.f);
    rs[i] = rsqrtf(var + 1e-5f);
  }
  int b = win/144, rem = win - b*144, wh = rem/12, ww = rem - (rem/12)*12;
  #pragma unroll
  for (int cc = 0; cc < 12; ++cc) {
    int c = cc*16 + lr;
    if (c < 180) {
      #pragma unroll
      for (int i = 0; i < 4; ++i) {
        int r = 16*wid + lg*4 + i;
        int l = (wh*8 + (r>>3))*96 + ww*8 + (r&7);
        size_t o = (size_t)(b*9216 + l)*180 + c;
        x1[o] = x[o] + (acc[cc][i] - m[i])*rs[i]*g1[c] + b1[c];
      }
    }
  }
}

// ---------------- VAB p1 ----------------
__global__ __launch_bounds__(256) void k_p1_mfma(const float* __restrict__ x1,
    const unsigned short* __restrict__ wp1, const float* __restrict__ bias,
    float* __restrict__ v1){
  __shared__ unsigned short A[64*200];
  int blk = blockIdx.x, tid = threadIdx.x;
  int b = blk/144, p0 = (blk - b*144)*64;
  int rowb = b*9216 + p0;
  for (int idx = tid; idx < 64*192; idx += 256) {
    int i = idx/192, k = idx - i*192;
    A[i*200 + k] = (k < 180) ? f2b(x1[(size_t)(rowb + i)*180 + k]) : (unsigned short)0;
  }
  __syncthreads();
  int wid = tid>>6, lane = tid&63, lr = lane&15, lg = lane>>4;
  const unsigned short* arow = A + (16*wid + lr)*200 + lg*8;
  #pragma unroll
  for (int pp = 0; pp < 3; ++pp) {
    int c0 = pp*32;
    f4v acc0 = {0.f,0.f,0.f,0.f}, acc1 = {0.f,0.f,0.f,0.f};
    #pragma unroll
    for (int k0 = 0; k0 < 6; ++k0) {
      s8v a  = *(const s8v*)(arow + k0*32);
      s8v b0 = *(const s8v*)(wp1 + (size_t)(c0 + lr)*192 + k0*32 + lg*8);
      s8v b1 = *(const s8v*)(wp1 + (size_t)(c0 + 16 + lr)*192 + k0*32 + lg*8);
      acc0 = mfma16(a, b0, acc0);
      acc1 = mfma16(a, b1, acc1);
    }
    int c  = c0 + lr, c2 = c0 + 16 + lr;
    float bv = bias[c], bv2 = bias[c2];
    #pragma unroll
    for (int i = 0; i < 4; ++i) {
      int px = 16*wid + lg*4 + i;
      v1[(size_t)(b*96 + c )*9216 + p0 + px] = geluf(acc0[i] + bv );
      v1[(size_t)(b*96 + c2)*9216 + p0 + px] = geluf(acc1[i] + bv2);
    }
  }
}

// ---------------- VAB pw ----------------
__global__ __launch_bounds__(256) void k_pw_mfma(const float* __restrict__ v1,
    const unsigned short* __restrict__ wpw, const float* __restrict__ bias,
    float* __restrict__ outp){
  __shared__ unsigned short A[64*104];
  int blk = blockIdx.x, tid = threadIdx.x;
  int b = blk/144, p0 = (blk - b*144)*64;
  for (int idx = tid; idx < 96*64; idx += 256) {
    int k = idx >> 6, i = idx & 63;
    A[i*104 + k] = f2b(v1[(size_t)(b*96 + k)*9216 + p0 + i]);
  }
  __syncthreads();
  int wid = tid>>6, lane = tid&63, lr = lane&15, lg = lane>>4;
  const unsigned short* arow = A + (16*wid + lr)*104 + lg*8;
  #pragma unroll
  for (int pp = 0; pp < 3; ++pp) {
    int c0 = pp*32;
    f4v acc0 = {0.f,0.f,0.f,0.f}, acc1 = {0.f,0.f,0.f,0.f};
    #pragma unroll
    for (int k0 = 0; k0 < 3; ++k0) {
      s8v a  = *(const s8v*)(arow + k0*32);
      s8v b0 = *(const s8v*)(wpw + (size_t)(c0 + lr)*96 + k0*32 + lg*8);
      s8v b1 = *(const s8v*)(wpw + (size_t)(c0 + 16 + lr)*96 + k0*32 + lg*8);
      acc0 = mfma16(a, b0, acc0);
      acc1 = mfma16(a, b1, acc1);
    }
    int c  = c0 + lr, c2 = c0 + 16 + lr;
    float bv = bias[c], bv2 = bias[c2];
    #pragma unroll
    for (int i = 0; i < 4; ++i) {
      int px = 16*wid + lg*4 + i;
      outp[(size_t)(b*96 + c )*9216 + p0 + px] = acc0[i] + bv;
      outp[(size_t)(b*96 + c2)*9216 + p0 + px] = acc1[i] + bv2;
    }
  }
}

// ---------------- depthwise 5x5 ----------------
__global__ __launch_bounds__(256) void k_dwc(const float* __restrict__ in,
    const float* __restrict__ w, const float* __restrict__ bias,
    float* __restrict__ out, int dil){
  int blk = blockIdx.x, tid = threadIdx.x;
  int bc = blk/36, pc = blk - bc*36;
  int c = bc - (bc/96)*96;
  int p = pc*256 + tid;
  int hh = p/96, ww = p - hh*96;
  float acc = bias[c];
  const float* wc = w + c*25;
  const float* inb = in + (size_t)bc*9216;
  #pragma unroll
  for (int i = 0; i < 5; ++i) {
    int y = hh + dil*(i-2);
    if (y < 0 || y >= 96) continue;
    #pragma unroll
    for (int j = 0; j < 5; ++j) {
      int xq = ww + dil*(j-2);
      if (xq >= 0 && xq < 96) acc += inb[y*96 + xq]*wc[i*5 + j];
    }
  }
  out[(size_t)bc*9216 + p] = acc;
}

// ---------------- p2 + residual + VAB-LN -> vnb NHWC bf16 (group-padded) -----
__global__ __launch_bounds__(256) void k_p2ln_mfma(const float* __restrict__ v1,
    const float* __restrict__ a3, const float* __restrict__ x1,
    const unsigned short* __restrict__ wp2, const float* __restrict__ bias,
    const float* __restrict__ lng, const float* __restrict__ lnb,
    unsigned short* __restrict__ vnb){
  __shared__ unsigned short A[64*104];
  int blk = blockIdx.x, tid = threadIdx.x;
  int b = blk/144, p0 = (blk - b*144)*64;
  for (int idx = tid; idx < 96*64; idx += 256) {
    int k = idx >> 6, i = idx & 63;
    size_t o = (size_t)(b*96 + k)*9216 + p0 + i;
    A[i*104 + k] = f2b(v1[o]*a3[o]);
  }
  __syncthreads();
  int wid = tid>>6, lane = tid&63, lr = lane&15, lg = lane>>4;
  const unsigned short* arow = A + (16*wid + lr)*104 + lg*8;
  f4v z = {0.f,0.f,0.f,0.f};
  f4v acc[12];
  #pragma unroll
  for (int cc = 0; cc < 12; ++cc) acc[cc] = z;
  #pragma unroll
  for (int k0 = 0; k0 < 3; ++k0) {
    s8v a = *(const s8v*)(arow + k0*32);
    #pragma unroll
    for (int cc = 0; cc < 12; ++cc) {
      s8v bb = *(const s8v*)(wp2 + (size_t)(cc*16 + lr)*96 + k0*32 + lg*8);
      acc[cc] = mfma16(a, bb, acc[cc]);
    }
  }
  float psum[4] = {0,0,0,0}, psq[4] = {0,0,0,0};
  #pragma unroll
  for (int cc = 0; cc < 12; ++cc) {
    int c = cc*16 + lr;
    float bv = (c < 180) ? bias[c] : 0.f;
    #pragma unroll
    for (int i = 0; i < 4; ++i) {
      int px = 16*wid + lg*4 + i;
      float v = 0.f;
      if (c < 180) v = acc[cc][i] + bv + x1[(size_t)(b*9216 + p0 + px)*180 + c];
      acc[cc][i] = v;
      psum[i] += v; psq[i] += v*v;
    }
  }
  float m[4], rs[4];
  #pragma unroll
  for (int i = 0; i < 4; ++i) {
    float s = rsum16(psum[i]), s2 = rsum16(psq[i]);
    m[i] = s*(1.f/180.f);
    float var = fmaxf(s2*(1.f/180.f) - m[i]*m[i], 0.f);
    rs[i] = rsqrtf(var + 1e-5f);
  }
  #pragma unroll
  for (int cc = 0; cc < 12; ++cc) {
    int c = cc*16 + lr;
    if (c < 180) {
      int cpos = c + (c >= 90 ? 6 : 0);
      #pragma unroll
      for (int i = 0; i < 4; ++i) {
        int px = 16*wid + lg*4 + i;
        vnb[(size_t)(b*9216 + p0 + px)*192 + cpos] =
            f2b((acc[cc][i] - m[i])*rs[i]*lng[c] + lnb[c]);
      }
    }
  }
  // zero-fill pad slots 90..95 and 186..191
  for (int idx = tid; idx < 64*12; idx += 256) {
    int px = idx/12, j = idx - (idx/12)*12;
    int pos = (j < 6) ? (90 + j) : (180 + j);
    vnb[(size_t)(b*9216 + p0 + px)*192 + pos] = 0;
  }
}

// ---------------- convbody: 8x8 tile, halo once, wave-owns-(g,cc3), packed B -
__global__ __launch_bounds__(256) void k_cb_mfma(const unsigned short* __restrict__ vnb,
    const unsigned short* __restrict__ wcbp, const float* __restrict__ bias,
    unsigned short* __restrict__ cbn){
  __shared__ __align__(16) unsigned short S[100*200];   // 10x10 halo x 192ch, stride 200
  int blk = blockIdx.x, tid = threadIdx.x;
  int b = blk/144, t = blk - b*144;
  int th = t/12, tw = t - (t/12)*12;
  int h0 = th*8, w0 = tw*8;
  for (int idx = tid; idx < 2400; idx += 256) {
    int pix = idx/24, chunk = idx - pix*24;
    int hp = pix/10, wp = pix - hp*10;
    int h = h0 + hp - 1, w = w0 + wp - 1;
    s8v v = {0,0,0,0,0,0,0,0};
    if (h >= 0 && h < 96 && w >= 0 && w < 96)
      v = *(const s8v*)(vnb + (size_t)(b*9216 + h*96 + w)*192 + chunk*8);
    *(s8v*)(S + pix*200 + chunk*8) = v;
  }
  __syncthreads();
  int wid = tid>>6, lane = tid&63, lr = lane&15, lg = lane>>4;
  int g = wid >> 1, ccb = (wid & 1)*3;     // wave owns gch=g, cc in [ccb, ccb+3)
  f4v z = {0.f,0.f,0.f,0.f};
  f4v acc[3][4];
  #pragma unroll
  for (int t3 = 0; t3 < 3; ++t3)
    #pragma unroll
    for (int rg = 0; rg < 4; ++rg) acc[t3][rg] = z;
  #pragma unroll
  for (int tap = 0; tap < 9; ++tap) {
    int dh = tap/3 - 1, dw = tap - (tap/3)*3 - 1;
    #pragma unroll
    for (int k0 = 0; k0 < 3; ++k0) {
      s8v a0, a1, a2, a3;
      {
        int base_k = g*96 + k0*32 + lg*8;
        int ai0 = lr;
        a0 = *(const s8v*)(S + (((ai0>>3)+1+dh)*10 + (ai0&7)+1+dw)*200 + base_k);
        int ai1 = 16 + lr;
        a1 = *(const s8v*)(S + (((ai1>>3)+1+dh)*10 + (ai1&7)+1+dw)*200 + base_k);
        int ai2 = 32 + lr;
        a2 = *(const s8v*)(S + (((ai2>>3)+1+dh)*10 + (ai2&7)+1+dw)*200 + base_k);
        int ai3 = 48 + lr;
        a3 = *(const s8v*)(S + (((ai3>>3)+1+dh)*10 + (ai3&7)+1+dw)*200 + base_k);
      }
      #pragma unroll
      for (int t3 = 0; t3 < 3; ++t3) {
        int cc = ccb + t3;
        s8v bb = *(const s8v*)(wcbp + (size_t)((((g*9 + tap)*6 + cc)*3 + k0)*64 + lane)*8);
        acc[t3][0] = mfma16(a0, bb, acc[t3][0]);
        acc[t3][1] = mfma16(a1, bb, acc[t3][1]);
        acc[t3][2] = mfma16(a2, bb, acc[t3][2]);
        acc[t3][3] = mfma16(a3, bb, acc[t3][3]);
      }
    }
  }
  #pragma unroll
  for (int t3 = 0; t3 < 3; ++t3) {
    int c = (ccb + t3)*16 + lr;
    if (c < 90) {
      int o = g*90 + c;
      float bv = bias[o];
      #pragma unroll
      for (int rg = 0; rg < 4; ++rg)
        #pragma unroll
        for (int i = 0; i < 4; ++i) {
          int oi = 16*rg + lg*4 + i;
          int oy = oi>>3, ox = oi&7;
          cbn[(size_t)(b*9216 + (h0+oy)*96 + (w0+ox))*192 + o] = f2b(acc[t3][rg][i] + bv);
        }
    }
  }
  for (int idx = tid; idx < 64*12; idx += 256) {
    int pxi = idx/12, j = idx - (idx/12)*12;
    int oy = pxi>>3, ox = pxi&7;
    cbn[(size_t)(b*9216 + (h0+oy)*96 + (w0+ox))*192 + 180 + j] = 0;
  }
}

// ---------------- pe ----------------
__global__ __launch_bounds__(256) void k_pe_mfma(const unsigned short* __restrict__ cbn,
    const unsigned short* __restrict__ wpe, const float* __restrict__ bias,
    const float* __restrict__ x1, float* __restrict__ outp){
  __shared__ unsigned short A[64*200];
  int blk = blockIdx.x, tid = threadIdx.x;
  int b = blk/144, p0 = (blk - b*144)*64;
  for (int idx = tid; idx < 64*192; idx += 256) {
    int i = idx/192, k = idx - i*192;
    A[i*200 + k] = cbn[(size_t)(b*9216 + p0 + i)*192 + k];
  }
  __syncthreads();
  int wid = tid>>6, lane = tid&63, lr = lane&15, lg = lane>>4;
  const unsigned short* arow = A + (16*wid + lr)*200 + lg*8;
  #pragma unroll
  for (int pp = 0; pp < 6; ++pp) {
    int c0 = pp*32;
    f4v acc0 = {0.f,0.f,0.f,0.f}, acc1 = {0.f,0.f,0.f,0.f};
    #pragma unroll
    for (int k0 = 0; k0 < 6; ++k0) {
      s8v a  = *(const s8v*)(arow + k0*32);
      s8v b0 = *(const s8v*)(wpe + (size_t)(c0 + lr)*192 + k0*32 + lg*8);
      s8v b1 = *(const s8v*)(wpe + (size_t)(c0 + 16 + lr)*192 + k0*32 + lg*8);
      acc0 = mfma16(a, b0, acc0);
      acc1 = mfma16(a, b1, acc1);
    }
    #pragma unroll
    for (int i = 0; i < 4; ++i) {
      int px = 16*wid + lg*4 + i;
      size_t rowo = (size_t)(b*9216 + p0 + px)*180;
      int c = c0 + lr;
      if (c < 180) outp[rowo + c] = x1[rowo + c] + acc0[i] + bias[c];
      int c2 = c0 + 16 + lr;
      if (c2 < 180) outp[rowo + c2] = x1[rowo + c2] + acc1[i] + bias[c2];
    }
  }
}

// ---------------- fc1: wave-owns-columns + packed B + gelu -> hbuf -----------
__global__ __launch_bounds__(256) void k_fc1_mfma(const float* __restrict__ xo,
    const unsigned short* __restrict__ wf1p, const float* __restrict__ bias,
    unsigned short* __restrict__ hbuf){
  __shared__ unsigned short A[64*200];
  int blk = blockIdx.x, tid = threadIdx.x;
  int r0 = blk*64;
  for (int idx = tid; idx < 64*192; idx += 256) {
    int i = idx/192, k = idx - i*192;
    A[i*200 + k] = (k < 180) ? f2b(xo[(size_t)(r0 + i)*180 + k]) : (unsigned short)0;
  }
  __syncthreads();
  int wid = tid>>6, lane = tid&63, lr = lane&15, lg = lane>>4;
  f4v z = {0.f,0.f,0.f,0.f};
  for (int ct = wid; ct < 45; ct += 4) {
    f4v acc[4];
    #pragma unroll
    for (int rg = 0; rg < 4; ++rg) acc[rg] = z;
    #pragma unroll
    for (int k0 = 0; k0 < 6; ++k0) {
      s8v b = *(const s8v*)(wf1p + (size_t)((ct*6 + k0)*64 + lane)*8);
      #pragma unroll
      for (int rg = 0; rg < 4; ++rg) {
        s8v a = *(const s8v*)(A + (16*rg + lr)*200 + k0*32 + lg*8);
        acc[rg] = mfma16(a, b, acc[rg]);
      }
    }
    int c = ct*16 + lr;              // always < 720 (45*16 == 720)
    float bv = bias[c];
    #pragma unroll
    for (int rg = 0; rg < 4; ++rg)
      #pragma unroll
      for (int i = 0; i < 4; ++i)
        hbuf[(size_t)(r0 + 16*rg + lg*4 + i)*736 + c] = f2b(geluf(acc[rg][i] + bv));
  }
  // zero pad cols 720..735
  for (int idx = tid; idx < 64*16; idx += 256) {
    int r = idx >> 4, j = idx & 15;
    hbuf[(size_t)(r0 + r)*736 + 720 + j] = 0;
  }
}

// ---------------- fc2 + norm2 LN + residual ----------------
__global__ __launch_bounds__(256) void k_fc2_mfma(const unsigned short* __restrict__ hbuf,
    const unsigned short* __restrict__ wf2, const float* __restrict__ bias,
    const float* __restrict__ g2, const float* __restrict__ b2,
    float* __restrict__ outp){
  int blk = blockIdx.x, tid = threadIdx.x;
  int r0 = blk*64;
  int wid = tid>>6, lane = tid&63, lr = lane&15, lg = lane>>4;
  const unsigned short* arow = hbuf + (size_t)(r0 + 16*wid + lr)*736 + lg*8;
  f4v z = {0.f,0.f,0.f,0.f};
  f4v acc[12];
  #pragma unroll
  for (int cc = 0; cc < 12; ++cc) acc[cc] = z;
  for (int k0 = 0; k0 < 23; ++k0) {
    s8v a = *(const s8v*)(arow + k0*32);
    #pragma unroll
    for (int cc = 0; cc < 12; ++cc) {
      s8v b = *(const s8v*)(wf2 + (size_t)(cc*16 + lr)*736 + k0*32 + lg*8);
      acc[cc] = mfma16(a, b, acc[cc]);
    }
  }
  float psum[4] = {0,0,0,0}, psq[4] = {0,0,0,0};
  #pragma unroll
  for (int cc = 0; cc < 12; ++cc) {
    int c = cc*16 + lr;
    float bv = (c < 180) ? bias[c] : 0.f;
    #pragma unroll
    for (int i = 0; i < 4; ++i) {
      float v = (c < 180) ? acc[cc][i] + bv : 0.f;
      acc[cc][i] = v;
      psum[i] += v; psq[i] += v*v;
    }
  }
  float m[4], rs[4];
  #pragma unroll
  for (int i = 0; i < 4; ++i) {
    float s = rsum16(psum[i]), s2 = rsum16(psq[i]);
    m[i] = s*(1.f/180.f);
    float var = fmaxf(s2*(1.f/180.f) - m[i]*m[i], 0.f);
    rs[i] = rsqrtf(var + 1e-5f);
  }
  #pragma unroll
  for (int cc = 0; cc < 12; ++cc) {
    int c = cc*16 + lr;
    if (c < 180) {
      #pragma unroll
      for (int i = 0; i < 4; ++i) {
        size_t o = (size_t)(r0 + 16*wid + lg*4 + i)*180 + c;
        outp[o] = outp[o] + (acc[cc][i] - m[i])*rs[i]*g2[c] + b2[c];
      }
    }
  }
}

// ---------------- launch ----------------
extern "C" void kernel_launch(void* const* d_in, const int* in_sizes, int n_in,
                              void* d_out, int out_size, void* d_ws, size_t ws_size,
                              hipStream_t stream) {
  const float* x      = (const float*)d_in[0];
  const float* qkv_w  = (const float*)d_in[1];
  const float* q_bias = (const float*)d_in[2];
  const float* v_bias = (const float*)d_in[3];
  const float* lsc    = (const float*)d_in[4];
  const float* cpb_w1 = (const float*)d_in[5];
  const float* cpb_b1 = (const float*)d_in[6];
  const float* cpb_w2 = (const float*)d_in[7];
  const float* proj_w = (const float*)d_in[8];
  const float* proj_b = (const float*)d_in[9];
  const float* n1g    = (const float*)d_in[10];
  const float* n1b    = (const float*)d_in[11];
  const float* n2g    = (const float*)d_in[12];
  const float* n2b    = (const float*)d_in[13];
  const float* fc1w   = (const float*)d_in[14];
  const float* fc1b   = (const float*)d_in[15];
  const float* fc2w   = (const float*)d_in[16];
  const float* fc2b   = (const float*)d_in[17];
  const float* p1w    = (const float*)d_in[18];
  const float* p1b    = (const float*)d_in[19];
  const float* pww    = (const float*)d_in[20];
  const float* pwb    = (const float*)d_in[21];
  const float* dww    = (const float*)d_in[22];
  const float* dwb    = (const float*)d_in[23];
  const float* ddw    = (const float*)d_in[24];
  const float* ddb    = (const float*)d_in[25];
  const float* p2w    = (const float*)d_in[26];
  const float* p2b    = (const float*)d_in[27];
  const float* vlng   = (const float*)d_in[28];
  const float* vlnb   = (const float*)d_in[29];
  const float* cbw    = (const float*)d_in[30];
  const float* cbb    = (const float*)d_in[31];
  const float* pew    = (const float*)d_in[32];
  const float* peb    = (const float*)d_in[33];
  float* out = (float*)d_out;
  char* ws = (char*)d_ws;

  unsigned short* qkv  = (unsigned short*)(ws + OFF_QKV);
  unsigned short* awin = (unsigned short*)(ws + OFF_AWIN);
  float* x1   = (float*)(ws + OFF_X1);
  float* v1   = (float*)(ws + OFF_V1);
  float* ab1  = (float*)(ws + OFF_AB1);
  float* ab2  = (float*)(ws + OFF_AB2);
  unsigned short* vnb = (unsigned short*)(ws + OFF_VNB);
  unsigned short* cbn = (unsigned short*)(ws + OFF_CBN);
  unsigned short* hbf = (unsigned short*)(ws + OFF_H);
  float* tbl   = (float*)(ws + O_TBL);
  float* biasA = (float*)(ws + O_BIASA);
  unsigned short* wqp = (unsigned short*)(ws + O_WQ);
  unsigned short* wpj = (unsigned short*)(ws + O_WPJ);
  unsigned short* wpe = (unsigned short*)(ws + O_WPE);
  unsigned short* wp1 = (unsigned short*)(ws + O_WP1);
  unsigned short* wpw = (unsigned short*)(ws + O_WPW);
  unsigned short* wp2 = (unsigned short*)(ws + O_WP2);
  unsigned short* wf1p = (unsigned short*)(ws + O_WF1);
  unsigned short* wf2 = (unsigned short*)(ws + O_WF2);
  unsigned short* wcbp = (unsigned short*)(ws + O_WCB);

  // prep
  k_cpb_tbl<<<225, 512, 0, stream>>>(cpb_w1, cpb_b1, cpb_w2, tbl);
  k_cpb_bias<<<96, 256, 0, stream>>>(tbl, biasA);
  k_pack<<<(34*6*512+255)/256, 256, 0, stream>>>(qkv_w, wqp, 540, 180, 34, 6);
  k_cvtpad<<<(192*192+255)/256, 256, 0, stream>>>(proj_w, wpj, 180, 180, 192, 192*192);
  k_cvtpad<<<(192*192+255)/256, 256, 0, stream>>>(pew, wpe, 180, 180, 192, 192*192);
  k_cvtpad<<<(96*192+255)/256, 256, 0, stream>>>(p1w, wp1, 96, 180, 192, 96*192);
  k_cvtpad<<<(96*96+255)/256, 256, 0, stream>>>(pww, wpw, 96, 96, 96, 96*96);
  k_cvtpad<<<(192*96+255)/256, 256, 0, stream>>>(p2w, wp2, 180, 96, 96, 192*96);
  k_pack<<<(45*6*512+255)/256, 256, 0, stream>>>(fc1w, wf1p, 720, 180, 45, 6);
  k_cvtpad<<<(192*736+255)/256, 256, 0, stream>>>(fc2w, wf2, 180, 720, 736, 192*736);
  k_pack_cb<<<(2*9*6*3*512+255)/256, 256, 0, stream>>>(cbw, wcbp);
  // main chain
  k_qkv_mfma<<<NWIN, 256, 0, stream>>>(x, wqp, q_bias, v_bias, qkv);
  k_attn_mfma<<<NWIN*6, 256, 0, stream>>>(qkv, biasA, lsc, awin);
  k_proj_mfma<<<NWIN, 256, 0, stream>>>(awin, wpj, proj_b, n1g, n1b, x, x1);
  k_p1_mfma<<<NWIN, 256, 0, stream>>>(x1, wp1, p1b, v1);
  k_pw_mfma<<<NWIN, 256, 0, stream>>>(v1, wpw, pwb, ab1);
  k_dwc<<<27648, 256, 0, stream>>>(ab1, dww, dwb, ab2, 1);
  k_dwc<<<27648, 256, 0, stream>>>(ab2, ddw, ddb, ab1, 3);
  k_p2ln_mfma<<<NWIN, 256, 0, stream>>>(v1, ab1, x1, wp2, p2b, vlng, vlnb, vnb);
  k_cb_mfma<<<NWIN, 256, 0, stream>>>(vnb, wcbp, cbb, cbn);
  k_pe_mfma<<<NWIN, 256, 0, stream>>>(cbn, wpe, peb, x1, out);
  k_fc1_mfma<<<NWIN, 256, 0, stream>>>(out, wf1p, fc1b, hbf);
  k_fc2_mfma<<<NWIN, 256, 0, stream>>>(hbf, wf2, fc2b, n2g, n2b, out);
}